// Round 1
// baseline (224.384 us; speedup 1.0000x reference)
//
#include <hip/hip_runtime.h>
#include <hip/hip_bf16.h>
#include <cstdint>
#include <cstddef>

// R9: attention occupancy + L2-locality round.
//  - dilated_attn restructured 256->512 threads: 8 waves x 16 q-rows (was
//    4 x 32). Same grid (448), same LDS (52KB), half the per-wave state ->
//    2x wave contexts per SIMD (~1.75 -> ~3.5) to hide the QK->exp->P->PV
//    chain latency and the barrier vmcnt drain. Counters said latency-bound
//    (MfmaUtil 16%, VALUBusy 20%, HBM 12%, occupancy 17%).
//  - XCD-chunked swizzle: 448 = 8*56; L=(bx&7)*56+(bx>>3) gives each XCD a
//    contiguous sh-chunk (~1.8MB K+V working set -> L2-resident; the 16
//    q-tiles sharing one K/V stream now share one XCD's L2).
//  - s_setprio(1) around both MFMA clusters.
// GEMMs / cvt3 / ln_inplace unchanged (m97-recipe gemm128).

typedef __attribute__((ext_vector_type(8))) short short8;
typedef __attribute__((ext_vector_type(4))) short short4_;
typedef __attribute__((ext_vector_type(4))) float float4_;

#if __has_builtin(__builtin_amdgcn_exp2f)
#define EXP2(x) __builtin_amdgcn_exp2f(x)
#else
#define EXP2(x) exp2f(x)
#endif

__device__ __forceinline__ float bf2f(short s) {
    unsigned int u = ((unsigned int)(unsigned short)s) << 16;
    float f;
    __builtin_memcpy(&f, &u, 4);
    return f;
}
__device__ __forceinline__ short f2bf(float f) {
    unsigned int u;
    __builtin_memcpy(&u, &f, 4);
    u += 0x7fffu + ((u >> 16) & 1u);   // round-to-nearest-even
    return (short)(u >> 16);
}
__device__ __forceinline__ short f2bf_trunc(float f) {
    unsigned int u;
    __builtin_memcpy(&u, &f, 4);
    return (short)(u >> 16);
}
__device__ __forceinline__ short8 f8_to_bf8(const float* __restrict__ p) {
    float4_ a = *(const float4_*)(p);
    float4_ b = *(const float4_*)(p + 4);
    short8 r;
    r[0] = f2bf(a[0]); r[1] = f2bf(a[1]); r[2] = f2bf(a[2]); r[3] = f2bf(a[3]);
    r[4] = f2bf(b[0]); r[5] = f2bf(b[1]); r[6] = f2bf(b[2]); r[7] = f2bf(b[3]);
    return r;
}
__device__ __forceinline__ void gll16(const short* g, short* l) {
    __builtin_amdgcn_global_load_lds(
        (const __attribute__((address_space(1))) unsigned int*)g,
        (__attribute__((address_space(3))) unsigned int*)l, 16, 0, 0);
}

#define LDT 72

// ---- cvt3: fp32->bf16 for x / w_qkv / w_out -------------------------------
__global__ __launch_bounds__(256) void cvt3(
    const float* __restrict__ a, int na, const float* __restrict__ b, int nb,
    const float* __restrict__ c, int nc,
    short* __restrict__ oa, short* __restrict__ ob, short* __restrict__ oc)
{
    int i = (blockIdx.x * 256 + threadIdx.x) * 8;
    if (i < na) {
        *(short8*)&oa[i] = f8_to_bf8(a + i);
    } else if (i < na + nb) {
        int j = i - na;
        *(short8*)&ob[j] = f8_to_bf8(b + j);
    } else {
        int j = i - na - nb;
        if (j < nc) *(short8*)&oc[j] = f8_to_bf8(c + j);
    }
}

// ---- gemm128<EPI>: C[M,N] = A[M,K](lda) @ B[N,K]^T + bias ----------------
template<int EPI>
__global__ __launch_bounds__(256) void gemm128(
    const short* __restrict__ A, int lda,
    const short* __restrict__ B,
    const float* __restrict__ bias,
    void* __restrict__ Cv,
    int N, int K)
{
    __shared__ short As[128 * 64];   // chunk-swizzled: slot(r,c)=G(r, c^(r&7))
    __shared__ short Bs[128 * 64];
    const int tid  = threadIdx.x;
    const int wave = tid >> 6, lane = tid & 63;
    const int quad = lane >> 4, l16 = lane & 15;
    const int wr = wave >> 1, wc = wave & 1;
    const int m0 = blockIdx.y * 128, n0 = blockIdx.x * 128;
    const int lrow   = lane >> 3;
    const int lchunk = (lane & 7) ^ lrow;

    const short* Abase = A + (size_t)(m0 + wave * 32 + lrow) * lda + lchunk * 8;
    const short* Bbase = B + (size_t)(n0 + wave * 32 + lrow) * (size_t)K + lchunk * 8;
    short* AsW = &As[(wave * 32) * 64];
    short* BsW = &Bs[(wave * 32) * 64];

    float4_ acc[4][4] = {};

    for (int k0 = 0; k0 < K; k0 += 64) {
        __syncthreads();
        #pragma unroll
        for (int i = 0; i < 4; i++) {
            gll16(Abase + (size_t)(i * 8) * lda + k0, AsW + (i * 8) * 64);
            gll16(Bbase + (size_t)(i * 8) * K   + k0, BsW + (i * 8) * 64);
        }
        __syncthreads();
        #pragma unroll
        for (int ks = 0; ks < 2; ks++) {
            short8 af[4], bf[4];
            const int ca = ((ks * 4 + quad) ^ (l16 & 7)) * 8;
            #pragma unroll
            for (int t = 0; t < 4; t++) {
                af[t] = *(const short8*)&As[(wr * 64 + t * 16 + l16) * 64 + ca];
                bf[t] = *(const short8*)&Bs[(wc * 64 + t * 16 + l16) * 64 + ca];
            }
            #pragma unroll
            for (int mt = 0; mt < 4; mt++)
                #pragma unroll
                for (int nt = 0; nt < 4; nt++)
                    acc[mt][nt] = __builtin_amdgcn_mfma_f32_16x16x32_bf16(
                        af[mt], bf[nt], acc[mt][nt], 0, 0, 0);
        }
    }

    #pragma unroll
    for (int nt = 0; nt < 4; nt++) {
        const int col = n0 + wc * 64 + nt * 16 + l16;
        const float bv = bias[col];
        if constexpr (EPI == 0) {
            short* C = (short*)Cv;
            const int g = col >> 8;
            #pragma unroll
            for (int mt = 0; mt < 4; mt++) {
                #pragma unroll
                for (int r = 0; r < 4; r++) {
                    int row = m0 + wr * 64 + mt * 16 + quad * 4 + r;
                    bool cov = (col >= 768) || (g == 0) ||
                               (g == 1 && (row & 1) == 1) ||
                               (g == 2 && (row & 3) == 2);
                    C[(size_t)row * N + col] = cov ? f2bf(acc[mt][nt][r] + bv) : (short)0;
                }
            }
        } else {
            float* C = (float*)Cv;
            #pragma unroll
            for (int mt = 0; mt < 4; mt++)
                #pragma unroll
                for (int r = 0; r < 4; r++) {
                    int row = m0 + wr * 64 + mt * 16 + quad * 4 + r;
                    C[(size_t)row * N + col] = acc[mt][nt][r] + bv;
                }
        }
    }
}

// ---- Pipelined dilated attention, Q-tile 128, 8 waves x 16 rows -----------
// Grid: 448 (XCD-chunk swizzled: 8 XCDs x 56 blocks; contiguous sh per XCD
// so the 16 q-tiles sharing one K/V stream share one L2). Block 512 = 8
// waves; wave w owns q-rows [w*16, w*16+16). 32 K/V tiles of 64 keys,
// double-buffered, 1 barrier/iter. Writes UNNORMALIZED O into the q section
// + 1/l into lbuf[pos*12+head].
__global__ __launch_bounds__(512, 4) void dilated_attn(
    short* __restrict__ qkv, float* __restrict__ lbuf)
{
    __shared__ short Ks[2 * 64 * 64];   // unpadded, chunk-XOR swizzled (DMA)
    __shared__ short Vt[2 * 64 * LDT];  // Vt[d][key], key cols XOR-swizzled
    __shared__ short Ps[8 * 16 * LDT];  // per-wave P, column-swizzled

    // XCD-chunk swizzle: physical bx%8 = XCD; give each XCD 56 contiguous
    // logical blocks (3.5 sh groups -> ~1.8MB K+V working set, L2-resident).
    const int bx = blockIdx.x;
    const int L  = (bx & 7) * 56 + (bx >> 3);
    const int qt = L & 15;
    const int sh = L >> 4;   // 0..27

    int g, seg, s, rate, off0;
    if (sh < 16)      { g = 0; seg = sh >> 2;        s = 2048; rate = 1; off0 = 0; }
    else if (sh < 24) { g = 1; seg = (sh - 16) >> 2; s = 4096; rate = 2; off0 = 1; }
    else              { g = 2; seg = 0;              s = 8192; rate = 4; off0 = 2; }
    const int head = g * 4 + (sh & 3);

    const int tid  = threadIdx.x;
    const int wave = tid >> 6, lane = tid & 63, quad = lane >> 4, l16 = lane & 15;
    const int srow = tid >> 3, scol = (tid & 7) * 8;    // V-staging map
    const int vswz = scol & 48;                          // (d>>4)*16 swizzle

    // ---- Q frags direct global->regs, pre-scaled by 0.125*log2(e) --------
    short8 aq[2];
    {
        int t = qt * 128 + wave * 16 + l16;
        size_t pos = (size_t)seg * s + off0 + (size_t)t * rate;
        const short* qsrc = qkv + pos * 2304 + head * 64 + quad * 8;
        #pragma unroll
        for (int ks = 0; ks < 2; ks++) {
            short8 q = *(const short8*)(qsrc + ks * 32);
            #pragma unroll
            for (int e = 0; e < 8; e++) q[e] = f2bf(bf2f(q[e]) * 0.1803368801111244f);
            aq[ks] = q;
        }
    }

    // staging maps: 8 waves x 8 rows = 64 K-rows, one gll16 per thread
    const int krow0  = wave * 8 + (lane >> 3);
    const int kchunk = (lane & 7) ^ (lane >> 3);
    const size_t kstep = (size_t)64 * rate * 2304;
    const short* kg = qkv + ((size_t)seg * s + off0 + (size_t)krow0 * rate) * 2304
                          + 768 + head * 64 + kchunk * 8;
    const short* vgp = qkv + ((size_t)seg * s + off0 + (size_t)srow * rate) * 2304
                           + 1536 + head * 64 + scol;
    const int kofs = (wave * 8) * 64;

    // ---- prologue: K tile 0 via DMA into Ks[0]; V tile 0 regs -> Vt[0] ----
    gll16(kg, &Ks[kofs]);
    kg += kstep;
    short8 va = *(const short8*)(vgp);
    vgp += kstep;
    #pragma unroll
    for (int e = 0; e < 8; e++) Vt[(scol + e) * LDT + (srow ^ vswz)] = va[e];
    va = *(const short8*)(vgp);       // V tile 1
    vgp += kstep;

    float lrow[4] = {};
    float4_ oacc[4] = {};
    short* pw = &Ps[wave * 16 * LDT];
    const int cswap = (lane >> 5) & 1;       // = quad>>1 = (row>>3)&1
    const int pswz  = (l16 & 8) << 1;

    for (int j = 0; j < 32; j++) {
        __syncthreads();   // buf[j&1] staging visible; prev compute done
        if (j < 31) {
            const int nb = (j + 1) & 1;
            gll16(kg, &Ks[nb * 4096 + kofs]);
            kg += kstep;
            short* vt = &Vt[nb * 64 * LDT];
            #pragma unroll
            for (int e = 0; e < 8; e++) vt[(scol + e) * LDT + (srow ^ vswz)] = va[e];
            if (j < 30) {
                va = *(const short8*)(vgp);
                vgp += kstep;
            }
        }
        const short* kb = &Ks[(j & 1) * 4096];
        const short* vb = &Vt[(j & 1) * 64 * LDT];

        // S' = (Q*c) K^T : 16 q-rows x 64 keys per wave
        float4_ sacc[4] = {};
        __builtin_amdgcn_s_setprio(1);
        #pragma unroll
        for (int ks = 0; ks < 2; ks++) {
            #pragma unroll
            for (int kt = 0; kt < 4; kt++) {
                short8 bk = *(const short8*)&kb[(kt * 16 + l16) * 64
                                                + (((quad + 4 * ks) ^ (l16 & 7)) * 8)];
                sacc[kt] = __builtin_amdgcn_mfma_f32_16x16x32_bf16(
                    aq[ks], bk, sacc[kt], 0, 0, 0);
            }
        }
        __builtin_amdgcn_s_setprio(0);

        // P = exp2(S'), per-lane partial sums, stash to LDS
        #pragma unroll
        for (int r = 0; r < 4; r++) {
            float p0 = EXP2(sacc[0][r]), p1 = EXP2(sacc[1][r]);
            float p2 = EXP2(sacc[2][r]), p3 = EXP2(sacc[3][r]);
            short* prow = &pw[(quad * 4 + r) * LDT + l16];
            prow[(0 ^ cswap) * 16] = f2bf_trunc(p0);
            prow[(1 ^ cswap) * 16] = f2bf_trunc(p1);
            prow[(2 ^ cswap) * 16] = f2bf_trunc(p2);
            prow[(3 ^ cswap) * 16] = f2bf_trunc(p3);
            lrow[r] += (p0 + p1) + (p2 + p3);
        }

        // O += P @ V
        __builtin_amdgcn_s_setprio(1);
        #pragma unroll
        for (int ks = 0; ks < 2; ks++) {
            short8 ap = *(const short8*)&pw[l16 * LDT + ((ks * 32 + quad * 8) ^ pswz)];
            #pragma unroll
            for (int nt = 0; nt < 4; nt++) {
                short8 bv = *(const short8*)&vb[(nt * 16 + l16) * LDT
                                                + ((ks * 32 + quad * 8) ^ (nt * 16))];
                oacc[nt] = __builtin_amdgcn_mfma_f32_16x16x32_bf16(
                    ap, bv, oacc[nt], 0, 0, 0);
            }
        }
        __builtin_amdgcn_s_setprio(0);
    }

    // epilogue: write unnormalized O into q section, 1/l into lbuf
    #pragma unroll
    for (int r = 0; r < 4; r++) {
        float v = lrow[r];
        #pragma unroll
        for (int off = 1; off < 16; off <<= 1) v += __shfl_xor(v, off, 64);
        int qrow = wave * 16 + quad * 4 + r;
        int t = qt * 128 + qrow;
        size_t pos = (size_t)seg * s + off0 + (size_t)t * rate;
        short* od = qkv + pos * 2304 + head * 64;
        #pragma unroll
        for (int nt = 0; nt < 4; nt++)
            od[nt * 16 + l16] = f2bf(oacc[nt][r]);
        if (l16 == 0) lbuf[pos * 12 + head] = 1.0f / v;
    }
}

// ---- Fused LayerNorm: apply 1/l per head, stats, gamma/beta, in-place -----
__global__ __launch_bounds__(256) void ln_inplace(
    short* __restrict__ qkv, const float* __restrict__ lbuf,
    const float* __restrict__ gamma, const float* __restrict__ beta)
{
    const int row  = blockIdx.x * 4 + (threadIdx.x >> 6);
    const int lane = threadIdx.x & 63;
    short* src = qkv + (size_t)row * 2304;

    // heads: first 8 elems (idx lane*8..+7) in head lane>>3;
    // last 4 (idx 512+lane*4..+3) in head 8+(lane>>4)
    const float li1 = lbuf[row * 12 + (lane >> 3)];
    const float li2 = lbuf[row * 12 + 8 + (lane >> 4)];

    short8  a = *(const short8*)&src[lane * 8];
    short4_ b = *(const short4_*)&src[512 + lane * 4];
    float v[12];
    #pragma unroll
    for (int e = 0; e < 8; e++) v[e] = bf2f(a[e]) * li1;
    #pragma unroll
    for (int e = 0; e < 4; e++) v[8 + e] = bf2f(b[e]) * li2;

    float sum = 0.f, sq = 0.f;
    #pragma unroll
    for (int e = 0; e < 12; e++) { sum += v[e]; sq += v[e] * v[e]; }
    #pragma unroll
    for (int off = 1; off < 64; off <<= 1) {
        sum += __shfl_xor(sum, off, 64);
        sq  += __shfl_xor(sq,  off, 64);
    }
    float mean = sum * (1.0f / 768.0f);
    float var  = sq * (1.0f / 768.0f) - mean * mean;
    float rstd = rsqrtf(var + 1e-5f);

    short8 o8; short4_ o4;
    #pragma unroll
    for (int e = 0; e < 8; e++)
        o8[e] = f2bf((v[e] - mean) * rstd * gamma[lane * 8 + e] + beta[lane * 8 + e]);
    #pragma unroll
    for (int e = 0; e < 4; e++)
        o4[e] = f2bf((v[8 + e] - mean) * rstd * gamma[512 + lane * 4 + e] + beta[512 + lane * 4 + e]);

    *(short8*)&src[lane * 8] = o8;
    *(short4_*)&src[512 + lane * 4] = o4;
}

extern "C" void kernel_launch(void* const* d_in, const int* in_sizes, int n_in,
                              void* d_out, int out_size, void* d_ws, size_t ws_size,
                              hipStream_t stream) {
    const float* x     = (const float*)d_in[0];   // [8192,768]
    const float* w_qkv = (const float*)d_in[1];   // [2304,768]
    const float* b_qkv = (const float*)d_in[2];
    const float* w_out = (const float*)d_in[3];   // [768,768]
    const float* b_out = (const float*)d_in[4];
    const float* gamma = (const float*)d_in[5];
    const float* beta  = (const float*)d_in[6];
    float* out = (float*)d_out;                   // [8192,768] fp32

    const int NX = 8192 * 768, NW1 = 2304 * 768, NW2 = 768 * 768;
    char* ws = (char*)d_ws;
    short* qkv   = (short*)(ws);                          // 37.75 MB
    short* xb    = (short*)(ws + (size_t)8192 * 2304 * 2);
    short* wqkvb = xb + NX;
    short* woutb = wqkvb + NW1;
    float* lbuf  = (float*)(woutb + NW2);                 // 8192*12 fp32 = 393 KB

    // 0) one-shot fp32->bf16 conversions
    cvt3<<<dim3((NX + NW1 + NW2) / (256 * 8)), 256, 0, stream>>>(
        x, NX, w_qkv, NW1, w_out, NW2, xb, wqkvb, woutb);

    // 1) qkv = x @ w_qkv^T + b_qkv (bf16), non-dilated q cells zeroed
    gemm128<0><<<dim3(2304 / 128, 8192 / 128), 256, 0, stream>>>(
        xb, 768, wqkvb, b_qkv, qkv, 2304, 768);

    // 2) pipelined attention: unnormalized O into q section + 1/l to lbuf
    dilated_attn<<<dim3(28 * 16), 512, 0, stream>>>(qkv, lbuf);

    // 3) LayerNorm (applies 1/l per head) in-place on q section
    ln_inplace<<<dim3(8192 / 4), 256, 0, stream>>>(qkv, lbuf, gamma, beta);

    // 4) out = LN(o) @ w_out^T + b_out (fp32 store)
    gemm128<1><<<dim3(768 / 128, 8192 / 128), 256, 0, stream>>>(
        qkv, 2304, woutb, b_out, out, 768, 768);
}

// Round 2
// 220.141 us; speedup vs baseline: 1.0193x; 1.0193x over previous
//
#include <hip/hip_runtime.h>
#include <hip/hip_bf16.h>
#include <cstdint>
#include <cstddef>

// R10: split-K attention (LDS-issue-bound fix).
//  R9 post-mortem: attn is LDS-unit-bound. Every wave reads the full K and V
//  tile from LDS regardless of how many q-rows it owns, so 8 waves x 16 rows
//  doubled LDS read traffic vs 4 x 32 (bank-conflict counter confirmed 2x).
//  LDS-cycle model: ~310 cyc/wave-iter x 8 waves x 32 it x 1.75 blk/CU ~ 58us
//  = the measured floor.
//  Fix: 4 waves x 32 rows (halves LDS reads/row) AND 3.5 waves/SIMD occupancy
//  via split-K: 896 blocks = 28 sh x 16 qt x 2 key-halves, 16 K-tiles each.
//  Combine folded into ln_inplace: split0 -> q-section + l0; split1 -> scratch
//  (aliases dead xb) + l1; LN computes (O0+O1)/(l0+l1) with an explicit
//  coverage predicate (kills the latent garbage-lbuf NaN risk).
//  Keep: XCD-chunk swizzle (112 blocks/XCD, qt-major within (sh,half) so K/V
//  stays L2-resident), s_setprio around MFMA clusters, 1-barrier pipeline.
// GEMMs / cvt3 unchanged.

typedef __attribute__((ext_vector_type(8))) short short8;
typedef __attribute__((ext_vector_type(4))) short short4_;
typedef __attribute__((ext_vector_type(4))) float float4_;

#if __has_builtin(__builtin_amdgcn_exp2f)
#define EXP2(x) __builtin_amdgcn_exp2f(x)
#else
#define EXP2(x) exp2f(x)
#endif

__device__ __forceinline__ float bf2f(short s) {
    unsigned int u = ((unsigned int)(unsigned short)s) << 16;
    float f;
    __builtin_memcpy(&f, &u, 4);
    return f;
}
__device__ __forceinline__ short f2bf(float f) {
    unsigned int u;
    __builtin_memcpy(&u, &f, 4);
    u += 0x7fffu + ((u >> 16) & 1u);   // round-to-nearest-even
    return (short)(u >> 16);
}
__device__ __forceinline__ short f2bf_trunc(float f) {
    unsigned int u;
    __builtin_memcpy(&u, &f, 4);
    return (short)(u >> 16);
}
__device__ __forceinline__ short8 f8_to_bf8(const float* __restrict__ p) {
    float4_ a = *(const float4_*)(p);
    float4_ b = *(const float4_*)(p + 4);
    short8 r;
    r[0] = f2bf(a[0]); r[1] = f2bf(a[1]); r[2] = f2bf(a[2]); r[3] = f2bf(a[3]);
    r[4] = f2bf(b[0]); r[5] = f2bf(b[1]); r[6] = f2bf(b[2]); r[7] = f2bf(b[3]);
    return r;
}
__device__ __forceinline__ void gll16(const short* g, short* l) {
    __builtin_amdgcn_global_load_lds(
        (const __attribute__((address_space(1))) unsigned int*)g,
        (__attribute__((address_space(3))) unsigned int*)l, 16, 0, 0);
}

#define LDT 72

// ---- cvt3: fp32->bf16 for x / w_qkv / w_out -------------------------------
__global__ __launch_bounds__(256) void cvt3(
    const float* __restrict__ a, int na, const float* __restrict__ b, int nb,
    const float* __restrict__ c, int nc,
    short* __restrict__ oa, short* __restrict__ ob, short* __restrict__ oc)
{
    int i = (blockIdx.x * 256 + threadIdx.x) * 8;
    if (i < na) {
        *(short8*)&oa[i] = f8_to_bf8(a + i);
    } else if (i < na + nb) {
        int j = i - na;
        *(short8*)&ob[j] = f8_to_bf8(b + j);
    } else {
        int j = i - na - nb;
        if (j < nc) *(short8*)&oc[j] = f8_to_bf8(c + j);
    }
}

// ---- gemm128<EPI>: C[M,N] = A[M,K](lda) @ B[N,K]^T + bias ----------------
template<int EPI>
__global__ __launch_bounds__(256) void gemm128(
    const short* __restrict__ A, int lda,
    const short* __restrict__ B,
    const float* __restrict__ bias,
    void* __restrict__ Cv,
    int N, int K)
{
    __shared__ short As[128 * 64];   // chunk-swizzled: slot(r,c)=G(r, c^(r&7))
    __shared__ short Bs[128 * 64];
    const int tid  = threadIdx.x;
    const int wave = tid >> 6, lane = tid & 63;
    const int quad = lane >> 4, l16 = lane & 15;
    const int wr = wave >> 1, wc = wave & 1;
    const int m0 = blockIdx.y * 128, n0 = blockIdx.x * 128;
    const int lrow   = lane >> 3;
    const int lchunk = (lane & 7) ^ lrow;

    const short* Abase = A + (size_t)(m0 + wave * 32 + lrow) * lda + lchunk * 8;
    const short* Bbase = B + (size_t)(n0 + wave * 32 + lrow) * (size_t)K + lchunk * 8;
    short* AsW = &As[(wave * 32) * 64];
    short* BsW = &Bs[(wave * 32) * 64];

    float4_ acc[4][4] = {};

    for (int k0 = 0; k0 < K; k0 += 64) {
        __syncthreads();
        #pragma unroll
        for (int i = 0; i < 4; i++) {
            gll16(Abase + (size_t)(i * 8) * lda + k0, AsW + (i * 8) * 64);
            gll16(Bbase + (size_t)(i * 8) * K   + k0, BsW + (i * 8) * 64);
        }
        __syncthreads();
        #pragma unroll
        for (int ks = 0; ks < 2; ks++) {
            short8 af[4], bf[4];
            const int ca = ((ks * 4 + quad) ^ (l16 & 7)) * 8;
            #pragma unroll
            for (int t = 0; t < 4; t++) {
                af[t] = *(const short8*)&As[(wr * 64 + t * 16 + l16) * 64 + ca];
                bf[t] = *(const short8*)&Bs[(wc * 64 + t * 16 + l16) * 64 + ca];
            }
            #pragma unroll
            for (int mt = 0; mt < 4; mt++)
                #pragma unroll
                for (int nt = 0; nt < 4; nt++)
                    acc[mt][nt] = __builtin_amdgcn_mfma_f32_16x16x32_bf16(
                        af[mt], bf[nt], acc[mt][nt], 0, 0, 0);
        }
    }

    #pragma unroll
    for (int nt = 0; nt < 4; nt++) {
        const int col = n0 + wc * 64 + nt * 16 + l16;
        const float bv = bias[col];
        if constexpr (EPI == 0) {
            short* C = (short*)Cv;
            const int g = col >> 8;
            #pragma unroll
            for (int mt = 0; mt < 4; mt++) {
                #pragma unroll
                for (int r = 0; r < 4; r++) {
                    int row = m0 + wr * 64 + mt * 16 + quad * 4 + r;
                    bool cov = (col >= 768) || (g == 0) ||
                               (g == 1 && (row & 1) == 1) ||
                               (g == 2 && (row & 3) == 2);
                    C[(size_t)row * N + col] = cov ? f2bf(acc[mt][nt][r] + bv) : (short)0;
                }
            }
        } else {
            float* C = (float*)Cv;
            #pragma unroll
            for (int mt = 0; mt < 4; mt++)
                #pragma unroll
                for (int r = 0; r < 4; r++) {
                    int row = m0 + wr * 64 + mt * 16 + quad * 4 + r;
                    C[(size_t)row * N + col] = acc[mt][nt][r] + bv;
                }
        }
    }
}

// ---- Split-K pipelined dilated attention ----------------------------------
// Grid: 896 = 28 sh * 2 half * 16 qt (XCD-chunk swizzled, qt fastest so the
// 16 q-tiles sharing one (sh,half) K/V stream share one XCD's L2).
// Block 256 = 4 waves; wave w owns q-rows [w*32, w*32+32). 16 K/V tiles of
// 64 keys (half the 2048-key stream), double-buffered, 1 barrier/iter.
// half 0: unnormalized O -> q section, l -> lbuf[0]
// half 1: unnormalized O -> obuf2,     l -> lbuf[1]
__global__ __launch_bounds__(256, 3) void dilated_attn(
    short* __restrict__ qkv, short* __restrict__ obuf2, float* __restrict__ lbuf)
{
    __shared__ short Ks[2 * 64 * 64];   // unpadded, chunk-XOR swizzled (DMA)
    __shared__ short Vt[2 * 64 * LDT];  // Vt[d][key], key cols XOR-swizzled
    __shared__ short Ps[4 * 32 * LDT];  // per-wave P, column-swizzled

    const int bx = blockIdx.x;
    const int L  = (bx & 7) * 112 + (bx >> 3);   // 896 = 8 XCDs * 112
    const int qt   = L & 15;
    const int half = (L >> 4) & 1;
    const int sh   = L >> 5;   // 0..27

    int g, seg, s, rate, off0;
    if (sh < 16)      { g = 0; seg = sh >> 2;        s = 2048; rate = 1; off0 = 0; }
    else if (sh < 24) { g = 1; seg = (sh - 16) >> 2; s = 4096; rate = 2; off0 = 1; }
    else              { g = 2; seg = 0;              s = 8192; rate = 4; off0 = 2; }
    const int head = g * 4 + (sh & 3);

    const int tid  = threadIdx.x;
    const int wave = tid >> 6, lane = tid & 63, quad = lane >> 4, l16 = lane & 15;
    const int srow = tid >> 2, scol = (tid & 3) * 16;   // V-staging map

    // ---- Q frags direct global->regs, pre-scaled by 0.125*log2(e) --------
    short8 aq[2][2];
    #pragma unroll
    for (int rg = 0; rg < 2; rg++) {
        int t = qt * 128 + wave * 32 + rg * 16 + l16;
        size_t pos = (size_t)seg * s + off0 + (size_t)t * rate;
        const short* qsrc = qkv + pos * 2304 + head * 64 + quad * 8;
        #pragma unroll
        for (int ks = 0; ks < 2; ks++) {
            short8 q = *(const short8*)(qsrc + ks * 32);
            #pragma unroll
            for (int e = 0; e < 8; e++) q[e] = f2bf(bf2f(q[e]) * 0.1803368801111244f);
            aq[rg][ks] = q;
        }
    }

    // staging maps (key index offset by half*1024)
    const int krow0  = wave * 8 + (lane >> 3);
    const int kchunk = (lane & 7) ^ (lane >> 3);
    const size_t kstep = (size_t)64 * rate * 2304;
    const size_t kq0 = (size_t)seg * s + off0 + (size_t)(half * 1024) * rate;
    const short* kg0 = qkv + (kq0 + (size_t)krow0 * rate) * 2304
                           + 768 + head * 64 + kchunk * 8;
    const short* kg1 = kg0 + (size_t)32 * rate * 2304;
    const short* vgp = qkv + (kq0 + (size_t)srow * rate) * 2304
                           + 1536 + head * 64 + scol;
    const int kofsA = (wave * 8) * 64;
    const int kofsB = kofsA + 32 * 64;
    const int vswz  = scol;

    // ---- prologue: K tile 0 via DMA into Ks[0]; V tile 0 regs -> Vt[0] ----
    gll16(kg0, &Ks[kofsA]);
    gll16(kg1, &Ks[kofsB]);
    kg0 += kstep; kg1 += kstep;
    short8 va0 = *(const short8*)(vgp);
    short8 va1 = *(const short8*)(vgp + 8);
    vgp += kstep;
    #pragma unroll
    for (int e = 0; e < 8; e++) Vt[(scol + e) * LDT + (srow ^ vswz)] = va0[e];
    #pragma unroll
    for (int e = 0; e < 8; e++) Vt[(scol + 8 + e) * LDT + (srow ^ vswz)] = va1[e];
    va0 = *(const short8*)(vgp);      // V tile 1
    va1 = *(const short8*)(vgp + 8);
    vgp += kstep;

    float lrow[2][4] = {};
    float4_ oacc[2][4] = {};
    short* pw = &Ps[wave * 32 * LDT];
    const int cswap = (lane >> 5) & 1;
    const int pswz  = (l16 & 8) << 1;

    for (int j = 0; j < 16; j++) {
        __syncthreads();   // buf[j&1] staging visible; prev compute done
        if (j < 15) {
            const int nb = (j + 1) & 1;
            gll16(kg0, &Ks[nb * 4096 + kofsA]);
            gll16(kg1, &Ks[nb * 4096 + kofsB]);
            kg0 += kstep; kg1 += kstep;
            short* vt = &Vt[nb * 64 * LDT];
            #pragma unroll
            for (int e = 0; e < 8; e++) vt[(scol + e) * LDT + (srow ^ vswz)] = va0[e];
            #pragma unroll
            for (int e = 0; e < 8; e++) vt[(scol + 8 + e) * LDT + (srow ^ vswz)] = va1[e];
            if (j < 14) {
                va0 = *(const short8*)(vgp);
                va1 = *(const short8*)(vgp + 8);
                vgp += kstep;
            }
        }
        const short* kb = &Ks[(j & 1) * 4096];
        const short* vb = &Vt[(j & 1) * 64 * LDT];

        // S' = (Q*c) K^T : 32 q-rows x 64 keys per wave
        float4_ sacc[2][4] = {};
        __builtin_amdgcn_s_setprio(1);
        #pragma unroll
        for (int ks = 0; ks < 2; ks++) {
            #pragma unroll
            for (int kt = 0; kt < 4; kt++) {
                short8 bk = *(const short8*)&kb[(kt * 16 + l16) * 64
                                                + (((quad + 4 * ks) ^ (l16 & 7)) * 8)];
                #pragma unroll
                for (int rg = 0; rg < 2; rg++)
                    sacc[rg][kt] = __builtin_amdgcn_mfma_f32_16x16x32_bf16(
                        aq[rg][ks], bk, sacc[rg][kt], 0, 0, 0);
            }
        }
        __builtin_amdgcn_s_setprio(0);

        // P = exp2(S'), per-lane partial sums, stash to LDS
        #pragma unroll
        for (int rg = 0; rg < 2; rg++) {
            #pragma unroll
            for (int r = 0; r < 4; r++) {
                float p0 = EXP2(sacc[rg][0][r]), p1 = EXP2(sacc[rg][1][r]);
                float p2 = EXP2(sacc[rg][2][r]), p3 = EXP2(sacc[rg][3][r]);
                short* prow = &pw[(rg * 16 + quad * 4 + r) * LDT + l16];
                prow[(0 ^ cswap) * 16] = f2bf_trunc(p0);
                prow[(1 ^ cswap) * 16] = f2bf_trunc(p1);
                prow[(2 ^ cswap) * 16] = f2bf_trunc(p2);
                prow[(3 ^ cswap) * 16] = f2bf_trunc(p3);
                lrow[rg][r] += (p0 + p1) + (p2 + p3);
            }
        }

        // O += P @ V
        __builtin_amdgcn_s_setprio(1);
        #pragma unroll
        for (int ks = 0; ks < 2; ks++) {
            short8 ap[2];
            #pragma unroll
            for (int rg = 0; rg < 2; rg++)
                ap[rg] = *(const short8*)&pw[(rg * 16 + l16) * LDT
                                             + ((ks * 32 + quad * 8) ^ pswz)];
            #pragma unroll
            for (int nt = 0; nt < 4; nt++) {
                short8 bv = *(const short8*)&vb[(nt * 16 + l16) * LDT
                                                + ((ks * 32 + quad * 8) ^ (nt * 16))];
                #pragma unroll
                for (int rg = 0; rg < 2; rg++)
                    oacc[rg][nt] = __builtin_amdgcn_mfma_f32_16x16x32_bf16(
                        ap[rg], bv, oacc[rg][nt], 0, 0, 0);
            }
        }
        __builtin_amdgcn_s_setprio(0);
    }

    // epilogue: write unnormalized partial O + raw l (combine lives in LN)
    short* obase = half ? obuf2 : qkv;
    const int ostride = half ? 768 : 2304;
    float* lb = lbuf + (size_t)half * 8192 * 12;
    #pragma unroll
    for (int rg = 0; rg < 2; rg++) {
        #pragma unroll
        for (int r = 0; r < 4; r++) {
            float v = lrow[rg][r];
            #pragma unroll
            for (int off = 1; off < 16; off <<= 1) v += __shfl_xor(v, off, 64);
            int qrow = wave * 32 + rg * 16 + quad * 4 + r;
            int t = qt * 128 + qrow;
            size_t pos = (size_t)seg * s + off0 + (size_t)t * rate;
            short* od = obase + pos * ostride + head * 64;
            #pragma unroll
            for (int nt = 0; nt < 4; nt++)
                od[nt * 16 + l16] = f2bf(oacc[rg][nt][r]);
            if (l16 == 0) lb[pos * 12 + head] = v;
        }
    }
}

// ---- Fused LayerNorm + split-K combine, in-place on q section -------------
__global__ __launch_bounds__(256) void ln_inplace(
    short* __restrict__ qkv, const short* __restrict__ obuf2,
    const float* __restrict__ lbuf,
    const float* __restrict__ gamma, const float* __restrict__ beta)
{
    const int row  = blockIdx.x * 4 + (threadIdx.x >> 6);
    const int lane = threadIdx.x & 63;
    short* src = qkv + (size_t)row * 2304;
    const short* src2 = obuf2 + (size_t)row * 768;

    // heads: first 8 elems (idx lane*8..+7) in head lane>>3;
    // last 4 (idx 512+lane*4..+3) in head 8+(lane>>4)
    const int h1 = lane >> 3;          // 0..7  (groups 0,1)
    const int h2 = 8 + (lane >> 4);    // 8..11 (group 2)
    const bool cov1 = (h1 < 4) || ((row & 1) == 1);
    const bool cov2 = ((row & 3) == 2);
    const float li1 = cov1
        ? 1.0f / (lbuf[row * 12 + h1] + lbuf[8192 * 12 + row * 12 + h1]) : 0.0f;
    const float li2 = cov2
        ? 1.0f / (lbuf[row * 12 + h2] + lbuf[8192 * 12 + row * 12 + h2]) : 0.0f;

    short8  a  = *(const short8*)&src[lane * 8];
    short4_ b  = *(const short4_*)&src[512 + lane * 4];
    short8  a2 = *(const short8*)&src2[lane * 8];
    short4_ b2 = *(const short4_*)&src2[512 + lane * 4];
    float v[12];
    #pragma unroll
    for (int e = 0; e < 8; e++)
        v[e] = cov1 ? (bf2f(a[e]) + bf2f(a2[e])) * li1 : 0.0f;
    #pragma unroll
    for (int e = 0; e < 4; e++)
        v[8 + e] = cov2 ? (bf2f(b[e]) + bf2f(b2[e])) * li2 : 0.0f;

    float sum = 0.f, sq = 0.f;
    #pragma unroll
    for (int e = 0; e < 12; e++) { sum += v[e]; sq += v[e] * v[e]; }
    #pragma unroll
    for (int off = 1; off < 64; off <<= 1) {
        sum += __shfl_xor(sum, off, 64);
        sq  += __shfl_xor(sq,  off, 64);
    }
    float mean = sum * (1.0f / 768.0f);
    float var  = sq * (1.0f / 768.0f) - mean * mean;
    float rstd = rsqrtf(var + 1e-5f);

    short8 o8; short4_ o4;
    #pragma unroll
    for (int e = 0; e < 8; e++)
        o8[e] = f2bf((v[e] - mean) * rstd * gamma[lane * 8 + e] + beta[lane * 8 + e]);
    #pragma unroll
    for (int e = 0; e < 4; e++)
        o4[e] = f2bf((v[8 + e] - mean) * rstd * gamma[512 + lane * 4 + e] + beta[512 + lane * 4 + e]);

    *(short8*)&src[lane * 8] = o8;
    *(short4_*)&src[512 + lane * 4] = o4;
}

extern "C" void kernel_launch(void* const* d_in, const int* in_sizes, int n_in,
                              void* d_out, int out_size, void* d_ws, size_t ws_size,
                              hipStream_t stream) {
    const float* x     = (const float*)d_in[0];   // [8192,768]
    const float* w_qkv = (const float*)d_in[1];   // [2304,768]
    const float* b_qkv = (const float*)d_in[2];
    const float* w_out = (const float*)d_in[3];   // [768,768]
    const float* b_out = (const float*)d_in[4];
    const float* gamma = (const float*)d_in[5];
    const float* beta  = (const float*)d_in[6];
    float* out = (float*)d_out;                   // [8192,768] fp32

    const int NX = 8192 * 768, NW1 = 2304 * 768, NW2 = 768 * 768;
    char* ws = (char*)d_ws;
    short* qkv   = (short*)(ws);                          // 37.75 MB
    short* xb    = (short*)(ws + (size_t)8192 * 2304 * 2);
    short* wqkvb = xb + NX;
    short* woutb = wqkvb + NW1;
    float* lbuf  = (float*)(woutb + NW2);                 // 2*8192*12 fp32 = 786 KB
    short* obuf2 = xb;   // xb is dead after gemm1; reuse for split-1 partial O

    // 0) one-shot fp32->bf16 conversions
    cvt3<<<dim3((NX + NW1 + NW2) / (256 * 8)), 256, 0, stream>>>(
        x, NX, w_qkv, NW1, w_out, NW2, xb, wqkvb, woutb);

    // 1) qkv = x @ w_qkv^T + b_qkv (bf16), non-dilated q cells zeroed
    gemm128<0><<<dim3(2304 / 128, 8192 / 128), 256, 0, stream>>>(
        xb, 768, wqkvb, b_qkv, qkv, 2304, 768);

    // 2) split-K attention: partial O (q section / obuf2) + l (lbuf[0/1])
    dilated_attn<<<dim3(28 * 2 * 16), 256, 0, stream>>>(qkv, obuf2, lbuf);

    // 3) LayerNorm + combine (applies 1/(l0+l1) per head) in-place
    ln_inplace<<<dim3(8192 / 4), 256, 0, stream>>>(qkv, obuf2, lbuf, gamma, beta);

    // 4) out = LN(o) @ w_out^T + b_out (fp32 store)
    gemm128<1><<<dim3(768 / 128, 8192 / 128), 256, 0, stream>>>(
        qkv, 2304, woutb, b_out, out, 768, 768);
}

// Round 3
// 213.422 us; speedup vs baseline: 1.0514x; 1.0315x over previous
//
#include <hip/hip_runtime.h>
#include <hip/hip_bf16.h>
#include <cstdint>
#include <cstddef>

// R11: in-register P (T12) attention — kill the P LDS round-trip.
//  R10 post-mortem: all grid variants land 66-74us; the invariant is the P
//  stash (32 ds_write_b16 + 4 ds_read_b128 per 32 q-rows ~ 45% of LDS-unit
//  traffic) plus its write->lgkm->read latency hop every iter. Also found a
//  latent race in split-K (tail half-1 blocks read Q cells half-0 partners
//  overwrite) -> split-K dropped.
//  New attn: 32x32x16 MFMAs with SWAPPED QK (mfma(K,Q)) so each lane holds
//  P[q=lane&31][32 keys] in-register; PV A-frags built with
//  v_cvt_pk_bf16_f32 + v_permlane32_swap_b32 (HK/T12 recipe; operand pattern
//  pk(p[8b],p[8b+1]) / pk(p[8b+4],p[8b+5]) per 16-key slice). Zero P LDS ops,
//  Ps buffer freed (LDS 52->34.8KB), row-sum lane-local (one shfl_xor(32) at
//  epilogue). Grid: race-free 448 = 28 sh x 16 qt (XCD-chunk swizzled),
//  4 waves x 32 q-rows, 32 K/V tiles, 1 barrier/iter, setprio on MFMA.
//  LN: single-source again, coverage predicate kept (lbuf holds raw l).
// GEMMs / cvt3 unchanged (m97-recipe gemm128).

typedef __attribute__((ext_vector_type(8))) short short8;
typedef __attribute__((ext_vector_type(4))) short short4_;
typedef __attribute__((ext_vector_type(4))) float float4_;
typedef __attribute__((ext_vector_type(16))) float floatx16;
typedef __attribute__((ext_vector_type(4))) int int4_;

#if __has_builtin(__builtin_amdgcn_exp2f)
#define EXP2(x) __builtin_amdgcn_exp2f(x)
#else
#define EXP2(x) exp2f(x)
#endif

__device__ __forceinline__ float bf2f(short s) {
    unsigned int u = ((unsigned int)(unsigned short)s) << 16;
    float f;
    __builtin_memcpy(&f, &u, 4);
    return f;
}
__device__ __forceinline__ short f2bf(float f) {
    unsigned int u;
    __builtin_memcpy(&u, &f, 4);
    u += 0x7fffu + ((u >> 16) & 1u);   // round-to-nearest-even
    return (short)(u >> 16);
}
__device__ __forceinline__ short8 f8_to_bf8(const float* __restrict__ p) {
    float4_ a = *(const float4_*)(p);
    float4_ b = *(const float4_*)(p + 4);
    short8 r;
    r[0] = f2bf(a[0]); r[1] = f2bf(a[1]); r[2] = f2bf(a[2]); r[3] = f2bf(a[3]);
    r[4] = f2bf(b[0]); r[5] = f2bf(b[1]); r[6] = f2bf(b[2]); r[7] = f2bf(b[3]);
    return r;
}
__device__ __forceinline__ void gll16(const short* g, short* l) {
    __builtin_amdgcn_global_load_lds(
        (const __attribute__((address_space(1))) unsigned int*)g,
        (__attribute__((address_space(3))) unsigned int*)l, 16, 0, 0);
}
// pack two f32 -> one u32 of 2 bf16 (lo = first arg)
__device__ __forceinline__ int cvtpk(float lo, float hi) {
    int r;
    asm("v_cvt_pk_bf16_f32 %0, %1, %2" : "=v"(r) : "v"(lo), "v"(hi));
    return r;
}

#define LDT 72

// ---- cvt3: fp32->bf16 for x / w_qkv / w_out -------------------------------
__global__ __launch_bounds__(256) void cvt3(
    const float* __restrict__ a, int na, const float* __restrict__ b, int nb,
    const float* __restrict__ c, int nc,
    short* __restrict__ oa, short* __restrict__ ob, short* __restrict__ oc)
{
    int i = (blockIdx.x * 256 + threadIdx.x) * 8;
    if (i < na) {
        *(short8*)&oa[i] = f8_to_bf8(a + i);
    } else if (i < na + nb) {
        int j = i - na;
        *(short8*)&ob[j] = f8_to_bf8(b + j);
    } else {
        int j = i - na - nb;
        if (j < nc) *(short8*)&oc[j] = f8_to_bf8(c + j);
    }
}

// ---- gemm128<EPI>: C[M,N] = A[M,K](lda) @ B[N,K]^T + bias ----------------
template<int EPI>
__global__ __launch_bounds__(256) void gemm128(
    const short* __restrict__ A, int lda,
    const short* __restrict__ B,
    const float* __restrict__ bias,
    void* __restrict__ Cv,
    int N, int K)
{
    __shared__ short As[128 * 64];   // chunk-swizzled: slot(r,c)=G(r, c^(r&7))
    __shared__ short Bs[128 * 64];
    const int tid  = threadIdx.x;
    const int wave = tid >> 6, lane = tid & 63;
    const int quad = lane >> 4, l16 = lane & 15;
    const int wr = wave >> 1, wc = wave & 1;
    const int m0 = blockIdx.y * 128, n0 = blockIdx.x * 128;
    const int lrow   = lane >> 3;
    const int lchunk = (lane & 7) ^ lrow;

    const short* Abase = A + (size_t)(m0 + wave * 32 + lrow) * lda + lchunk * 8;
    const short* Bbase = B + (size_t)(n0 + wave * 32 + lrow) * (size_t)K + lchunk * 8;
    short* AsW = &As[(wave * 32) * 64];
    short* BsW = &Bs[(wave * 32) * 64];

    float4_ acc[4][4] = {};

    for (int k0 = 0; k0 < K; k0 += 64) {
        __syncthreads();
        #pragma unroll
        for (int i = 0; i < 4; i++) {
            gll16(Abase + (size_t)(i * 8) * lda + k0, AsW + (i * 8) * 64);
            gll16(Bbase + (size_t)(i * 8) * K   + k0, BsW + (i * 8) * 64);
        }
        __syncthreads();
        #pragma unroll
        for (int ks = 0; ks < 2; ks++) {
            short8 af[4], bf[4];
            const int ca = ((ks * 4 + quad) ^ (l16 & 7)) * 8;
            #pragma unroll
            for (int t = 0; t < 4; t++) {
                af[t] = *(const short8*)&As[(wr * 64 + t * 16 + l16) * 64 + ca];
                bf[t] = *(const short8*)&Bs[(wc * 64 + t * 16 + l16) * 64 + ca];
            }
            #pragma unroll
            for (int mt = 0; mt < 4; mt++)
                #pragma unroll
                for (int nt = 0; nt < 4; nt++)
                    acc[mt][nt] = __builtin_amdgcn_mfma_f32_16x16x32_bf16(
                        af[mt], bf[nt], acc[mt][nt], 0, 0, 0);
        }
    }

    #pragma unroll
    for (int nt = 0; nt < 4; nt++) {
        const int col = n0 + wc * 64 + nt * 16 + l16;
        const float bv = bias[col];
        if constexpr (EPI == 0) {
            short* C = (short*)Cv;
            const int g = col >> 8;
            #pragma unroll
            for (int mt = 0; mt < 4; mt++) {
                #pragma unroll
                for (int r = 0; r < 4; r++) {
                    int row = m0 + wr * 64 + mt * 16 + quad * 4 + r;
                    bool cov = (col >= 768) || (g == 0) ||
                               (g == 1 && (row & 1) == 1) ||
                               (g == 2 && (row & 3) == 2);
                    C[(size_t)row * N + col] = cov ? f2bf(acc[mt][nt][r] + bv) : (short)0;
                }
            }
        } else {
            float* C = (float*)Cv;
            #pragma unroll
            for (int mt = 0; mt < 4; mt++)
                #pragma unroll
                for (int r = 0; r < 4; r++) {
                    int row = m0 + wr * 64 + mt * 16 + quad * 4 + r;
                    C[(size_t)row * N + col] = acc[mt][nt][r] + bv;
                }
        }
    }
}

// ---- In-register-P dilated attention --------------------------------------
// Grid: 448 = 28 sh * 16 qt (XCD-chunk swizzled). Block 256 = 4 waves; wave
// w owns q-rows [w*32, w*32+32). 32 K/V tiles of 64 keys, double-buffered,
// 1 barrier/iter. Swapped QK (mfma(K,Q), 32x32x16): lane (h=lane>>5,
// l32=lane&31) holds P[q=l32][key = t*32 + 4h + (reg&3) + 8*(reg>>2)].
// PV A-frag per 16-key slice kt: lane needs P[q=l32][kt*16 + h*8 + e] ->
// built in-register via cvt_pk + permlane32_swap (no P LDS traffic).
// Writes UNNORMALIZED O into the q section + raw l into lbuf[pos*12+head].
__global__ __launch_bounds__(256, 3) void dilated_attn(
    short* __restrict__ qkv, float* __restrict__ lbuf)
{
    __shared__ short Ks[2 * 64 * 64];   // K[key][d], chunk-XOR swizzled (DMA)
    __shared__ short Vt[2 * 64 * LDT];  // Vt[d][key], key cols XOR-swizzled

    const int bx = blockIdx.x;
    const int L  = (bx & 7) * 56 + (bx >> 3);   // 448 = 8 XCDs * 56
    const int qt = L & 15;
    const int sh = L >> 4;   // 0..27

    int g, seg, s, rate, off0;
    if (sh < 16)      { g = 0; seg = sh >> 2;        s = 2048; rate = 1; off0 = 0; }
    else if (sh < 24) { g = 1; seg = (sh - 16) >> 2; s = 4096; rate = 2; off0 = 1; }
    else              { g = 2; seg = 0;              s = 8192; rate = 4; off0 = 2; }
    const int head = g * 4 + (sh & 3);

    const int tid  = threadIdx.x;
    const int wave = tid >> 6, lane = tid & 63;
    const int h = lane >> 5, l32 = lane & 31;
    const int srow = tid >> 2, scol = (tid & 3) * 16;   // V-staging map

    // ---- Q frags (B-operand of swapped QK): lane (h,l32) holds
    // Q[q = qt*128+wave*32+l32][kt*16 + h*8 + e], pre-scaled 0.125*log2(e).
    const size_t bpos = (size_t)seg * s + off0
                      + (size_t)(qt * 128 + wave * 32) * rate;
    short8 aq[4];
    {
        const short* qsrc = qkv + (bpos + (size_t)l32 * rate) * 2304
                                + head * 64 + h * 8;
        #pragma unroll
        for (int kt = 0; kt < 4; kt++) {
            short8 q = *(const short8*)(qsrc + kt * 16);
            #pragma unroll
            for (int e = 0; e < 8; e++) q[e] = f2bf(bf2f(q[e]) * 0.1803368801111244f);
            aq[kt] = q;
        }
    }

    // staging maps
    const int krow0  = wave * 8 + (lane >> 3);
    const int kchunk = (lane & 7) ^ (lane >> 3);
    const size_t kstep = (size_t)64 * rate * 2304;
    const short* kg0 = qkv + ((size_t)seg * s + off0 + (size_t)krow0 * rate) * 2304
                           + 768 + head * 64 + kchunk * 8;
    const short* kg1 = kg0 + (size_t)32 * rate * 2304;
    const short* vgp = qkv + ((size_t)seg * s + off0 + (size_t)srow * rate) * 2304
                           + 1536 + head * 64 + scol;
    const int kofsA = (wave * 8) * 64;
    const int kofsB = kofsA + 32 * 64;
    const int vswz  = scol;

    // ---- prologue: K tile 0 via DMA into Ks[0]; V tile 0 regs -> Vt[0] ----
    gll16(kg0, &Ks[kofsA]);
    gll16(kg1, &Ks[kofsB]);
    kg0 += kstep; kg1 += kstep;
    short8 va0 = *(const short8*)(vgp);
    short8 va1 = *(const short8*)(vgp + 8);
    vgp += kstep;
    #pragma unroll
    for (int e = 0; e < 8; e++) Vt[(scol + e) * LDT + (srow ^ vswz)] = va0[e];
    #pragma unroll
    for (int e = 0; e < 8; e++) Vt[(scol + 8 + e) * LDT + (srow ^ vswz)] = va1[e];
    va0 = *(const short8*)(vgp);      // V tile 1
    va1 = *(const short8*)(vgp + 8);
    vgp += kstep;

    float lsum = 0.f;
    floatx16 oacc[2] = {};

    for (int j = 0; j < 32; j++) {
        __syncthreads();   // buf[j&1] staging visible; prev compute done
        if (j < 31) {
            const int nb = (j + 1) & 1;
            gll16(kg0, &Ks[nb * 4096 + kofsA]);
            gll16(kg1, &Ks[nb * 4096 + kofsB]);
            kg0 += kstep; kg1 += kstep;
            short* vt = &Vt[nb * 64 * LDT];
            #pragma unroll
            for (int e = 0; e < 8; e++) vt[(scol + e) * LDT + (srow ^ vswz)] = va0[e];
            #pragma unroll
            for (int e = 0; e < 8; e++) vt[(scol + 8 + e) * LDT + (srow ^ vswz)] = va1[e];
            if (j < 30) {
                va0 = *(const short8*)(vgp);
                va1 = *(const short8*)(vgp + 8);
                vgp += kstep;
            }
        }
        const short* kb = &Ks[(j & 1) * 4096];
        const short* vb = &Vt[(j & 1) * 64 * LDT];

        // S'^T = K (Q*c)^T : sacc[t] covers keys [t*32, t*32+32) x 32 q-rows
        floatx16 sacc[2] = {};
        __builtin_amdgcn_s_setprio(1);
        #pragma unroll
        for (int kt = 0; kt < 4; kt++) {
            #pragma unroll
            for (int t = 0; t < 2; t++) {
                short8 ak = *(const short8*)&kb[(t * 32 + l32) * 64
                                                + (((kt * 2 + h) ^ (l32 & 7)) * 8)];
                sacc[t] = __builtin_amdgcn_mfma_f32_32x32x16_bf16(
                    ak, aq[kt], sacc[t], 0, 0, 0);
            }
        }
        __builtin_amdgcn_s_setprio(0);

        // P = exp2(S'), lane-local partial row sum
        #pragma unroll
        for (int e = 0; e < 16; e++) {
            float pa_ = EXP2(sacc[0][e]);
            float pb_ = EXP2(sacc[1][e]);
            sacc[0][e] = pa_; sacc[1][e] = pb_;
            lsum += pa_ + pb_;
        }

        // Build PV A-frags in-register: pa[kt] = P[q=l32][kt*16 + h*8 + e]
        short8 pa[4];
        #pragma unroll
        for (int kt = 0; kt < 4; kt++) {
            const int t = kt >> 1, b = (kt & 1) * 8;
            int A1 = cvtpk(sacc[t][b + 0], sacc[t][b + 1]);
            int A2 = cvtpk(sacc[t][b + 2], sacc[t][b + 3]);
            int B1 = cvtpk(sacc[t][b + 4], sacc[t][b + 5]);
            int B2 = cvtpk(sacc[t][b + 6], sacc[t][b + 7]);
            // swap A.hi(32 lanes) <-> B.lo: A becomes word(e0,e1) for all
            // lanes, B becomes word(e4,e5); same for A2/B2 -> (e2,e3),(e6,e7)
            asm volatile("v_permlane32_swap_b32 %0, %1" : "+v"(A1), "+v"(B1));
            asm volatile("v_permlane32_swap_b32 %0, %1" : "+v"(A2), "+v"(B2));
            int4_ w; w[0] = A1; w[1] = A2; w[2] = B1; w[3] = B2;
            __builtin_memcpy(&pa[kt], &w, 16);
        }

        // O += P @ V  (B-frag from Vt: V[kt*16 + h*8 + e][d = dt*32 + l32])
        __builtin_amdgcn_s_setprio(1);
        #pragma unroll
        for (int kt = 0; kt < 4; kt++) {
            #pragma unroll
            for (int dt = 0; dt < 2; dt++) {
                const int d = dt * 32 + l32;
                short8 bv = *(const short8*)&vb[d * LDT
                                                + ((kt ^ ((d >> 4) & 3)) * 16 + h * 8)];
                oacc[dt] = __builtin_amdgcn_mfma_f32_32x32x16_bf16(
                    pa[kt], bv, oacc[dt], 0, 0, 0);
            }
        }
        __builtin_amdgcn_s_setprio(0);
    }

    // epilogue: write unnormalized O into q section, raw l into lbuf.
    // oacc[dt][reg] = O[q_local = 4h + (reg&3) + 8*(reg>>2)][d = dt*32+l32]
    {
        float lt = lsum + __shfl_xor(lsum, 32, 64);
        #pragma unroll
        for (int m = 0; m < 4; m++) {
            #pragma unroll
            for (int r = 0; r < 4; r++) {
                const int ql = 4 * h + r + 8 * m;
                short* od = qkv + (bpos + (size_t)ql * rate) * 2304 + head * 64;
                od[l32]      = f2bf(oacc[0][m * 4 + r]);
                od[32 + l32] = f2bf(oacc[1][m * 4 + r]);
            }
        }
        if (lane < 32)
            lbuf[(bpos + (size_t)l32 * rate) * 12 + head] = lt;
    }
}

// ---- Fused LayerNorm: apply 1/l per head, stats, gamma/beta, in-place -----
__global__ __launch_bounds__(256) void ln_inplace(
    short* __restrict__ qkv, const float* __restrict__ lbuf,
    const float* __restrict__ gamma, const float* __restrict__ beta)
{
    const int row  = blockIdx.x * 4 + (threadIdx.x >> 6);
    const int lane = threadIdx.x & 63;
    short* src = qkv + (size_t)row * 2304;

    // heads: first 8 elems (idx lane*8..+7) in head lane>>3;
    // last 4 (idx 512+lane*4..+3) in head 8+(lane>>4)
    const int h1 = lane >> 3;          // 0..7  (groups 0,1)
    const int h2 = 8 + (lane >> 4);    // 8..11 (group 2)
    const bool cov1 = (h1 < 4) || ((row & 1) == 1);
    const bool cov2 = ((row & 3) == 2);
    const float li1 = cov1 ? 1.0f / lbuf[row * 12 + h1] : 0.0f;
    const float li2 = cov2 ? 1.0f / lbuf[row * 12 + h2] : 0.0f;

    short8  a = *(const short8*)&src[lane * 8];
    short4_ b = *(const short4_*)&src[512 + lane * 4];
    float v[12];
    #pragma unroll
    for (int e = 0; e < 8; e++) v[e] = bf2f(a[e]) * li1;
    #pragma unroll
    for (int e = 0; e < 4; e++) v[8 + e] = bf2f(b[e]) * li2;

    float sum = 0.f, sq = 0.f;
    #pragma unroll
    for (int e = 0; e < 12; e++) { sum += v[e]; sq += v[e] * v[e]; }
    #pragma unroll
    for (int off = 1; off < 64; off <<= 1) {
        sum += __shfl_xor(sum, off, 64);
        sq  += __shfl_xor(sq,  off, 64);
    }
    float mean = sum * (1.0f / 768.0f);
    float var  = sq * (1.0f / 768.0f) - mean * mean;
    float rstd = rsqrtf(var + 1e-5f);

    short8 o8; short4_ o4;
    #pragma unroll
    for (int e = 0; e < 8; e++)
        o8[e] = f2bf((v[e] - mean) * rstd * gamma[lane * 8 + e] + beta[lane * 8 + e]);
    #pragma unroll
    for (int e = 0; e < 4; e++)
        o4[e] = f2bf((v[8 + e] - mean) * rstd * gamma[512 + lane * 4 + e] + beta[512 + lane * 4 + e]);

    *(short8*)&src[lane * 8] = o8;
    *(short4_*)&src[512 + lane * 4] = o4;
}

extern "C" void kernel_launch(void* const* d_in, const int* in_sizes, int n_in,
                              void* d_out, int out_size, void* d_ws, size_t ws_size,
                              hipStream_t stream) {
    const float* x     = (const float*)d_in[0];   // [8192,768]
    const float* w_qkv = (const float*)d_in[1];   // [2304,768]
    const float* b_qkv = (const float*)d_in[2];
    const float* w_out = (const float*)d_in[3];   // [768,768]
    const float* b_out = (const float*)d_in[4];
    const float* gamma = (const float*)d_in[5];
    const float* beta  = (const float*)d_in[6];
    float* out = (float*)d_out;                   // [8192,768] fp32

    const int NX = 8192 * 768, NW1 = 2304 * 768, NW2 = 768 * 768;
    char* ws = (char*)d_ws;
    short* qkv   = (short*)(ws);                          // 37.75 MB
    short* xb    = (short*)(ws + (size_t)8192 * 2304 * 2);
    short* wqkvb = xb + NX;
    short* woutb = wqkvb + NW1;
    float* lbuf  = (float*)(woutb + NW2);                 // 8192*12 fp32 = 393 KB

    // 0) one-shot fp32->bf16 conversions
    cvt3<<<dim3((NX + NW1 + NW2) / (256 * 8)), 256, 0, stream>>>(
        x, NX, w_qkv, NW1, w_out, NW2, xb, wqkvb, woutb);

    // 1) qkv = x @ w_qkv^T + b_qkv (bf16), non-dilated q cells zeroed
    gemm128<0><<<dim3(2304 / 128, 8192 / 128), 256, 0, stream>>>(
        xb, 768, wqkvb, b_qkv, qkv, 2304, 768);

    // 2) in-register-P attention: unnormalized O into q section + l to lbuf
    dilated_attn<<<dim3(28 * 16), 256, 0, stream>>>(qkv, lbuf);

    // 3) LayerNorm (applies 1/l per head) in-place on q section
    ln_inplace<<<dim3(8192 / 4), 256, 0, stream>>>(qkv, lbuf, gamma, beta);

    // 4) out = LN(o) @ w_out^T + b_out (fp32 store)
    gemm128<1><<<dim3(768 / 128, 8192 / 128), 256, 0, stream>>>(
        qkv, 2304, woutb, b_out, out, 768, 768);
}

// Round 4
// 207.714 us; speedup vs baseline: 1.0803x; 1.0275x over previous
//
#include <hip/hip_runtime.h>
#include <hip/hip_bf16.h>
#include <cstdint>
#include <cstddef>

// R12: race-free split-K on top of in-register-P (T12) attention.
//  R11 post-mortem: attn 53us, occupancy 15% (448 blocks = 1.75 blk/CU);
//  per-iter chain (barrier -> DMA drain -> QK mfma -> 32x exp2 -> cvtpk/
//  permlane -> PV mfma) ~1k cyc with <2 waves/SIMD to cover it. Pure TLP
//  deficit. R10's split-K failure causes are both gone now: LDS is 34.8KB
//  (4 blk/CU -> 896 blocks fit in ONE scheduling round) and the Q-read/
//  O-write race is fixed by writing BOTH halves' partial O to scratch
//  (obuf1 = dead xb, obuf2 = new region; q-section read-only during attn).
//  ln_inplace combines (O0+O1)/(l0+l1) from scratch and writes the full
//  normalized row into the q-section for gemm2 (coverage predicates mask
//  garbage in uncovered scratch cells). 16 iters/block, launch_bounds(256,4).
// GEMMs / cvt3 unchanged (m97-recipe gemm128).

typedef __attribute__((ext_vector_type(8))) short short8;
typedef __attribute__((ext_vector_type(4))) short short4_;
typedef __attribute__((ext_vector_type(4))) float float4_;
typedef __attribute__((ext_vector_type(16))) float floatx16;
typedef __attribute__((ext_vector_type(4))) int int4_;

#if __has_builtin(__builtin_amdgcn_exp2f)
#define EXP2(x) __builtin_amdgcn_exp2f(x)
#else
#define EXP2(x) exp2f(x)
#endif

__device__ __forceinline__ float bf2f(short s) {
    unsigned int u = ((unsigned int)(unsigned short)s) << 16;
    float f;
    __builtin_memcpy(&f, &u, 4);
    return f;
}
__device__ __forceinline__ short f2bf(float f) {
    unsigned int u;
    __builtin_memcpy(&u, &f, 4);
    u += 0x7fffu + ((u >> 16) & 1u);   // round-to-nearest-even
    return (short)(u >> 16);
}
__device__ __forceinline__ short8 f8_to_bf8(const float* __restrict__ p) {
    float4_ a = *(const float4_*)(p);
    float4_ b = *(const float4_*)(p + 4);
    short8 r;
    r[0] = f2bf(a[0]); r[1] = f2bf(a[1]); r[2] = f2bf(a[2]); r[3] = f2bf(a[3]);
    r[4] = f2bf(b[0]); r[5] = f2bf(b[1]); r[6] = f2bf(b[2]); r[7] = f2bf(b[3]);
    return r;
}
__device__ __forceinline__ void gll16(const short* g, short* l) {
    __builtin_amdgcn_global_load_lds(
        (const __attribute__((address_space(1))) unsigned int*)g,
        (__attribute__((address_space(3))) unsigned int*)l, 16, 0, 0);
}
// pack two f32 -> one u32 of 2 bf16 (lo = first arg)
__device__ __forceinline__ int cvtpk(float lo, float hi) {
    int r;
    asm("v_cvt_pk_bf16_f32 %0, %1, %2" : "=v"(r) : "v"(lo), "v"(hi));
    return r;
}

#define LDT 72

// ---- cvt3: fp32->bf16 for x / w_qkv / w_out -------------------------------
__global__ __launch_bounds__(256) void cvt3(
    const float* __restrict__ a, int na, const float* __restrict__ b, int nb,
    const float* __restrict__ c, int nc,
    short* __restrict__ oa, short* __restrict__ ob, short* __restrict__ oc)
{
    int i = (blockIdx.x * 256 + threadIdx.x) * 8;
    if (i < na) {
        *(short8*)&oa[i] = f8_to_bf8(a + i);
    } else if (i < na + nb) {
        int j = i - na;
        *(short8*)&ob[j] = f8_to_bf8(b + j);
    } else {
        int j = i - na - nb;
        if (j < nc) *(short8*)&oc[j] = f8_to_bf8(c + j);
    }
}

// ---- gemm128<EPI>: C[M,N] = A[M,K](lda) @ B[N,K]^T + bias ----------------
template<int EPI>
__global__ __launch_bounds__(256) void gemm128(
    const short* __restrict__ A, int lda,
    const short* __restrict__ B,
    const float* __restrict__ bias,
    void* __restrict__ Cv,
    int N, int K)
{
    __shared__ short As[128 * 64];   // chunk-swizzled: slot(r,c)=G(r, c^(r&7))
    __shared__ short Bs[128 * 64];
    const int tid  = threadIdx.x;
    const int wave = tid >> 6, lane = tid & 63;
    const int quad = lane >> 4, l16 = lane & 15;
    const int wr = wave >> 1, wc = wave & 1;
    const int m0 = blockIdx.y * 128, n0 = blockIdx.x * 128;
    const int lrow   = lane >> 3;
    const int lchunk = (lane & 7) ^ lrow;

    const short* Abase = A + (size_t)(m0 + wave * 32 + lrow) * lda + lchunk * 8;
    const short* Bbase = B + (size_t)(n0 + wave * 32 + lrow) * (size_t)K + lchunk * 8;
    short* AsW = &As[(wave * 32) * 64];
    short* BsW = &Bs[(wave * 32) * 64];

    float4_ acc[4][4] = {};

    for (int k0 = 0; k0 < K; k0 += 64) {
        __syncthreads();
        #pragma unroll
        for (int i = 0; i < 4; i++) {
            gll16(Abase + (size_t)(i * 8) * lda + k0, AsW + (i * 8) * 64);
            gll16(Bbase + (size_t)(i * 8) * K   + k0, BsW + (i * 8) * 64);
        }
        __syncthreads();
        #pragma unroll
        for (int ks = 0; ks < 2; ks++) {
            short8 af[4], bf[4];
            const int ca = ((ks * 4 + quad) ^ (l16 & 7)) * 8;
            #pragma unroll
            for (int t = 0; t < 4; t++) {
                af[t] = *(const short8*)&As[(wr * 64 + t * 16 + l16) * 64 + ca];
                bf[t] = *(const short8*)&Bs[(wc * 64 + t * 16 + l16) * 64 + ca];
            }
            #pragma unroll
            for (int mt = 0; mt < 4; mt++)
                #pragma unroll
                for (int nt = 0; nt < 4; nt++)
                    acc[mt][nt] = __builtin_amdgcn_mfma_f32_16x16x32_bf16(
                        af[mt], bf[nt], acc[mt][nt], 0, 0, 0);
        }
    }

    #pragma unroll
    for (int nt = 0; nt < 4; nt++) {
        const int col = n0 + wc * 64 + nt * 16 + l16;
        const float bv = bias[col];
        if constexpr (EPI == 0) {
            short* C = (short*)Cv;
            const int g = col >> 8;
            #pragma unroll
            for (int mt = 0; mt < 4; mt++) {
                #pragma unroll
                for (int r = 0; r < 4; r++) {
                    int row = m0 + wr * 64 + mt * 16 + quad * 4 + r;
                    bool cov = (col >= 768) || (g == 0) ||
                               (g == 1 && (row & 1) == 1) ||
                               (g == 2 && (row & 3) == 2);
                    C[(size_t)row * N + col] = cov ? f2bf(acc[mt][nt][r] + bv) : (short)0;
                }
            }
        } else {
            float* C = (float*)Cv;
            #pragma unroll
            for (int mt = 0; mt < 4; mt++)
                #pragma unroll
                for (int r = 0; r < 4; r++) {
                    int row = m0 + wr * 64 + mt * 16 + quad * 4 + r;
                    C[(size_t)row * N + col] = acc[mt][nt][r] + bv;
                }
        }
    }
}

// ---- Split-K in-register-P dilated attention ------------------------------
// Grid: 896 = 28 sh * 2 half * 16 qt (XCD-chunk swizzled, qt fastest).
// Block 256 = 4 waves; wave w owns q-rows [w*32, w*32+32). 16 K/V tiles of
// 64 keys per block (key half-stream), double-buffered, 1 barrier/iter.
// Swapped QK (mfma(K,Q), 32x32x16): lane (h=lane>>5, l32=lane&31) holds
// P[q=l32][32 keys]; PV A-frags built in-register via cvt_pk + permlane32.
// Partial O (unnormalized, bf16) -> obuf[half], raw l -> lbuf[half].
// q-section is READ-ONLY here (no split-K race).
__global__ __launch_bounds__(256, 4) void dilated_attn(
    const short* __restrict__ qkv, short* __restrict__ obuf1,
    short* __restrict__ obuf2, float* __restrict__ lbuf)
{
    __shared__ short Ks[2 * 64 * 64];   // K[key][d], chunk-XOR swizzled (DMA)
    __shared__ short Vt[2 * 64 * LDT];  // Vt[d][key], key cols XOR-swizzled

    const int bx = blockIdx.x;
    const int L  = (bx & 7) * 112 + (bx >> 3);   // 896 = 8 XCDs * 112
    const int qt   = L & 15;
    const int half = (L >> 4) & 1;
    const int sh   = L >> 5;   // 0..27

    int g, seg, s, rate, off0;
    if (sh < 16)      { g = 0; seg = sh >> 2;        s = 2048; rate = 1; off0 = 0; }
    else if (sh < 24) { g = 1; seg = (sh - 16) >> 2; s = 4096; rate = 2; off0 = 1; }
    else              { g = 2; seg = 0;              s = 8192; rate = 4; off0 = 2; }
    const int head = g * 4 + (sh & 3);

    const int tid  = threadIdx.x;
    const int wave = tid >> 6, lane = tid & 63;
    const int h = lane >> 5, l32 = lane & 31;
    const int srow = tid >> 2, scol = (tid & 3) * 16;   // V-staging map

    // ---- Q frags (B-operand of swapped QK): lane (h,l32) holds
    // Q[q = qt*128+wave*32+l32][kt*16 + h*8 + e], pre-scaled 0.125*log2(e).
    const size_t bpos = (size_t)seg * s + off0
                      + (size_t)(qt * 128 + wave * 32) * rate;
    short8 aq[4];
    {
        const short* qsrc = qkv + (bpos + (size_t)l32 * rate) * 2304
                                + head * 64 + h * 8;
        #pragma unroll
        for (int kt = 0; kt < 4; kt++) {
            short8 q = *(const short8*)(qsrc + kt * 16);
            #pragma unroll
            for (int e = 0; e < 8; e++) q[e] = f2bf(bf2f(q[e]) * 0.1803368801111244f);
            aq[kt] = q;
        }
    }

    // staging maps (key index offset by half*1024 dilated positions)
    const int krow0  = wave * 8 + (lane >> 3);
    const int kchunk = (lane & 7) ^ (lane >> 3);
    const size_t kstep = (size_t)64 * rate * 2304;
    const size_t kq0 = (size_t)seg * s + off0 + (size_t)(half * 1024) * rate;
    const short* kg0 = qkv + (kq0 + (size_t)krow0 * rate) * 2304
                           + 768 + head * 64 + kchunk * 8;
    const short* kg1 = kg0 + (size_t)32 * rate * 2304;
    const short* vgp = qkv + (kq0 + (size_t)srow * rate) * 2304
                           + 1536 + head * 64 + scol;
    const int kofsA = (wave * 8) * 64;
    const int kofsB = kofsA + 32 * 64;
    const int vswz  = scol;

    // ---- prologue: K tile 0 via DMA into Ks[0]; V tile 0 regs -> Vt[0] ----
    gll16(kg0, &Ks[kofsA]);
    gll16(kg1, &Ks[kofsB]);
    kg0 += kstep; kg1 += kstep;
    short8 va0 = *(const short8*)(vgp);
    short8 va1 = *(const short8*)(vgp + 8);
    vgp += kstep;
    #pragma unroll
    for (int e = 0; e < 8; e++) Vt[(scol + e) * LDT + (srow ^ vswz)] = va0[e];
    #pragma unroll
    for (int e = 0; e < 8; e++) Vt[(scol + 8 + e) * LDT + (srow ^ vswz)] = va1[e];
    va0 = *(const short8*)(vgp);      // V tile 1
    va1 = *(const short8*)(vgp + 8);
    vgp += kstep;

    float lsum = 0.f;
    floatx16 oacc[2] = {};

    for (int j = 0; j < 16; j++) {
        __syncthreads();   // buf[j&1] staging visible; prev compute done
        if (j < 15) {
            const int nb = (j + 1) & 1;
            gll16(kg0, &Ks[nb * 4096 + kofsA]);
            gll16(kg1, &Ks[nb * 4096 + kofsB]);
            kg0 += kstep; kg1 += kstep;
            short* vt = &Vt[nb * 64 * LDT];
            #pragma unroll
            for (int e = 0; e < 8; e++) vt[(scol + e) * LDT + (srow ^ vswz)] = va0[e];
            #pragma unroll
            for (int e = 0; e < 8; e++) vt[(scol + 8 + e) * LDT + (srow ^ vswz)] = va1[e];
            if (j < 14) {
                va0 = *(const short8*)(vgp);
                va1 = *(const short8*)(vgp + 8);
                vgp += kstep;
            }
        }
        const short* kb = &Ks[(j & 1) * 4096];
        const short* vb = &Vt[(j & 1) * 64 * LDT];

        // S'^T = K (Q*c)^T : sacc[t] covers keys [t*32, t*32+32) x 32 q-rows
        floatx16 sacc[2] = {};
        __builtin_amdgcn_s_setprio(1);
        #pragma unroll
        for (int kt = 0; kt < 4; kt++) {
            #pragma unroll
            for (int t = 0; t < 2; t++) {
                short8 ak = *(const short8*)&kb[(t * 32 + l32) * 64
                                                + (((kt * 2 + h) ^ (l32 & 7)) * 8)];
                sacc[t] = __builtin_amdgcn_mfma_f32_32x32x16_bf16(
                    ak, aq[kt], sacc[t], 0, 0, 0);
            }
        }
        __builtin_amdgcn_s_setprio(0);

        // P = exp2(S'), lane-local partial row sum
        #pragma unroll
        for (int e = 0; e < 16; e++) {
            float pa_ = EXP2(sacc[0][e]);
            float pb_ = EXP2(sacc[1][e]);
            sacc[0][e] = pa_; sacc[1][e] = pb_;
            lsum += pa_ + pb_;
        }

        // Build PV A-frags in-register: pa[kt] = P[q=l32][kt*16 + h*8 + e]
        short8 pa[4];
        #pragma unroll
        for (int kt = 0; kt < 4; kt++) {
            const int t = kt >> 1, b = (kt & 1) * 8;
            int A1 = cvtpk(sacc[t][b + 0], sacc[t][b + 1]);
            int A2 = cvtpk(sacc[t][b + 2], sacc[t][b + 3]);
            int B1 = cvtpk(sacc[t][b + 4], sacc[t][b + 5]);
            int B2 = cvtpk(sacc[t][b + 6], sacc[t][b + 7]);
            // swap A.hi(32 lanes) <-> B.lo: A becomes word(e0,e1) for all
            // lanes, B becomes word(e4,e5); same for A2/B2 -> (e2,e3),(e6,e7)
            asm volatile("v_permlane32_swap_b32 %0, %1" : "+v"(A1), "+v"(B1));
            asm volatile("v_permlane32_swap_b32 %0, %1" : "+v"(A2), "+v"(B2));
            int4_ w; w[0] = A1; w[1] = A2; w[2] = B1; w[3] = B2;
            __builtin_memcpy(&pa[kt], &w, 16);
        }

        // O += P @ V  (B-frag from Vt: V[kt*16 + h*8 + e][d = dt*32 + l32])
        __builtin_amdgcn_s_setprio(1);
        #pragma unroll
        for (int kt = 0; kt < 4; kt++) {
            #pragma unroll
            for (int dt = 0; dt < 2; dt++) {
                const int d = dt * 32 + l32;
                short8 bv = *(const short8*)&vb[d * LDT
                                                + ((kt ^ ((d >> 4) & 3)) * 16 + h * 8)];
                oacc[dt] = __builtin_amdgcn_mfma_f32_32x32x16_bf16(
                    pa[kt], bv, oacc[dt], 0, 0, 0);
            }
        }
        __builtin_amdgcn_s_setprio(0);
    }

    // epilogue: partial O (unnormalized) -> obuf[half], raw l -> lbuf[half].
    // oacc[dt][reg] = O[q_local = 4h + (reg&3) + 8*(reg>>2)][d = dt*32+l32]
    {
        short* obase = half ? obuf2 : obuf1;
        float* lb = lbuf + (size_t)half * 8192 * 12;
        float lt = lsum + __shfl_xor(lsum, 32, 64);
        #pragma unroll
        for (int m = 0; m < 4; m++) {
            #pragma unroll
            for (int r = 0; r < 4; r++) {
                const int ql = 4 * h + r + 8 * m;
                short* od = obase + (bpos + (size_t)ql * rate) * 768 + head * 64;
                od[l32]      = f2bf(oacc[0][m * 4 + r]);
                od[32 + l32] = f2bf(oacc[1][m * 4 + r]);
            }
        }
        if (lane < 32)
            lb[(bpos + (size_t)l32 * rate) * 12 + head] = lt;
    }
}

// ---- Fused LayerNorm + split-K combine: obuf1+obuf2 -> q section ----------
__global__ __launch_bounds__(256) void ln_inplace(
    short* __restrict__ qkv, const short* __restrict__ obuf1,
    const short* __restrict__ obuf2, const float* __restrict__ lbuf,
    const float* __restrict__ gamma, const float* __restrict__ beta)
{
    const int row  = blockIdx.x * 4 + (threadIdx.x >> 6);
    const int lane = threadIdx.x & 63;
    const short* s1 = obuf1 + (size_t)row * 768;
    const short* s2 = obuf2 + (size_t)row * 768;
    short* dst = qkv + (size_t)row * 2304;

    // heads: first 8 elems (idx lane*8..+7) in head lane>>3;
    // last 4 (idx 512+lane*4..+3) in head 8+(lane>>4)
    const int h1 = lane >> 3;          // 0..7  (groups 0,1)
    const int h2 = 8 + (lane >> 4);    // 8..11 (group 2)
    const bool cov1 = (h1 < 4) || ((row & 1) == 1);
    const bool cov2 = ((row & 3) == 2);
    const float li1 = cov1
        ? 1.0f / (lbuf[row * 12 + h1] + lbuf[8192 * 12 + row * 12 + h1]) : 0.0f;
    const float li2 = cov2
        ? 1.0f / (lbuf[row * 12 + h2] + lbuf[8192 * 12 + row * 12 + h2]) : 0.0f;

    short8  a  = *(const short8*)&s1[lane * 8];
    short4_ b  = *(const short4_*)&s1[512 + lane * 4];
    short8  a2 = *(const short8*)&s2[lane * 8];
    short4_ b2 = *(const short4_*)&s2[512 + lane * 4];
    float v[12];
    #pragma unroll
    for (int e = 0; e < 8; e++)
        v[e] = cov1 ? (bf2f(a[e]) + bf2f(a2[e])) * li1 : 0.0f;
    #pragma unroll
    for (int e = 0; e < 4; e++)
        v[8 + e] = cov2 ? (bf2f(b[e]) + bf2f(b2[e])) * li2 : 0.0f;

    float sum = 0.f, sq = 0.f;
    #pragma unroll
    for (int e = 0; e < 12; e++) { sum += v[e]; sq += v[e] * v[e]; }
    #pragma unroll
    for (int off = 1; off < 64; off <<= 1) {
        sum += __shfl_xor(sum, off, 64);
        sq  += __shfl_xor(sq,  off, 64);
    }
    float mean = sum * (1.0f / 768.0f);
    float var  = sq * (1.0f / 768.0f) - mean * mean;
    float rstd = rsqrtf(var + 1e-5f);

    short8 o8; short4_ o4;
    #pragma unroll
    for (int e = 0; e < 8; e++)
        o8[e] = f2bf((v[e] - mean) * rstd * gamma[lane * 8 + e] + beta[lane * 8 + e]);
    #pragma unroll
    for (int e = 0; e < 4; e++)
        o4[e] = f2bf((v[8 + e] - mean) * rstd * gamma[512 + lane * 4 + e] + beta[512 + lane * 4 + e]);

    *(short8*)&dst[lane * 8] = o8;
    *(short4_*)&dst[512 + lane * 4] = o4;
}

extern "C" void kernel_launch(void* const* d_in, const int* in_sizes, int n_in,
                              void* d_out, int out_size, void* d_ws, size_t ws_size,
                              hipStream_t stream) {
    const float* x     = (const float*)d_in[0];   // [8192,768]
    const float* w_qkv = (const float*)d_in[1];   // [2304,768]
    const float* b_qkv = (const float*)d_in[2];
    const float* w_out = (const float*)d_in[3];   // [768,768]
    const float* b_out = (const float*)d_in[4];
    const float* gamma = (const float*)d_in[5];
    const float* beta  = (const float*)d_in[6];
    float* out = (float*)d_out;                   // [8192,768] fp32

    const int NX = 8192 * 768, NW1 = 2304 * 768, NW2 = 768 * 768;
    char* ws = (char*)d_ws;
    short* qkv   = (short*)(ws);                          // 37.75 MB
    short* xb    = (short*)(ws + (size_t)8192 * 2304 * 2);
    short* wqkvb = xb + NX;
    short* woutb = wqkvb + NW1;
    float* lbuf  = (float*)(woutb + NW2);                 // 2*8192*12 fp32
    short* obuf2 = (short*)(lbuf + 2 * 8192 * 12);        // 12.6 MB
    short* obuf1 = xb;   // xb dead after gemm1; reuse for split-0 partial O

    // 0) one-shot fp32->bf16 conversions
    cvt3<<<dim3((NX + NW1 + NW2) / (256 * 8)), 256, 0, stream>>>(
        x, NX, w_qkv, NW1, w_out, NW2, xb, wqkvb, woutb);

    // 1) qkv = x @ w_qkv^T + b_qkv (bf16), non-dilated q cells zeroed
    gemm128<0><<<dim3(2304 / 128, 8192 / 128), 256, 0, stream>>>(
        xb, 768, wqkvb, b_qkv, qkv, 2304, 768);

    // 2) split-K in-reg-P attention: partial O -> obuf1/obuf2, l -> lbuf
    dilated_attn<<<dim3(28 * 2 * 16), 256, 0, stream>>>(qkv, obuf1, obuf2, lbuf);

    // 3) LayerNorm + combine -> q section (full 768 cols written)
    ln_inplace<<<dim3(8192 / 4), 256, 0, stream>>>(
        qkv, obuf1, obuf2, lbuf, gamma, beta);

    // 4) out = LN(o) @ w_out^T + b_out (fp32 store)
    gemm128<1><<<dim3(768 / 128, 8192 / 128), 256, 0, stream>>>(
        qkv, 2304, woutb, b_out, out, 768, 768);
}

// Round 5
// 193.624 us; speedup vs baseline: 1.1589x; 1.0728x over previous
//
#include <hip/hip_runtime.h>
#include <hip/hip_bf16.h>
#include <cstdint>
#include <cstddef>

// R13: dilution-aware QKV GEMM — compute only covered (pos, head) cells.
//  R12 post-mortem: attn off the top-5; gemm<0> (8192x2304x768, 29 GFLOP,
//  50.5us, 574 TF) is now the largest dispatch. But dilated attention only
//  reads QKV at covered cells: group0 (rate1) 100% of positions, group1
//  (rate2) 50%, group2 (rate4) 25% -- for Q, K AND V. 58.3% of the output
//  is consumed; since R12 nothing reads uncovered cells (LN rewrites the
//  full q-section from scratch buffers). So: 3 row-gathered sub-GEMMs in
//  one kernel (gemm_qkv): group g computes rows {off0_g + i*rate_g} x its
//  768 cols (q/k/v sections of heads 4g..4g+3). 16.9 GFLOP (1.72x less).
//  672 blocks = 384+192+96 of the same 128^2 m97-recipe tile; a 128-col
//  block sits inside one 256-col section -> constant B-base per block.
//  XCD swizzle 672 = 8*84, nx fastest (A-panel L2 sharing). Uncovered qkv
//  cells stay garbage (provably unread).
// attn / ln / gemm128<1> / cvt3 unchanged from R12.

typedef __attribute__((ext_vector_type(8))) short short8;
typedef __attribute__((ext_vector_type(4))) short short4_;
typedef __attribute__((ext_vector_type(4))) float float4_;
typedef __attribute__((ext_vector_type(16))) float floatx16;
typedef __attribute__((ext_vector_type(4))) int int4_;

#if __has_builtin(__builtin_amdgcn_exp2f)
#define EXP2(x) __builtin_amdgcn_exp2f(x)
#else
#define EXP2(x) exp2f(x)
#endif

__device__ __forceinline__ float bf2f(short s) {
    unsigned int u = ((unsigned int)(unsigned short)s) << 16;
    float f;
    __builtin_memcpy(&f, &u, 4);
    return f;
}
__device__ __forceinline__ short f2bf(float f) {
    unsigned int u;
    __builtin_memcpy(&u, &f, 4);
    u += 0x7fffu + ((u >> 16) & 1u);   // round-to-nearest-even
    return (short)(u >> 16);
}
__device__ __forceinline__ short8 f8_to_bf8(const float* __restrict__ p) {
    float4_ a = *(const float4_*)(p);
    float4_ b = *(const float4_*)(p + 4);
    short8 r;
    r[0] = f2bf(a[0]); r[1] = f2bf(a[1]); r[2] = f2bf(a[2]); r[3] = f2bf(a[3]);
    r[4] = f2bf(b[0]); r[5] = f2bf(b[1]); r[6] = f2bf(b[2]); r[7] = f2bf(b[3]);
    return r;
}
__device__ __forceinline__ void gll16(const short* g, short* l) {
    __builtin_amdgcn_global_load_lds(
        (const __attribute__((address_space(1))) unsigned int*)g,
        (__attribute__((address_space(3))) unsigned int*)l, 16, 0, 0);
}
// pack two f32 -> one u32 of 2 bf16 (lo = first arg)
__device__ __forceinline__ int cvtpk(float lo, float hi) {
    int r;
    asm("v_cvt_pk_bf16_f32 %0, %1, %2" : "=v"(r) : "v"(lo), "v"(hi));
    return r;
}

#define LDT 72

// ---- cvt3: fp32->bf16 for x / w_qkv / w_out -------------------------------
__global__ __launch_bounds__(256) void cvt3(
    const float* __restrict__ a, int na, const float* __restrict__ b, int nb,
    const float* __restrict__ c, int nc,
    short* __restrict__ oa, short* __restrict__ ob, short* __restrict__ oc)
{
    int i = (blockIdx.x * 256 + threadIdx.x) * 8;
    if (i < na) {
        *(short8*)&oa[i] = f8_to_bf8(a + i);
    } else if (i < na + nb) {
        int j = i - na;
        *(short8*)&ob[j] = f8_to_bf8(b + j);
    } else {
        int j = i - na - nb;
        if (j < nc) *(short8*)&oc[j] = f8_to_bf8(c + j);
    }
}

// ---- gemm_qkv: dilution-aware QKV projection ------------------------------
// qkv[grow, gcol] = x[grow,:] @ w_qkv[gcol,:]^T + b_qkv[gcol], computed only
// for covered cells. 672 blocks: g0 = 384 (rows stride1, heads 0-3),
// g1 = 192 (rows 1+2i, heads 4-7), g2 = 96 (rows 2+4i, heads 8-11).
// Per group: N = 768 local cols -> gcol = sec*768 + g*256 + (nx&1)*128 + c.
__global__ __launch_bounds__(256) void gemm_qkv(
    const short* __restrict__ A,     // xb [8192,768]
    const short* __restrict__ B,     // wqkvb [2304,768]
    const float* __restrict__ bias,  // b_qkv [2304]
    short* __restrict__ C)           // qkv [8192,2304]
{
    __shared__ short As[128 * 64];   // chunk-swizzled: slot(r,c)=G(r, c^(r&7))
    __shared__ short Bs[128 * 64];

    const int bx = blockIdx.x;
    const int L  = (bx & 7) * 84 + (bx >> 3);   // 672 = 8 XCDs * 84
    int g, t, rate, off0;
    if (L < 384)      { g = 0; t = L;       rate = 1; off0 = 0; }
    else if (L < 576) { g = 1; t = L - 384; rate = 2; off0 = 1; }
    else              { g = 2; t = L - 576; rate = 4; off0 = 2; }
    const int nx = t % 6, my = t / 6;           // nx fastest: A-panel shared
    const int ncol0 = (nx >> 1) * 768 + g * 256 + (nx & 1) * 128;
    const int m0 = my * 128;                    // local (gathered) row base

    const int tid  = threadIdx.x;
    const int wave = tid >> 6, lane = tid & 63;
    const int quad = lane >> 4, l16 = lane & 15;
    const int wr = wave >> 1, wc = wave & 1;
    const int lrow   = lane >> 3;
    const int lchunk = (lane & 7) ^ lrow;

    const short* Abase = A + (size_t)(off0 + (m0 + wave * 32 + lrow) * rate) * 768
                           + lchunk * 8;
    const short* Bbase = B + (size_t)(ncol0 + wave * 32 + lrow) * 768 + lchunk * 8;
    short* AsW = &As[(wave * 32) * 64];
    short* BsW = &Bs[(wave * 32) * 64];
    const size_t arowstep = (size_t)8 * rate * 768;

    float4_ acc[4][4] = {};

    for (int k0 = 0; k0 < 768; k0 += 64) {
        __syncthreads();
        #pragma unroll
        for (int i = 0; i < 4; i++) {
            gll16(Abase + (size_t)i * arowstep + k0, AsW + (i * 8) * 64);
            gll16(Bbase + (size_t)(i * 8) * 768 + k0, BsW + (i * 8) * 64);
        }
        __syncthreads();
        #pragma unroll
        for (int ks = 0; ks < 2; ks++) {
            short8 af[4], bf[4];
            const int ca = ((ks * 4 + quad) ^ (l16 & 7)) * 8;
            #pragma unroll
            for (int tt = 0; tt < 4; tt++) {
                af[tt] = *(const short8*)&As[(wr * 64 + tt * 16 + l16) * 64 + ca];
                bf[tt] = *(const short8*)&Bs[(wc * 64 + tt * 16 + l16) * 64 + ca];
            }
            #pragma unroll
            for (int mt = 0; mt < 4; mt++)
                #pragma unroll
                for (int nt = 0; nt < 4; nt++)
                    acc[mt][nt] = __builtin_amdgcn_mfma_f32_16x16x32_bf16(
                        af[mt], bf[nt], acc[mt][nt], 0, 0, 0);
        }
    }

    #pragma unroll
    for (int nt = 0; nt < 4; nt++) {
        const int gcol = ncol0 + wc * 64 + nt * 16 + l16;
        const float bv = bias[gcol];
        #pragma unroll
        for (int mt = 0; mt < 4; mt++) {
            #pragma unroll
            for (int r = 0; r < 4; r++) {
                const int rl = m0 + wr * 64 + mt * 16 + quad * 4 + r;
                const size_t grow = (size_t)off0 + (size_t)rl * rate;
                C[grow * 2304 + gcol] = f2bf(acc[mt][nt][r] + bv);
            }
        }
    }
}

// ---- gemm128<EPI>: C[M,N] = A[M,K](lda) @ B[N,K]^T + bias ----------------
// (only EPI=1 instantiated now: the fp32-output out-projection)
template<int EPI>
__global__ __launch_bounds__(256) void gemm128(
    const short* __restrict__ A, int lda,
    const short* __restrict__ B,
    const float* __restrict__ bias,
    void* __restrict__ Cv,
    int N, int K)
{
    __shared__ short As[128 * 64];
    __shared__ short Bs[128 * 64];
    const int tid  = threadIdx.x;
    const int wave = tid >> 6, lane = tid & 63;
    const int quad = lane >> 4, l16 = lane & 15;
    const int wr = wave >> 1, wc = wave & 1;
    const int m0 = blockIdx.y * 128, n0 = blockIdx.x * 128;
    const int lrow   = lane >> 3;
    const int lchunk = (lane & 7) ^ lrow;

    const short* Abase = A + (size_t)(m0 + wave * 32 + lrow) * lda + lchunk * 8;
    const short* Bbase = B + (size_t)(n0 + wave * 32 + lrow) * (size_t)K + lchunk * 8;
    short* AsW = &As[(wave * 32) * 64];
    short* BsW = &Bs[(wave * 32) * 64];

    float4_ acc[4][4] = {};

    for (int k0 = 0; k0 < K; k0 += 64) {
        __syncthreads();
        #pragma unroll
        for (int i = 0; i < 4; i++) {
            gll16(Abase + (size_t)(i * 8) * lda + k0, AsW + (i * 8) * 64);
            gll16(Bbase + (size_t)(i * 8) * K   + k0, BsW + (i * 8) * 64);
        }
        __syncthreads();
        #pragma unroll
        for (int ks = 0; ks < 2; ks++) {
            short8 af[4], bf[4];
            const int ca = ((ks * 4 + quad) ^ (l16 & 7)) * 8;
            #pragma unroll
            for (int t = 0; t < 4; t++) {
                af[t] = *(const short8*)&As[(wr * 64 + t * 16 + l16) * 64 + ca];
                bf[t] = *(const short8*)&Bs[(wc * 64 + t * 16 + l16) * 64 + ca];
            }
            #pragma unroll
            for (int mt = 0; mt < 4; mt++)
                #pragma unroll
                for (int nt = 0; nt < 4; nt++)
                    acc[mt][nt] = __builtin_amdgcn_mfma_f32_16x16x32_bf16(
                        af[mt], bf[nt], acc[mt][nt], 0, 0, 0);
        }
    }

    #pragma unroll
    for (int nt = 0; nt < 4; nt++) {
        const int col = n0 + wc * 64 + nt * 16 + l16;
        const float bv = bias[col];
        if constexpr (EPI == 0) {
            short* C = (short*)Cv;
            #pragma unroll
            for (int mt = 0; mt < 4; mt++)
                #pragma unroll
                for (int r = 0; r < 4; r++) {
                    int row = m0 + wr * 64 + mt * 16 + quad * 4 + r;
                    C[(size_t)row * N + col] = f2bf(acc[mt][nt][r] + bv);
                }
        } else {
            float* C = (float*)Cv;
            #pragma unroll
            for (int mt = 0; mt < 4; mt++)
                #pragma unroll
                for (int r = 0; r < 4; r++) {
                    int row = m0 + wr * 64 + mt * 16 + quad * 4 + r;
                    C[(size_t)row * N + col] = acc[mt][nt][r] + bv;
                }
        }
    }
}

// ---- Split-K in-register-P dilated attention ------------------------------
// Grid: 896 = 28 sh * 2 half * 16 qt (XCD-chunk swizzled, qt fastest).
// Block 256 = 4 waves; wave w owns q-rows [w*32, w*32+32). 16 K/V tiles of
// 64 keys per block (key half-stream), double-buffered, 1 barrier/iter.
// Swapped QK (mfma(K,Q), 32x32x16): lane (h=lane>>5, l32=lane&31) holds
// P[q=l32][32 keys]; PV A-frags built in-register via cvt_pk + permlane32.
// Partial O (unnormalized, bf16) -> obuf[half], raw l -> lbuf[half].
// q-section is READ-ONLY here (no split-K race).
__global__ __launch_bounds__(256, 4) void dilated_attn(
    const short* __restrict__ qkv, short* __restrict__ obuf1,
    short* __restrict__ obuf2, float* __restrict__ lbuf)
{
    __shared__ short Ks[2 * 64 * 64];   // K[key][d], chunk-XOR swizzled (DMA)
    __shared__ short Vt[2 * 64 * LDT];  // Vt[d][key], key cols XOR-swizzled

    const int bx = blockIdx.x;
    const int L  = (bx & 7) * 112 + (bx >> 3);   // 896 = 8 XCDs * 112
    const int qt   = L & 15;
    const int half = (L >> 4) & 1;
    const int sh   = L >> 5;   // 0..27

    int g, seg, s, rate, off0;
    if (sh < 16)      { g = 0; seg = sh >> 2;        s = 2048; rate = 1; off0 = 0; }
    else if (sh < 24) { g = 1; seg = (sh - 16) >> 2; s = 4096; rate = 2; off0 = 1; }
    else              { g = 2; seg = 0;              s = 8192; rate = 4; off0 = 2; }
    const int head = g * 4 + (sh & 3);

    const int tid  = threadIdx.x;
    const int wave = tid >> 6, lane = tid & 63;
    const int h = lane >> 5, l32 = lane & 31;
    const int srow = tid >> 2, scol = (tid & 3) * 16;   // V-staging map

    // ---- Q frags (B-operand of swapped QK): lane (h,l32) holds
    // Q[q = qt*128+wave*32+l32][kt*16 + h*8 + e], pre-scaled 0.125*log2(e).
    const size_t bpos = (size_t)seg * s + off0
                      + (size_t)(qt * 128 + wave * 32) * rate;
    short8 aq[4];
    {
        const short* qsrc = qkv + (bpos + (size_t)l32 * rate) * 2304
                                + head * 64 + h * 8;
        #pragma unroll
        for (int kt = 0; kt < 4; kt++) {
            short8 q = *(const short8*)(qsrc + kt * 16);
            #pragma unroll
            for (int e = 0; e < 8; e++) q[e] = f2bf(bf2f(q[e]) * 0.1803368801111244f);
            aq[kt] = q;
        }
    }

    // staging maps (key index offset by half*1024 dilated positions)
    const int krow0  = wave * 8 + (lane >> 3);
    const int kchunk = (lane & 7) ^ (lane >> 3);
    const size_t kstep = (size_t)64 * rate * 2304;
    const size_t kq0 = (size_t)seg * s + off0 + (size_t)(half * 1024) * rate;
    const short* kg0 = qkv + (kq0 + (size_t)krow0 * rate) * 2304
                           + 768 + head * 64 + kchunk * 8;
    const short* kg1 = kg0 + (size_t)32 * rate * 2304;
    const short* vgp = qkv + (kq0 + (size_t)srow * rate) * 2304
                           + 1536 + head * 64 + scol;
    const int kofsA = (wave * 8) * 64;
    const int kofsB = kofsA + 32 * 64;
    const int vswz  = scol;

    // ---- prologue: K tile 0 via DMA into Ks[0]; V tile 0 regs -> Vt[0] ----
    gll16(kg0, &Ks[kofsA]);
    gll16(kg1, &Ks[kofsB]);
    kg0 += kstep; kg1 += kstep;
    short8 va0 = *(const short8*)(vgp);
    short8 va1 = *(const short8*)(vgp + 8);
    vgp += kstep;
    #pragma unroll
    for (int e = 0; e < 8; e++) Vt[(scol + e) * LDT + (srow ^ vswz)] = va0[e];
    #pragma unroll
    for (int e = 0; e < 8; e++) Vt[(scol + 8 + e) * LDT + (srow ^ vswz)] = va1[e];
    va0 = *(const short8*)(vgp);      // V tile 1
    va1 = *(const short8*)(vgp + 8);
    vgp += kstep;

    float lsum = 0.f;
    floatx16 oacc[2] = {};

    for (int j = 0; j < 16; j++) {
        __syncthreads();   // buf[j&1] staging visible; prev compute done
        if (j < 15) {
            const int nb = (j + 1) & 1;
            gll16(kg0, &Ks[nb * 4096 + kofsA]);
            gll16(kg1, &Ks[nb * 4096 + kofsB]);
            kg0 += kstep; kg1 += kstep;
            short* vt = &Vt[nb * 64 * LDT];
            #pragma unroll
            for (int e = 0; e < 8; e++) vt[(scol + e) * LDT + (srow ^ vswz)] = va0[e];
            #pragma unroll
            for (int e = 0; e < 8; e++) vt[(scol + 8 + e) * LDT + (srow ^ vswz)] = va1[e];
            if (j < 14) {
                va0 = *(const short8*)(vgp);
                va1 = *(const short8*)(vgp + 8);
                vgp += kstep;
            }
        }
        const short* kb = &Ks[(j & 1) * 4096];
        const short* vb = &Vt[(j & 1) * 64 * LDT];

        // S'^T = K (Q*c)^T : sacc[t] covers keys [t*32, t*32+32) x 32 q-rows
        floatx16 sacc[2] = {};
        __builtin_amdgcn_s_setprio(1);
        #pragma unroll
        for (int kt = 0; kt < 4; kt++) {
            #pragma unroll
            for (int t = 0; t < 2; t++) {
                short8 ak = *(const short8*)&kb[(t * 32 + l32) * 64
                                                + (((kt * 2 + h) ^ (l32 & 7)) * 8)];
                sacc[t] = __builtin_amdgcn_mfma_f32_32x32x16_bf16(
                    ak, aq[kt], sacc[t], 0, 0, 0);
            }
        }
        __builtin_amdgcn_s_setprio(0);

        // P = exp2(S'), lane-local partial row sum
        #pragma unroll
        for (int e = 0; e < 16; e++) {
            float pa_ = EXP2(sacc[0][e]);
            float pb_ = EXP2(sacc[1][e]);
            sacc[0][e] = pa_; sacc[1][e] = pb_;
            lsum += pa_ + pb_;
        }

        // Build PV A-frags in-register: pa[kt] = P[q=l32][kt*16 + h*8 + e]
        short8 pa[4];
        #pragma unroll
        for (int kt = 0; kt < 4; kt++) {
            const int t = kt >> 1, b = (kt & 1) * 8;
            int A1 = cvtpk(sacc[t][b + 0], sacc[t][b + 1]);
            int A2 = cvtpk(sacc[t][b + 2], sacc[t][b + 3]);
            int B1 = cvtpk(sacc[t][b + 4], sacc[t][b + 5]);
            int B2 = cvtpk(sacc[t][b + 6], sacc[t][b + 7]);
            // swap A.hi(32 lanes) <-> B.lo: A becomes word(e0,e1) for all
            // lanes, B becomes word(e4,e5); same for A2/B2 -> (e2,e3),(e6,e7)
            asm volatile("v_permlane32_swap_b32 %0, %1" : "+v"(A1), "+v"(B1));
            asm volatile("v_permlane32_swap_b32 %0, %1" : "+v"(A2), "+v"(B2));
            int4_ w; w[0] = A1; w[1] = A2; w[2] = B1; w[3] = B2;
            __builtin_memcpy(&pa[kt], &w, 16);
        }

        // O += P @ V  (B-frag from Vt: V[kt*16 + h*8 + e][d = dt*32 + l32])
        __builtin_amdgcn_s_setprio(1);
        #pragma unroll
        for (int kt = 0; kt < 4; kt++) {
            #pragma unroll
            for (int dt = 0; dt < 2; dt++) {
                const int d = dt * 32 + l32;
                short8 bv = *(const short8*)&vb[d * LDT
                                                + ((kt ^ ((d >> 4) & 3)) * 16 + h * 8)];
                oacc[dt] = __builtin_amdgcn_mfma_f32_32x32x16_bf16(
                    pa[kt], bv, oacc[dt], 0, 0, 0);
            }
        }
        __builtin_amdgcn_s_setprio(0);
    }

    // epilogue: partial O (unnormalized) -> obuf[half], raw l -> lbuf[half].
    // oacc[dt][reg] = O[q_local = 4h + (reg&3) + 8*(reg>>2)][d = dt*32+l32]
    {
        short* obase = half ? obuf2 : obuf1;
        float* lb = lbuf + (size_t)half * 8192 * 12;
        float lt = lsum + __shfl_xor(lsum, 32, 64);
        #pragma unroll
        for (int m = 0; m < 4; m++) {
            #pragma unroll
            for (int r = 0; r < 4; r++) {
                const int ql = 4 * h + r + 8 * m;
                short* od = obase + (bpos + (size_t)ql * rate) * 768 + head * 64;
                od[l32]      = f2bf(oacc[0][m * 4 + r]);
                od[32 + l32] = f2bf(oacc[1][m * 4 + r]);
            }
        }
        if (lane < 32)
            lb[(bpos + (size_t)l32 * rate) * 12 + head] = lt;
    }
}

// ---- Fused LayerNorm + split-K combine: obuf1+obuf2 -> q section ----------
__global__ __launch_bounds__(256) void ln_inplace(
    short* __restrict__ qkv, const short* __restrict__ obuf1,
    const short* __restrict__ obuf2, const float* __restrict__ lbuf,
    const float* __restrict__ gamma, const float* __restrict__ beta)
{
    const int row  = blockIdx.x * 4 + (threadIdx.x >> 6);
    const int lane = threadIdx.x & 63;
    const short* s1 = obuf1 + (size_t)row * 768;
    const short* s2 = obuf2 + (size_t)row * 768;
    short* dst = qkv + (size_t)row * 2304;

    // heads: first 8 elems (idx lane*8..+7) in head lane>>3;
    // last 4 (idx 512+lane*4..+3) in head 8+(lane>>4)
    const int h1 = lane >> 3;          // 0..7  (groups 0,1)
    const int h2 = 8 + (lane >> 4);    // 8..11 (group 2)
    const bool cov1 = (h1 < 4) || ((row & 1) == 1);
    const bool cov2 = ((row & 3) == 2);
    const float li1 = cov1
        ? 1.0f / (lbuf[row * 12 + h1] + lbuf[8192 * 12 + row * 12 + h1]) : 0.0f;
    const float li2 = cov2
        ? 1.0f / (lbuf[row * 12 + h2] + lbuf[8192 * 12 + row * 12 + h2]) : 0.0f;

    short8  a  = *(const short8*)&s1[lane * 8];
    short4_ b  = *(const short4_*)&s1[512 + lane * 4];
    short8  a2 = *(const short8*)&s2[lane * 8];
    short4_ b2 = *(const short4_*)&s2[512 + lane * 4];
    float v[12];
    #pragma unroll
    for (int e = 0; e < 8; e++)
        v[e] = cov1 ? (bf2f(a[e]) + bf2f(a2[e])) * li1 : 0.0f;
    #pragma unroll
    for (int e = 0; e < 4; e++)
        v[8 + e] = cov2 ? (bf2f(b[e]) + bf2f(b2[e])) * li2 : 0.0f;

    float sum = 0.f, sq = 0.f;
    #pragma unroll
    for (int e = 0; e < 12; e++) { sum += v[e]; sq += v[e] * v[e]; }
    #pragma unroll
    for (int off = 1; off < 64; off <<= 1) {
        sum += __shfl_xor(sum, off, 64);
        sq  += __shfl_xor(sq,  off, 64);
    }
    float mean = sum * (1.0f / 768.0f);
    float var  = sq * (1.0f / 768.0f) - mean * mean;
    float rstd = rsqrtf(var + 1e-5f);

    short8 o8; short4_ o4;
    #pragma unroll
    for (int e = 0; e < 8; e++)
        o8[e] = f2bf((v[e] - mean) * rstd * gamma[lane * 8 + e] + beta[lane * 8 + e]);
    #pragma unroll
    for (int e = 0; e < 4; e++)
        o4[e] = f2bf((v[8 + e] - mean) * rstd * gamma[512 + lane * 4 + e] + beta[512 + lane * 4 + e]);

    *(short8*)&dst[lane * 8] = o8;
    *(short4_*)&dst[512 + lane * 4] = o4;
}

extern "C" void kernel_launch(void* const* d_in, const int* in_sizes, int n_in,
                              void* d_out, int out_size, void* d_ws, size_t ws_size,
                              hipStream_t stream) {
    const float* x     = (const float*)d_in[0];   // [8192,768]
    const float* w_qkv = (const float*)d_in[1];   // [2304,768]
    const float* b_qkv = (const float*)d_in[2];
    const float* w_out = (const float*)d_in[3];   // [768,768]
    const float* b_out = (const float*)d_in[4];
    const float* gamma = (const float*)d_in[5];
    const float* beta  = (const float*)d_in[6];
    float* out = (float*)d_out;                   // [8192,768] fp32

    const int NX = 8192 * 768, NW1 = 2304 * 768, NW2 = 768 * 768;
    char* ws = (char*)d_ws;
    short* qkv   = (short*)(ws);                          // 37.75 MB
    short* xb    = (short*)(ws + (size_t)8192 * 2304 * 2);
    short* wqkvb = xb + NX;
    short* woutb = wqkvb + NW1;
    float* lbuf  = (float*)(woutb + NW2);                 // 2*8192*12 fp32
    short* obuf2 = (short*)(lbuf + 2 * 8192 * 12);        // 12.6 MB
    short* obuf1 = xb;   // xb dead after gemm_qkv; reuse for split-0 partial O

    // 0) one-shot fp32->bf16 conversions
    cvt3<<<dim3((NX + NW1 + NW2) / (256 * 8)), 256, 0, stream>>>(
        x, NX, w_qkv, NW1, w_out, NW2, xb, wqkvb, woutb);

    // 1) qkv = x @ w_qkv^T + b_qkv, covered cells only (16.9 GFLOP)
    gemm_qkv<<<dim3(672), 256, 0, stream>>>(xb, wqkvb, b_qkv, qkv);

    // 2) split-K in-reg-P attention: partial O -> obuf1/obuf2, l -> lbuf
    dilated_attn<<<dim3(28 * 2 * 16), 256, 0, stream>>>(qkv, obuf1, obuf2, lbuf);

    // 3) LayerNorm + combine -> q section (full 768 cols written)
    ln_inplace<<<dim3(8192 / 4), 256, 0, stream>>>(
        qkv, obuf1, obuf2, lbuf, gamma, beta);

    // 4) out = LN(o) @ w_out^T + b_out (fp32 store)
    gemm128<1><<<dim3(768 / 128, 8192 / 128), 256, 0, stream>>>(
        qkv, 2304, woutb, b_out, out, 768, 768);
}

// Round 6
// 190.494 us; speedup vs baseline: 1.1779x; 1.0164x over previous
//
#include <hip/hip_runtime.h>
#include <hip/hip_bf16.h>
#include <cstdint>
#include <cstddef>

// R14: counted-vmcnt attention pipeline (T4) — kill the barrier drain.
//  R13 post-mortem: attn steady 50us = 7.5k cyc/iter vs ~650 cyc/iter of
//  issue work; no pipe saturated (HBM 7.6%, MfmaUtil 24, VALUBusy 37,
//  conflicts 64cyc/wave-iter). Classic 2-phase structural stall (m233:
//  stage+vmcnt+barrier ~72%): __syncthreads drains vmcnt(0) every iter, so
//  K-DMA and V-prefetch never span a phase. Fix (m218, +38-73% measured on
//  GEMM): raw s_barrier + counted s_waitcnt vmcnt(2) — K_{j+1} DMA and
//  va_{j+2} prefetch stay in flight across the compute phase AND the next
//  barrier. Count audit: steady outstanding = {K_{j+1}(2), va_{j+2}(2)};
//  top-of-iter vmcnt(2) retires K_j; post-issue vmcnt(2) retires va_{j+1};
//  lgkmcnt(0) before barrier publishes V ds_writes; last iter peeled with
//  vmcnt(0). Race audit: barrier at iter-j top ensures all waves finished
//  reading buf[(j+1)&1] before DMA/V-writes retarget it.
// gemm_qkv / gemm128<1> / ln / cvt3 unchanged from R13.

typedef __attribute__((ext_vector_type(8))) short short8;
typedef __attribute__((ext_vector_type(4))) short short4_;
typedef __attribute__((ext_vector_type(4))) float float4_;
typedef __attribute__((ext_vector_type(16))) float floatx16;
typedef __attribute__((ext_vector_type(4))) int int4_;

#if __has_builtin(__builtin_amdgcn_exp2f)
#define EXP2(x) __builtin_amdgcn_exp2f(x)
#else
#define EXP2(x) exp2f(x)
#endif

__device__ __forceinline__ float bf2f(short s) {
    unsigned int u = ((unsigned int)(unsigned short)s) << 16;
    float f;
    __builtin_memcpy(&f, &u, 4);
    return f;
}
__device__ __forceinline__ short f2bf(float f) {
    unsigned int u;
    __builtin_memcpy(&u, &f, 4);
    u += 0x7fffu + ((u >> 16) & 1u);   // round-to-nearest-even
    return (short)(u >> 16);
}
__device__ __forceinline__ short8 f8_to_bf8(const float* __restrict__ p) {
    float4_ a = *(const float4_*)(p);
    float4_ b = *(const float4_*)(p + 4);
    short8 r;
    r[0] = f2bf(a[0]); r[1] = f2bf(a[1]); r[2] = f2bf(a[2]); r[3] = f2bf(a[3]);
    r[4] = f2bf(b[0]); r[5] = f2bf(b[1]); r[6] = f2bf(b[2]); r[7] = f2bf(b[3]);
    return r;
}
__device__ __forceinline__ void gll16(const short* g, short* l) {
    __builtin_amdgcn_global_load_lds(
        (const __attribute__((address_space(1))) unsigned int*)g,
        (__attribute__((address_space(3))) unsigned int*)l, 16, 0, 0);
}
// pack two f32 -> one u32 of 2 bf16 (lo = first arg)
__device__ __forceinline__ int cvtpk(float lo, float hi) {
    int r;
    asm("v_cvt_pk_bf16_f32 %0, %1, %2" : "=v"(r) : "v"(lo), "v"(hi));
    return r;
}

#define LDT 72

// ---- cvt3: fp32->bf16 for x / w_qkv / w_out -------------------------------
__global__ __launch_bounds__(256) void cvt3(
    const float* __restrict__ a, int na, const float* __restrict__ b, int nb,
    const float* __restrict__ c, int nc,
    short* __restrict__ oa, short* __restrict__ ob, short* __restrict__ oc)
{
    int i = (blockIdx.x * 256 + threadIdx.x) * 8;
    if (i < na) {
        *(short8*)&oa[i] = f8_to_bf8(a + i);
    } else if (i < na + nb) {
        int j = i - na;
        *(short8*)&ob[j] = f8_to_bf8(b + j);
    } else {
        int j = i - na - nb;
        if (j < nc) *(short8*)&oc[j] = f8_to_bf8(c + j);
    }
}

// ---- gemm_qkv: dilution-aware QKV projection ------------------------------
// qkv[grow, gcol] = x[grow,:] @ w_qkv[gcol,:]^T + b_qkv[gcol], computed only
// for covered cells. 672 blocks: g0 = 384 (rows stride1, heads 0-3),
// g1 = 192 (rows 1+2i, heads 4-7), g2 = 96 (rows 2+4i, heads 8-11).
__global__ __launch_bounds__(256) void gemm_qkv(
    const short* __restrict__ A,     // xb [8192,768]
    const short* __restrict__ B,     // wqkvb [2304,768]
    const float* __restrict__ bias,  // b_qkv [2304]
    short* __restrict__ C)           // qkv [8192,2304]
{
    __shared__ short As[128 * 64];   // chunk-swizzled: slot(r,c)=G(r, c^(r&7))
    __shared__ short Bs[128 * 64];

    const int bx = blockIdx.x;
    const int L  = (bx & 7) * 84 + (bx >> 3);   // 672 = 8 XCDs * 84
    int g, t, rate, off0;
    if (L < 384)      { g = 0; t = L;       rate = 1; off0 = 0; }
    else if (L < 576) { g = 1; t = L - 384; rate = 2; off0 = 1; }
    else              { g = 2; t = L - 576; rate = 4; off0 = 2; }
    const int nx = t % 6, my = t / 6;           // nx fastest: A-panel shared
    const int ncol0 = (nx >> 1) * 768 + g * 256 + (nx & 1) * 128;
    const int m0 = my * 128;                    // local (gathered) row base

    const int tid  = threadIdx.x;
    const int wave = tid >> 6, lane = tid & 63;
    const int quad = lane >> 4, l16 = lane & 15;
    const int wr = wave >> 1, wc = wave & 1;
    const int lrow   = lane >> 3;
    const int lchunk = (lane & 7) ^ lrow;

    const short* Abase = A + (size_t)(off0 + (m0 + wave * 32 + lrow) * rate) * 768
                           + lchunk * 8;
    const short* Bbase = B + (size_t)(ncol0 + wave * 32 + lrow) * 768 + lchunk * 8;
    short* AsW = &As[(wave * 32) * 64];
    short* BsW = &Bs[(wave * 32) * 64];
    const size_t arowstep = (size_t)8 * rate * 768;

    float4_ acc[4][4] = {};

    for (int k0 = 0; k0 < 768; k0 += 64) {
        __syncthreads();
        #pragma unroll
        for (int i = 0; i < 4; i++) {
            gll16(Abase + (size_t)i * arowstep + k0, AsW + (i * 8) * 64);
            gll16(Bbase + (size_t)(i * 8) * 768 + k0, BsW + (i * 8) * 64);
        }
        __syncthreads();
        #pragma unroll
        for (int ks = 0; ks < 2; ks++) {
            short8 af[4], bf[4];
            const int ca = ((ks * 4 + quad) ^ (l16 & 7)) * 8;
            #pragma unroll
            for (int tt = 0; tt < 4; tt++) {
                af[tt] = *(const short8*)&As[(wr * 64 + tt * 16 + l16) * 64 + ca];
                bf[tt] = *(const short8*)&Bs[(wc * 64 + tt * 16 + l16) * 64 + ca];
            }
            #pragma unroll
            for (int mt = 0; mt < 4; mt++)
                #pragma unroll
                for (int nt = 0; nt < 4; nt++)
                    acc[mt][nt] = __builtin_amdgcn_mfma_f32_16x16x32_bf16(
                        af[mt], bf[nt], acc[mt][nt], 0, 0, 0);
        }
    }

    #pragma unroll
    for (int nt = 0; nt < 4; nt++) {
        const int gcol = ncol0 + wc * 64 + nt * 16 + l16;
        const float bv = bias[gcol];
        #pragma unroll
        for (int mt = 0; mt < 4; mt++) {
            #pragma unroll
            for (int r = 0; r < 4; r++) {
                const int rl = m0 + wr * 64 + mt * 16 + quad * 4 + r;
                const size_t grow = (size_t)off0 + (size_t)rl * rate;
                C[grow * 2304 + gcol] = f2bf(acc[mt][nt][r] + bv);
            }
        }
    }
}

// ---- gemm128<EPI>: C[M,N] = A[M,K](lda) @ B[N,K]^T + bias ----------------
template<int EPI>
__global__ __launch_bounds__(256) void gemm128(
    const short* __restrict__ A, int lda,
    const short* __restrict__ B,
    const float* __restrict__ bias,
    void* __restrict__ Cv,
    int N, int K)
{
    __shared__ short As[128 * 64];
    __shared__ short Bs[128 * 64];
    const int tid  = threadIdx.x;
    const int wave = tid >> 6, lane = tid & 63;
    const int quad = lane >> 4, l16 = lane & 15;
    const int wr = wave >> 1, wc = wave & 1;
    const int m0 = blockIdx.y * 128, n0 = blockIdx.x * 128;
    const int lrow   = lane >> 3;
    const int lchunk = (lane & 7) ^ lrow;

    const short* Abase = A + (size_t)(m0 + wave * 32 + lrow) * lda + lchunk * 8;
    const short* Bbase = B + (size_t)(n0 + wave * 32 + lrow) * (size_t)K + lchunk * 8;
    short* AsW = &As[(wave * 32) * 64];
    short* BsW = &Bs[(wave * 32) * 64];

    float4_ acc[4][4] = {};

    for (int k0 = 0; k0 < K; k0 += 64) {
        __syncthreads();
        #pragma unroll
        for (int i = 0; i < 4; i++) {
            gll16(Abase + (size_t)(i * 8) * lda + k0, AsW + (i * 8) * 64);
            gll16(Bbase + (size_t)(i * 8) * K   + k0, BsW + (i * 8) * 64);
        }
        __syncthreads();
        #pragma unroll
        for (int ks = 0; ks < 2; ks++) {
            short8 af[4], bf[4];
            const int ca = ((ks * 4 + quad) ^ (l16 & 7)) * 8;
            #pragma unroll
            for (int t = 0; t < 4; t++) {
                af[t] = *(const short8*)&As[(wr * 64 + t * 16 + l16) * 64 + ca];
                bf[t] = *(const short8*)&Bs[(wc * 64 + t * 16 + l16) * 64 + ca];
            }
            #pragma unroll
            for (int mt = 0; mt < 4; mt++)
                #pragma unroll
                for (int nt = 0; nt < 4; nt++)
                    acc[mt][nt] = __builtin_amdgcn_mfma_f32_16x16x32_bf16(
                        af[mt], bf[nt], acc[mt][nt], 0, 0, 0);
        }
    }

    #pragma unroll
    for (int nt = 0; nt < 4; nt++) {
        const int col = n0 + wc * 64 + nt * 16 + l16;
        const float bv = bias[col];
        if constexpr (EPI == 0) {
            short* C = (short*)Cv;
            #pragma unroll
            for (int mt = 0; mt < 4; mt++)
                #pragma unroll
                for (int r = 0; r < 4; r++) {
                    int row = m0 + wr * 64 + mt * 16 + quad * 4 + r;
                    C[(size_t)row * N + col] = f2bf(acc[mt][nt][r] + bv);
                }
        } else {
            float* C = (float*)Cv;
            #pragma unroll
            for (int mt = 0; mt < 4; mt++)
                #pragma unroll
                for (int r = 0; r < 4; r++) {
                    int row = m0 + wr * 64 + mt * 16 + quad * 4 + r;
                    C[(size_t)row * N + col] = acc[mt][nt][r] + bv;
                }
        }
    }
}

// ---- Split-K in-register-P dilated attention, counted-vmcnt pipeline ------
// Grid: 896 = 28 sh * 2 half * 16 qt (XCD-chunk swizzled, qt fastest).
// Block 256 = 4 waves; wave w owns q-rows [w*32, w*32+32). 16 K/V tiles of
// 64 keys, double-buffered. Raw s_barrier + counted vmcnt: K-DMA and V
// register-prefetch span phases (never drained to 0 mid-loop).
__global__ __launch_bounds__(256, 4) void dilated_attn(
    const short* __restrict__ qkv, short* __restrict__ obuf1,
    short* __restrict__ obuf2, float* __restrict__ lbuf)
{
    __shared__ short Ks[2 * 64 * 64];   // K[key][d], chunk-XOR swizzled (DMA)
    __shared__ short Vt[2 * 64 * LDT];  // Vt[d][key], key cols XOR-swizzled

    const int bx = blockIdx.x;
    const int L  = (bx & 7) * 112 + (bx >> 3);   // 896 = 8 XCDs * 112
    const int qt   = L & 15;
    const int half = (L >> 4) & 1;
    const int sh   = L >> 5;   // 0..27

    int g, seg, s, rate, off0;
    if (sh < 16)      { g = 0; seg = sh >> 2;        s = 2048; rate = 1; off0 = 0; }
    else if (sh < 24) { g = 1; seg = (sh - 16) >> 2; s = 4096; rate = 2; off0 = 1; }
    else              { g = 2; seg = 0;              s = 8192; rate = 4; off0 = 2; }
    const int head = g * 4 + (sh & 3);

    const int tid  = threadIdx.x;
    const int wave = tid >> 6, lane = tid & 63;
    const int h = lane >> 5, l32 = lane & 31;
    const int srow = tid >> 2, scol = (tid & 3) * 16;   // V-staging map

    // ---- Q frags (B-operand of swapped QK): lane (h,l32) holds
    // Q[q = qt*128+wave*32+l32][kt*16 + h*8 + e], pre-scaled 0.125*log2(e).
    const size_t bpos = (size_t)seg * s + off0
                      + (size_t)(qt * 128 + wave * 32) * rate;
    short8 aq[4];
    {
        const short* qsrc = qkv + (bpos + (size_t)l32 * rate) * 2304
                                + head * 64 + h * 8;
        #pragma unroll
        for (int kt = 0; kt < 4; kt++) {
            short8 q = *(const short8*)(qsrc + kt * 16);
            #pragma unroll
            for (int e = 0; e < 8; e++) q[e] = f2bf(bf2f(q[e]) * 0.1803368801111244f);
            aq[kt] = q;
        }
    }

    // staging maps (key index offset by half*1024 dilated positions)
    const int krow0  = wave * 8 + (lane >> 3);
    const int kchunk = (lane & 7) ^ (lane >> 3);
    const size_t kstep = (size_t)64 * rate * 2304;
    const size_t kq0 = (size_t)seg * s + off0 + (size_t)(half * 1024) * rate;
    const short* kg0 = qkv + (kq0 + (size_t)krow0 * rate) * 2304
                           + 768 + head * 64 + kchunk * 8;
    const short* kg1 = kg0 + (size_t)32 * rate * 2304;
    const short* vgp = qkv + (kq0 + (size_t)srow * rate) * 2304
                           + 1536 + head * 64 + scol;
    const int kofsA = (wave * 8) * 64;
    const int kofsB = kofsA + 32 * 64;
    const int vswz  = scol;

    // ---- prologue: K0 DMA into buf0; V0 regs -> buf0; va := V1 ------------
    gll16(kg0, &Ks[kofsA]);
    gll16(kg1, &Ks[kofsB]);
    kg0 += kstep; kg1 += kstep;
    short8 va0 = *(const short8*)(vgp);
    short8 va1 = *(const short8*)(vgp + 8);
    vgp += kstep;
    // compiler inserts counted vmcnt before consuming va0/va1 (drains K0 too)
    #pragma unroll
    for (int e = 0; e < 8; e++) Vt[(scol + e) * LDT + (srow ^ vswz)] = va0[e];
    #pragma unroll
    for (int e = 0; e < 8; e++) Vt[(scol + 8 + e) * LDT + (srow ^ vswz)] = va1[e];
    va0 = *(const short8*)(vgp);      // V tile 1
    va1 = *(const short8*)(vgp + 8);
    vgp += kstep;
    // outstanding entering loop: va_V1(2)

    float lsum = 0.f;
    floatx16 oacc[2] = {};

    auto compute = [&](const short* kb, const short* vb) {
        // S'^T = K (Q*c)^T : sacc[t] covers keys [t*32,t*32+32) x 32 q-rows
        floatx16 sacc[2] = {};
        __builtin_amdgcn_s_setprio(1);
        #pragma unroll
        for (int kt = 0; kt < 4; kt++) {
            #pragma unroll
            for (int t = 0; t < 2; t++) {
                short8 ak = *(const short8*)&kb[(t * 32 + l32) * 64
                                                + (((kt * 2 + h) ^ (l32 & 7)) * 8)];
                sacc[t] = __builtin_amdgcn_mfma_f32_32x32x16_bf16(
                    ak, aq[kt], sacc[t], 0, 0, 0);
            }
        }
        __builtin_amdgcn_s_setprio(0);

        // P = exp2(S'), lane-local partial row sum
        #pragma unroll
        for (int e = 0; e < 16; e++) {
            float pa_ = EXP2(sacc[0][e]);
            float pb_ = EXP2(sacc[1][e]);
            sacc[0][e] = pa_; sacc[1][e] = pb_;
            lsum += pa_ + pb_;
        }

        // PV A-frags in-register: pa[kt] = P[q=l32][kt*16 + h*8 + e]
        short8 pa[4];
        #pragma unroll
        for (int kt = 0; kt < 4; kt++) {
            const int t = kt >> 1, b = (kt & 1) * 8;
            int A1 = cvtpk(sacc[t][b + 0], sacc[t][b + 1]);
            int A2 = cvtpk(sacc[t][b + 2], sacc[t][b + 3]);
            int B1 = cvtpk(sacc[t][b + 4], sacc[t][b + 5]);
            int B2 = cvtpk(sacc[t][b + 6], sacc[t][b + 7]);
            asm volatile("v_permlane32_swap_b32 %0, %1" : "+v"(A1), "+v"(B1));
            asm volatile("v_permlane32_swap_b32 %0, %1" : "+v"(A2), "+v"(B2));
            int4_ w; w[0] = A1; w[1] = A2; w[2] = B1; w[3] = B2;
            __builtin_memcpy(&pa[kt], &w, 16);
        }

        // O += P @ V  (B-frag: V[kt*16 + h*8 + e][d = dt*32 + l32])
        __builtin_amdgcn_s_setprio(1);
        #pragma unroll
        for (int kt = 0; kt < 4; kt++) {
            #pragma unroll
            for (int dt = 0; dt < 2; dt++) {
                const int d = dt * 32 + l32;
                short8 bv = *(const short8*)&vb[d * LDT
                                                + ((kt ^ ((d >> 4) & 3)) * 16 + h * 8)];
                oacc[dt] = __builtin_amdgcn_mfma_f32_32x32x16_bf16(
                    pa[kt], bv, oacc[dt], 0, 0, 0);
            }
        }
        __builtin_amdgcn_s_setprio(0);
    };

    for (int j = 0; j < 15; j++) {
        // K_j DMA landed (2 newest — va_{j+1} — may fly); own ds ops retired
        asm volatile("s_waitcnt vmcnt(2)" ::: "memory");
        asm volatile("s_waitcnt lgkmcnt(0)" ::: "memory");
        __builtin_amdgcn_s_barrier();   // buf[j&1] fully valid for all waves

        const int nb = (j + 1) & 1;
        gll16(kg0, &Ks[nb * 4096 + kofsA]);   // K_{j+1}: flies across phases
        gll16(kg1, &Ks[nb * 4096 + kofsB]);
        kg0 += kstep; kg1 += kstep;
        // wait va_{j+1} only (K_{j+1} stays outstanding)
        asm volatile("s_waitcnt vmcnt(2)" ::: "memory");
        short* vt = &Vt[nb * 64 * LDT];
        #pragma unroll
        for (int e = 0; e < 8; e++) vt[(scol + e) * LDT + (srow ^ vswz)] = va0[e];
        #pragma unroll
        for (int e = 0; e < 8; e++) vt[(scol + 8 + e) * LDT + (srow ^ vswz)] = va1[e];
        if (j < 14) {
            va0 = *(const short8*)(vgp);      // va_{j+2}: flies across phases
            va1 = *(const short8*)(vgp + 8);
            vgp += kstep;
        }
        compute(&Ks[(j & 1) * 4096], &Vt[(j & 1) * 64 * LDT]);
    }
    // last iter (j=15): only K_15(2) outstanding
    asm volatile("s_waitcnt vmcnt(0)" ::: "memory");
    asm volatile("s_waitcnt lgkmcnt(0)" ::: "memory");
    __builtin_amdgcn_s_barrier();
    compute(&Ks[4096], &Vt[64 * LDT]);

    // epilogue: partial O (unnormalized) -> obuf[half], raw l -> lbuf[half].
    // oacc[dt][reg] = O[q_local = 4h + (reg&3) + 8*(reg>>2)][d = dt*32+l32]
    {
        short* obase = half ? obuf2 : obuf1;
        float* lb = lbuf + (size_t)half * 8192 * 12;
        float lt = lsum + __shfl_xor(lsum, 32, 64);
        #pragma unroll
        for (int m = 0; m < 4; m++) {
            #pragma unroll
            for (int r = 0; r < 4; r++) {
                const int ql = 4 * h + r + 8 * m;
                short* od = obase + (bpos + (size_t)ql * rate) * 768 + head * 64;
                od[l32]      = f2bf(oacc[0][m * 4 + r]);
                od[32 + l32] = f2bf(oacc[1][m * 4 + r]);
            }
        }
        if (lane < 32)
            lb[(bpos + (size_t)l32 * rate) * 12 + head] = lt;
    }
}

// ---- Fused LayerNorm + split-K combine: obuf1+obuf2 -> q section ----------
__global__ __launch_bounds__(256) void ln_inplace(
    short* __restrict__ qkv, const short* __restrict__ obuf1,
    const short* __restrict__ obuf2, const float* __restrict__ lbuf,
    const float* __restrict__ gamma, const float* __restrict__ beta)
{
    const int row  = blockIdx.x * 4 + (threadIdx.x >> 6);
    const int lane = threadIdx.x & 63;
    const short* s1 = obuf1 + (size_t)row * 768;
    const short* s2 = obuf2 + (size_t)row * 768;
    short* dst = qkv + (size_t)row * 2304;

    // heads: first 8 elems (idx lane*8..+7) in head lane>>3;
    // last 4 (idx 512+lane*4..+3) in head 8+(lane>>4)
    const int h1 = lane >> 3;          // 0..7  (groups 0,1)
    const int h2 = 8 + (lane >> 4);    // 8..11 (group 2)
    const bool cov1 = (h1 < 4) || ((row & 1) == 1);
    const bool cov2 = ((row & 3) == 2);
    const float li1 = cov1
        ? 1.0f / (lbuf[row * 12 + h1] + lbuf[8192 * 12 + row * 12 + h1]) : 0.0f;
    const float li2 = cov2
        ? 1.0f / (lbuf[row * 12 + h2] + lbuf[8192 * 12 + row * 12 + h2]) : 0.0f;

    short8  a  = *(const short8*)&s1[lane * 8];
    short4_ b  = *(const short4_*)&s1[512 + lane * 4];
    short8  a2 = *(const short8*)&s2[lane * 8];
    short4_ b2 = *(const short4_*)&s2[512 + lane * 4];
    float v[12];
    #pragma unroll
    for (int e = 0; e < 8; e++)
        v[e] = cov1 ? (bf2f(a[e]) + bf2f(a2[e])) * li1 : 0.0f;
    #pragma unroll
    for (int e = 0; e < 4; e++)
        v[8 + e] = cov2 ? (bf2f(b[e]) + bf2f(b2[e])) * li2 : 0.0f;

    float sum = 0.f, sq = 0.f;
    #pragma unroll
    for (int e = 0; e < 12; e++) { sum += v[e]; sq += v[e] * v[e]; }
    #pragma unroll
    for (int off = 1; off < 64; off <<= 1) {
        sum += __shfl_xor(sum, off, 64);
        sq  += __shfl_xor(sq,  off, 64);
    }
    float mean = sum * (1.0f / 768.0f);
    float var  = sq * (1.0f / 768.0f) - mean * mean;
    float rstd = rsqrtf(var + 1e-5f);

    short8 o8; short4_ o4;
    #pragma unroll
    for (int e = 0; e < 8; e++)
        o8[e] = f2bf((v[e] - mean) * rstd * gamma[lane * 8 + e] + beta[lane * 8 + e]);
    #pragma unroll
    for (int e = 0; e < 4; e++)
        o4[e] = f2bf((v[8 + e] - mean) * rstd * gamma[512 + lane * 4 + e] + beta[512 + lane * 4 + e]);

    *(short8*)&dst[lane * 8] = o8;
    *(short4_*)&dst[512 + lane * 4] = o4;
}

extern "C" void kernel_launch(void* const* d_in, const int* in_sizes, int n_in,
                              void* d_out, int out_size, void* d_ws, size_t ws_size,
                              hipStream_t stream) {
    const float* x     = (const float*)d_in[0];   // [8192,768]
    const float* w_qkv = (const float*)d_in[1];   // [2304,768]
    const float* b_qkv = (const float*)d_in[2];
    const float* w_out = (const float*)d_in[3];   // [768,768]
    const float* b_out = (const float*)d_in[4];
    const float* gamma = (const float*)d_in[5];
    const float* beta  = (const float*)d_in[6];
    float* out = (float*)d_out;                   // [8192,768] fp32

    const int NX = 8192 * 768, NW1 = 2304 * 768, NW2 = 768 * 768;
    char* ws = (char*)d_ws;
    short* qkv   = (short*)(ws);                          // 37.75 MB
    short* xb    = (short*)(ws + (size_t)8192 * 2304 * 2);
    short* wqkvb = xb + NX;
    short* woutb = wqkvb + NW1;
    float* lbuf  = (float*)(woutb + NW2);                 // 2*8192*12 fp32
    short* obuf2 = (short*)(lbuf + 2 * 8192 * 12);        // 12.6 MB
    short* obuf1 = xb;   // xb dead after gemm_qkv; reuse for split-0 partial O

    // 0) one-shot fp32->bf16 conversions
    cvt3<<<dim3((NX + NW1 + NW2) / (256 * 8)), 256, 0, stream>>>(
        x, NX, w_qkv, NW1, w_out, NW2, xb, wqkvb, woutb);

    // 1) qkv = x @ w_qkv^T + b_qkv, covered cells only (16.9 GFLOP)
    gemm_qkv<<<dim3(672), 256, 0, stream>>>(xb, wqkvb, b_qkv, qkv);

    // 2) split-K in-reg-P attention: partial O -> obuf1/obuf2, l -> lbuf
    dilated_attn<<<dim3(28 * 2 * 16), 256, 0, stream>>>(qkv, obuf1, obuf2, lbuf);

    // 3) LayerNorm + combine -> q section (full 768 cols written)
    ln_inplace<<<dim3(8192 / 4), 256, 0, stream>>>(
        qkv, obuf1, obuf2, lbuf, gamma, beta);

    // 4) out = LN(o) @ w_out^T + b_out (fp32 store)
    gemm128<1><<<dim3(768 / 128, 8192 / 128), 256, 0, stream>>>(
        qkv, 2304, woutb, b_out, out, 768, 768);
}

// Round 8
// 183.412 us; speedup vs baseline: 1.2234x; 1.0386x over previous
//
#include <hip/hip_runtime.h>
#include <hip/hip_bf16.h>
#include <cstdint>
#include <cstddef>

// R15b: resubmit of R15 (container-level infra failure, kernel audit clean).
//  GEMM occupancy round — 128x64 tiles for both projections.
//  R14 post-mortem: counted-vmcnt was nearly null (50->47.7us) — attn is at
//  its structural floor (~45us): 896 blocks co-resident, LDS-unit ~66% with
//  4x wave replication of K/V tile reads; removing replication needs 64-row
//  waves -> 64 VGPR O-state -> occupancy halves (VGPR wall = LDS wall).
//  Budget audit: gemm_qkv ~33us at 2.6 blk/CU (672 blocks), gemm_out ~28us
//  at 1.5 blk/CU (384 blocks) — both occupancy-starved, not efficiency-
//  starved. Retile both to 128x64 (LDS 24KB -> 6 blk/CU cap):
//   gemm_qkv: 1344 blocks (768+384+192), XCD swizzle 8x168, 5.25 blk/CU.
//   gemm_out: 768 blocks (12 nx x 64 my), XCD swizzle 8x96, 3 blk/CU.
//  Per-wave: 32x64 out, acc[2][4]; staging 4+2 gll16/thread/kstep.
// attn / ln / cvt3 unchanged from R14.

typedef __attribute__((ext_vector_type(8))) short short8;
typedef __attribute__((ext_vector_type(4))) short short4_;
typedef __attribute__((ext_vector_type(4))) float float4_;
typedef __attribute__((ext_vector_type(16))) float floatx16;
typedef __attribute__((ext_vector_type(4))) int int4_;

#if __has_builtin(__builtin_amdgcn_exp2f)
#define EXP2(x) __builtin_amdgcn_exp2f(x)
#else
#define EXP2(x) exp2f(x)
#endif

__device__ __forceinline__ float bf2f(short s) {
    unsigned int u = ((unsigned int)(unsigned short)s) << 16;
    float f;
    __builtin_memcpy(&f, &u, 4);
    return f;
}
__device__ __forceinline__ short f2bf(float f) {
    unsigned int u;
    __builtin_memcpy(&u, &f, 4);
    u += 0x7fffu + ((u >> 16) & 1u);   // round-to-nearest-even
    return (short)(u >> 16);
}
__device__ __forceinline__ short8 f8_to_bf8(const float* __restrict__ p) {
    float4_ a = *(const float4_*)(p);
    float4_ b = *(const float4_*)(p + 4);
    short8 r;
    r[0] = f2bf(a[0]); r[1] = f2bf(a[1]); r[2] = f2bf(a[2]); r[3] = f2bf(a[3]);
    r[4] = f2bf(b[0]); r[5] = f2bf(b[1]); r[6] = f2bf(b[2]); r[7] = f2bf(b[3]);
    return r;
}
__device__ __forceinline__ void gll16(const short* g, short* l) {
    __builtin_amdgcn_global_load_lds(
        (const __attribute__((address_space(1))) unsigned int*)g,
        (__attribute__((address_space(3))) unsigned int*)l, 16, 0, 0);
}
// pack two f32 -> one u32 of 2 bf16 (lo = first arg)
__device__ __forceinline__ int cvtpk(float lo, float hi) {
    int r;
    asm("v_cvt_pk_bf16_f32 %0, %1, %2" : "=v"(r) : "v"(lo), "v"(hi));
    return r;
}

#define LDT 72

// ---- cvt3: fp32->bf16 for x / w_qkv / w_out -------------------------------
__global__ __launch_bounds__(256) void cvt3(
    const float* __restrict__ a, int na, const float* __restrict__ b, int nb,
    const float* __restrict__ c, int nc,
    short* __restrict__ oa, short* __restrict__ ob, short* __restrict__ oc)
{
    int i = (blockIdx.x * 256 + threadIdx.x) * 8;
    if (i < na) {
        *(short8*)&oa[i] = f8_to_bf8(a + i);
    } else if (i < na + nb) {
        int j = i - na;
        *(short8*)&ob[j] = f8_to_bf8(b + j);
    } else {
        int j = i - na - nb;
        if (j < nc) *(short8*)&oc[j] = f8_to_bf8(c + j);
    }
}

// ---- gemm_qkv: dilution-aware QKV projection, 128x64 tiles ----------------
// Covered cells only. 1344 blocks: g0 = 768 (64 my x 12 nx, rows stride 1,
// heads 0-3), g1 = 384 (32 x 12, rows 1+2i), g2 = 192 (16 x 12, rows 2+4i).
// gcol = (nx>>2)*768 + g*256 + (nx&3)*64.
__global__ __launch_bounds__(256) void gemm_qkv(
    const short* __restrict__ A,     // xb [8192,768]
    const short* __restrict__ B,     // wqkvb [2304,768]
    const float* __restrict__ bias,  // b_qkv [2304]
    short* __restrict__ C)           // qkv [8192,2304]
{
    __shared__ short As[128 * 64];   // chunk-swizzled: slot(r,c)=G(r, c^(r&7))
    __shared__ short Bs[64 * 64];

    const int bx = blockIdx.x;
    const int L  = (bx & 7) * 168 + (bx >> 3);   // 1344 = 8 XCDs * 168
    int g, t, rate, off0;
    if (L < 768)       { g = 0; t = L;        rate = 1; off0 = 0; }
    else if (L < 1152) { g = 1; t = L - 768;  rate = 2; off0 = 1; }
    else               { g = 2; t = L - 1152; rate = 4; off0 = 2; }
    const int nx = t % 12, my = t / 12;         // nx fastest: A-panel shared
    const int ncol0 = (nx >> 2) * 768 + g * 256 + (nx & 3) * 64;
    const int m0 = my * 128;                    // local (gathered) row base

    const int tid  = threadIdx.x;
    const int wave = tid >> 6, lane = tid & 63;
    const int quad = lane >> 4, l16 = lane & 15;
    const int lrow   = lane >> 3;
    const int lchunk = (lane & 7) ^ lrow;

    const short* Abase = A + (size_t)(off0 + (m0 + wave * 32 + lrow) * rate) * 768
                           + lchunk * 8;
    const short* Bbase = B + (size_t)(ncol0 + wave * 16 + lrow) * 768 + lchunk * 8;
    short* AsW = &As[(wave * 32) * 64];
    short* BsW = &Bs[(wave * 16) * 64];
    const size_t arowstep = (size_t)8 * rate * 768;

    float4_ acc[2][4] = {};

    for (int k0 = 0; k0 < 768; k0 += 64) {
        __syncthreads();
        #pragma unroll
        for (int i = 0; i < 4; i++)
            gll16(Abase + (size_t)i * arowstep + k0, AsW + (i * 8) * 64);
        #pragma unroll
        for (int i = 0; i < 2; i++)
            gll16(Bbase + (size_t)(i * 8) * 768 + k0, BsW + (i * 8) * 64);
        __syncthreads();
        #pragma unroll
        for (int ks = 0; ks < 2; ks++) {
            const int ca = ((ks * 4 + quad) ^ (l16 & 7)) * 8;
            short8 af[2], bf[4];
            #pragma unroll
            for (int mt = 0; mt < 2; mt++)
                af[mt] = *(const short8*)&As[(wave * 32 + mt * 16 + l16) * 64 + ca];
            #pragma unroll
            for (int nt = 0; nt < 4; nt++)
                bf[nt] = *(const short8*)&Bs[(nt * 16 + l16) * 64 + ca];
            #pragma unroll
            for (int mt = 0; mt < 2; mt++)
                #pragma unroll
                for (int nt = 0; nt < 4; nt++)
                    acc[mt][nt] = __builtin_amdgcn_mfma_f32_16x16x32_bf16(
                        af[mt], bf[nt], acc[mt][nt], 0, 0, 0);
        }
    }

    #pragma unroll
    for (int nt = 0; nt < 4; nt++) {
        const int gcol = ncol0 + nt * 16 + l16;
        const float bv = bias[gcol];
        #pragma unroll
        for (int mt = 0; mt < 2; mt++) {
            #pragma unroll
            for (int r = 0; r < 4; r++) {
                const int rl = m0 + wave * 32 + mt * 16 + quad * 4 + r;
                const size_t grow = (size_t)off0 + (size_t)rl * rate;
                C[grow * 2304 + gcol] = f2bf(acc[mt][nt][r] + bv);
            }
        }
    }
}

// ---- gemm_out: out-projection, 128x64 tiles, fp32 store -------------------
// out[row, col] = LN(o)[row,:768] @ w_out[col,:]^T + b_out[col].
// 768 blocks = 12 nx x 64 my, XCD swizzle 8x96.
__global__ __launch_bounds__(256) void gemm_out(
    const short* __restrict__ A,     // qkv [8192,2304], q section = LN(o)
    const short* __restrict__ B,     // woutb [768,768]
    const float* __restrict__ bias,  // b_out [768]
    float* __restrict__ C)           // out [8192,768] fp32
{
    __shared__ short As[128 * 64];
    __shared__ short Bs[64 * 64];

    const int bx = blockIdx.x;
    const int L  = (bx & 7) * 96 + (bx >> 3);   // 768 = 8 XCDs * 96
    const int nx = L % 12, my = L / 12;
    const int n0 = nx * 64, m0 = my * 128;

    const int tid  = threadIdx.x;
    const int wave = tid >> 6, lane = tid & 63;
    const int quad = lane >> 4, l16 = lane & 15;
    const int lrow   = lane >> 3;
    const int lchunk = (lane & 7) ^ lrow;

    const short* Abase = A + (size_t)(m0 + wave * 32 + lrow) * 2304 + lchunk * 8;
    const short* Bbase = B + (size_t)(n0 + wave * 16 + lrow) * 768 + lchunk * 8;
    short* AsW = &As[(wave * 32) * 64];
    short* BsW = &Bs[(wave * 16) * 64];

    float4_ acc[2][4] = {};

    for (int k0 = 0; k0 < 768; k0 += 64) {
        __syncthreads();
        #pragma unroll
        for (int i = 0; i < 4; i++)
            gll16(Abase + (size_t)(i * 8) * 2304 + k0, AsW + (i * 8) * 64);
        #pragma unroll
        for (int i = 0; i < 2; i++)
            gll16(Bbase + (size_t)(i * 8) * 768 + k0, BsW + (i * 8) * 64);
        __syncthreads();
        #pragma unroll
        for (int ks = 0; ks < 2; ks++) {
            const int ca = ((ks * 4 + quad) ^ (l16 & 7)) * 8;
            short8 af[2], bf[4];
            #pragma unroll
            for (int mt = 0; mt < 2; mt++)
                af[mt] = *(const short8*)&As[(wave * 32 + mt * 16 + l16) * 64 + ca];
            #pragma unroll
            for (int nt = 0; nt < 4; nt++)
                bf[nt] = *(const short8*)&Bs[(nt * 16 + l16) * 64 + ca];
            #pragma unroll
            for (int mt = 0; mt < 2; mt++)
                #pragma unroll
                for (int nt = 0; nt < 4; nt++)
                    acc[mt][nt] = __builtin_amdgcn_mfma_f32_16x16x32_bf16(
                        af[mt], bf[nt], acc[mt][nt], 0, 0, 0);
        }
    }

    #pragma unroll
    for (int nt = 0; nt < 4; nt++) {
        const int col = n0 + nt * 16 + l16;
        const float bv = bias[col];
        #pragma unroll
        for (int mt = 0; mt < 2; mt++) {
            #pragma unroll
            for (int r = 0; r < 4; r++) {
                const int row = m0 + wave * 32 + mt * 16 + quad * 4 + r;
                C[(size_t)row * 768 + col] = acc[mt][nt][r] + bv;
            }
        }
    }
}

// ---- Split-K in-register-P dilated attention, counted-vmcnt pipeline ------
// Grid: 896 = 28 sh * 2 half * 16 qt (XCD-chunk swizzled, qt fastest).
// Block 256 = 4 waves; wave w owns q-rows [w*32, w*32+32). 16 K/V tiles of
// 64 keys, double-buffered. Raw s_barrier + counted vmcnt: K-DMA and V
// register-prefetch span phases (never drained to 0 mid-loop).
__global__ __launch_bounds__(256, 4) void dilated_attn(
    const short* __restrict__ qkv, short* __restrict__ obuf1,
    short* __restrict__ obuf2, float* __restrict__ lbuf)
{
    __shared__ short Ks[2 * 64 * 64];   // K[key][d], chunk-XOR swizzled (DMA)
    __shared__ short Vt[2 * 64 * LDT];  // Vt[d][key], key cols XOR-swizzled

    const int bx = blockIdx.x;
    const int L  = (bx & 7) * 112 + (bx >> 3);   // 896 = 8 XCDs * 112
    const int qt   = L & 15;
    const int half = (L >> 4) & 1;
    const int sh   = L >> 5;   // 0..27

    int g, seg, s, rate, off0;
    if (sh < 16)      { g = 0; seg = sh >> 2;        s = 2048; rate = 1; off0 = 0; }
    else if (sh < 24) { g = 1; seg = (sh - 16) >> 2; s = 4096; rate = 2; off0 = 1; }
    else              { g = 2; seg = 0;              s = 8192; rate = 4; off0 = 2; }
    const int head = g * 4 + (sh & 3);

    const int tid  = threadIdx.x;
    const int wave = tid >> 6, lane = tid & 63;
    const int h = lane >> 5, l32 = lane & 31;
    const int srow = tid >> 2, scol = (tid & 3) * 16;   // V-staging map

    // ---- Q frags (B-operand of swapped QK): lane (h,l32) holds
    // Q[q = qt*128+wave*32+l32][kt*16 + h*8 + e], pre-scaled 0.125*log2(e).
    const size_t bpos = (size_t)seg * s + off0
                      + (size_t)(qt * 128 + wave * 32) * rate;
    short8 aq[4];
    {
        const short* qsrc = qkv + (bpos + (size_t)l32 * rate) * 2304
                                + head * 64 + h * 8;
        #pragma unroll
        for (int kt = 0; kt < 4; kt++) {
            short8 q = *(const short8*)(qsrc + kt * 16);
            #pragma unroll
            for (int e = 0; e < 8; e++) q[e] = f2bf(bf2f(q[e]) * 0.1803368801111244f);
            aq[kt] = q;
        }
    }

    // staging maps (key index offset by half*1024 dilated positions)
    const int krow0  = wave * 8 + (lane >> 3);
    const int kchunk = (lane & 7) ^ (lane >> 3);
    const size_t kstep = (size_t)64 * rate * 2304;
    const size_t kq0 = (size_t)seg * s + off0 + (size_t)(half * 1024) * rate;
    const short* kg0 = qkv + (kq0 + (size_t)krow0 * rate) * 2304
                           + 768 + head * 64 + kchunk * 8;
    const short* kg1 = kg0 + (size_t)32 * rate * 2304;
    const short* vgp = qkv + (kq0 + (size_t)srow * rate) * 2304
                           + 1536 + head * 64 + scol;
    const int kofsA = (wave * 8) * 64;
    const int kofsB = kofsA + 32 * 64;
    const int vswz  = scol;

    // ---- prologue: K0 DMA into buf0; V0 regs -> buf0; va := V1 ------------
    gll16(kg0, &Ks[kofsA]);
    gll16(kg1, &Ks[kofsB]);
    kg0 += kstep; kg1 += kstep;
    short8 va0 = *(const short8*)(vgp);
    short8 va1 = *(const short8*)(vgp + 8);
    vgp += kstep;
    // compiler inserts counted vmcnt before consuming va0/va1 (drains K0 too)
    #pragma unroll
    for (int e = 0; e < 8; e++) Vt[(scol + e) * LDT + (srow ^ vswz)] = va0[e];
    #pragma unroll
    for (int e = 0; e < 8; e++) Vt[(scol + 8 + e) * LDT + (srow ^ vswz)] = va1[e];
    va0 = *(const short8*)(vgp);      // V tile 1
    va1 = *(const short8*)(vgp + 8);
    vgp += kstep;
    // outstanding entering loop: va_V1(2)

    float lsum = 0.f;
    floatx16 oacc[2] = {};

    auto compute = [&](const short* kb, const short* vb) {
        // S'^T = K (Q*c)^T : sacc[t] covers keys [t*32,t*32+32) x 32 q-rows
        floatx16 sacc[2] = {};
        __builtin_amdgcn_s_setprio(1);
        #pragma unroll
        for (int kt = 0; kt < 4; kt++) {
            #pragma unroll
            for (int t = 0; t < 2; t++) {
                short8 ak = *(const short8*)&kb[(t * 32 + l32) * 64
                                                + (((kt * 2 + h) ^ (l32 & 7)) * 8)];
                sacc[t] = __builtin_amdgcn_mfma_f32_32x32x16_bf16(
                    ak, aq[kt], sacc[t], 0, 0, 0);
            }
        }
        __builtin_amdgcn_s_setprio(0);

        // P = exp2(S'), lane-local partial row sum
        #pragma unroll
        for (int e = 0; e < 16; e++) {
            float pa_ = EXP2(sacc[0][e]);
            float pb_ = EXP2(sacc[1][e]);
            sacc[0][e] = pa_; sacc[1][e] = pb_;
            lsum += pa_ + pb_;
        }

        // PV A-frags in-register: pa[kt] = P[q=l32][kt*16 + h*8 + e]
        short8 pa[4];
        #pragma unroll
        for (int kt = 0; kt < 4; kt++) {
            const int t = kt >> 1, b = (kt & 1) * 8;
            int A1 = cvtpk(sacc[t][b + 0], sacc[t][b + 1]);
            int A2 = cvtpk(sacc[t][b + 2], sacc[t][b + 3]);
            int B1 = cvtpk(sacc[t][b + 4], sacc[t][b + 5]);
            int B2 = cvtpk(sacc[t][b + 6], sacc[t][b + 7]);
            asm volatile("v_permlane32_swap_b32 %0, %1" : "+v"(A1), "+v"(B1));
            asm volatile("v_permlane32_swap_b32 %0, %1" : "+v"(A2), "+v"(B2));
            int4_ w; w[0] = A1; w[1] = A2; w[2] = B1; w[3] = B2;
            __builtin_memcpy(&pa[kt], &w, 16);
        }

        // O += P @ V  (B-frag: V[kt*16 + h*8 + e][d = dt*32 + l32])
        __builtin_amdgcn_s_setprio(1);
        #pragma unroll
        for (int kt = 0; kt < 4; kt++) {
            #pragma unroll
            for (int dt = 0; dt < 2; dt++) {
                const int d = dt * 32 + l32;
                short8 bv = *(const short8*)&vb[d * LDT
                                                + ((kt ^ ((d >> 4) & 3)) * 16 + h * 8)];
                oacc[dt] = __builtin_amdgcn_mfma_f32_32x32x16_bf16(
                    pa[kt], bv, oacc[dt], 0, 0, 0);
            }
        }
        __builtin_amdgcn_s_setprio(0);
    };

    for (int j = 0; j < 15; j++) {
        // K_j DMA landed (2 newest — va_{j+1} — may fly); own ds ops retired
        asm volatile("s_waitcnt vmcnt(2)" ::: "memory");
        asm volatile("s_waitcnt lgkmcnt(0)" ::: "memory");
        __builtin_amdgcn_s_barrier();   // buf[j&1] fully valid for all waves

        const int nb = (j + 1) & 1;
        gll16(kg0, &Ks[nb * 4096 + kofsA]);   // K_{j+1}: flies across phases
        gll16(kg1, &Ks[nb * 4096 + kofsB]);
        kg0 += kstep; kg1 += kstep;
        // wait va_{j+1} only (K_{j+1} stays outstanding)
        asm volatile("s_waitcnt vmcnt(2)" ::: "memory");
        short* vt = &Vt[nb * 64 * LDT];
        #pragma unroll
        for (int e = 0; e < 8; e++) vt[(scol + e) * LDT + (srow ^ vswz)] = va0[e];
        #pragma unroll
        for (int e = 0; e < 8; e++) vt[(scol + 8 + e) * LDT + (srow ^ vswz)] = va1[e];
        if (j < 14) {
            va0 = *(const short8*)(vgp);      // va_{j+2}: flies across phases
            va1 = *(const short8*)(vgp + 8);
            vgp += kstep;
        }
        compute(&Ks[(j & 1) * 4096], &Vt[(j & 1) * 64 * LDT]);
    }
    // last iter (j=15): only K_15(2) outstanding
    asm volatile("s_waitcnt vmcnt(0)" ::: "memory");
    asm volatile("s_waitcnt lgkmcnt(0)" ::: "memory");
    __builtin_amdgcn_s_barrier();
    compute(&Ks[4096], &Vt[64 * LDT]);

    // epilogue: partial O (unnormalized) -> obuf[half], raw l -> lbuf[half].
    // oacc[dt][reg] = O[q_local = 4h + (reg&3) + 8*(reg>>2)][d = dt*32+l32]
    {
        short* obase = half ? obuf2 : obuf1;
        float* lb = lbuf + (size_t)half * 8192 * 12;
        float lt = lsum + __shfl_xor(lsum, 32, 64);
        #pragma unroll
        for (int m = 0; m < 4; m++) {
            #pragma unroll
            for (int r = 0; r < 4; r++) {
                const int ql = 4 * h + r + 8 * m;
                short* od = obase + (bpos + (size_t)ql * rate) * 768 + head * 64;
                od[l32]      = f2bf(oacc[0][m * 4 + r]);
                od[32 + l32] = f2bf(oacc[1][m * 4 + r]);
            }
        }
        if (lane < 32)
            lb[(bpos + (size_t)l32 * rate) * 12 + head] = lt;
    }
}

// ---- Fused LayerNorm + split-K combine: obuf1+obuf2 -> q section ----------
__global__ __launch_bounds__(256) void ln_inplace(
    short* __restrict__ qkv, const short* __restrict__ obuf1,
    const short* __restrict__ obuf2, const float* __restrict__ lbuf,
    const float* __restrict__ gamma, const float* __restrict__ beta)
{
    const int row  = blockIdx.x * 4 + (threadIdx.x >> 6);
    const int lane = threadIdx.x & 63;
    const short* s1 = obuf1 + (size_t)row * 768;
    const short* s2 = obuf2 + (size_t)row * 768;
    short* dst = qkv + (size_t)row * 2304;

    // heads: first 8 elems (idx lane*8..+7) in head lane>>3;
    // last 4 (idx 512+lane*4..+3) in head 8+(lane>>4)
    const int h1 = lane >> 3;          // 0..7  (groups 0,1)
    const int h2 = 8 + (lane >> 4);    // 8..11 (group 2)
    const bool cov1 = (h1 < 4) || ((row & 1) == 1);
    const bool cov2 = ((row & 3) == 2);
    const float li1 = cov1
        ? 1.0f / (lbuf[row * 12 + h1] + lbuf[8192 * 12 + row * 12 + h1]) : 0.0f;
    const float li2 = cov2
        ? 1.0f / (lbuf[row * 12 + h2] + lbuf[8192 * 12 + row * 12 + h2]) : 0.0f;

    short8  a  = *(const short8*)&s1[lane * 8];
    short4_ b  = *(const short4_*)&s1[512 + lane * 4];
    short8  a2 = *(const short8*)&s2[lane * 8];
    short4_ b2 = *(const short4_*)&s2[512 + lane * 4];
    float v[12];
    #pragma unroll
    for (int e = 0; e < 8; e++)
        v[e] = cov1 ? (bf2f(a[e]) + bf2f(a2[e])) * li1 : 0.0f;
    #pragma unroll
    for (int e = 0; e < 4; e++)
        v[8 + e] = cov2 ? (bf2f(b[e]) + bf2f(b2[e])) * li2 : 0.0f;

    float sum = 0.f, sq = 0.f;
    #pragma unroll
    for (int e = 0; e < 12; e++) { sum += v[e]; sq += v[e] * v[e]; }
    #pragma unroll
    for (int off = 1; off < 64; off <<= 1) {
        sum += __shfl_xor(sum, off, 64);
        sq  += __shfl_xor(sq,  off, 64);
    }
    float mean = sum * (1.0f / 768.0f);
    float var  = sq * (1.0f / 768.0f) - mean * mean;
    float rstd = rsqrtf(var + 1e-5f);

    short8 o8; short4_ o4;
    #pragma unroll
    for (int e = 0; e < 8; e++)
        o8[e] = f2bf((v[e] - mean) * rstd * gamma[lane * 8 + e] + beta[lane * 8 + e]);
    #pragma unroll
    for (int e = 0; e < 4; e++)
        o4[e] = f2bf((v[8 + e] - mean) * rstd * gamma[512 + lane * 4 + e] + beta[512 + lane * 4 + e]);

    *(short8*)&dst[lane * 8] = o8;
    *(short4_*)&dst[512 + lane * 4] = o4;
}

extern "C" void kernel_launch(void* const* d_in, const int* in_sizes, int n_in,
                              void* d_out, int out_size, void* d_ws, size_t ws_size,
                              hipStream_t stream) {
    const float* x     = (const float*)d_in[0];   // [8192,768]
    const float* w_qkv = (const float*)d_in[1];   // [2304,768]
    const float* b_qkv = (const float*)d_in[2];
    const float* w_out = (const float*)d_in[3];   // [768,768]
    const float* b_out = (const float*)d_in[4];
    const float* gamma = (const float*)d_in[5];
    const float* beta  = (const float*)d_in[6];
    float* out = (float*)d_out;                   // [8192,768] fp32

    const int NX = 8192 * 768, NW1 = 2304 * 768, NW2 = 768 * 768;
    char* ws = (char*)d_ws;
    short* qkv   = (short*)(ws);                          // 37.75 MB
    short* xb    = (short*)(ws + (size_t)8192 * 2304 * 2);
    short* wqkvb = xb + NX;
    short* woutb = wqkvb + NW1;
    float* lbuf  = (float*)(woutb + NW2);                 // 2*8192*12 fp32
    short* obuf2 = (short*)(lbuf + 2 * 8192 * 12);        // 12.6 MB
    short* obuf1 = xb;   // xb dead after gemm_qkv; reuse for split-0 partial O

    // 0) one-shot fp32->bf16 conversions
    cvt3<<<dim3((NX + NW1 + NW2) / (256 * 8)), 256, 0, stream>>>(
        x, NX, w_qkv, NW1, w_out, NW2, xb, wqkvb, woutb);

    // 1) qkv = x @ w_qkv^T + b_qkv, covered cells only (16.9 GFLOP)
    gemm_qkv<<<dim3(1344), 256, 0, stream>>>(xb, wqkvb, b_qkv, qkv);

    // 2) split-K in-reg-P attention: partial O -> obuf1/obuf2, l -> lbuf
    dilated_attn<<<dim3(28 * 2 * 16), 256, 0, stream>>>(qkv, obuf1, obuf2, lbuf);

    // 3) LayerNorm + combine -> q section (full 768 cols written)
    ln_inplace<<<dim3(8192 / 4), 256, 0, stream>>>(
        qkv, obuf1, obuf2, lbuf, gamma, beta);

    // 4) out = LN(o) @ w_out^T + b_out (fp32 store)
    gemm_out<<<dim3(768), 256, 0, stream>>>(qkv, woutb, b_out, out);
}

// Round 9
// 183.102 us; speedup vs baseline: 1.2255x; 1.0017x over previous
//
#include <hip/hip_runtime.h>
#include <hip/hip_bf16.h>
#include <cstdint>
#include <cstddef>

// R16: 64 q-rows per wave — halve the LDS replication traffic.
//  R15b post-mortem: GEMM retile landed (183.4us); attn back on top at a
//  steady 47.7us. R9's cost model: each wave reads the FULL K/V tile per
//  iter regardless of rows owned (LDS reads ~ waves x iters). Inverse of
//  R9's mistake: 64 q-rows/wave -> ak/bv fragments read once feed TWO
//  MFMAs (rg=0,1); grid 448 = 28sh x 2half x 8qt (256 rows/block); total
//  wave-iters 57344 -> 28672 => LDS reads, V-staging and K-DMA L2 traffic
//  all halve. Cost: VGPR ~190 (oacc 64 + sacc 64 peak) -> 2 waves/SIMD,
//  all 448 blocks co-resident. Cycle model: LDS/CU ~12us, VALU ~5us,
//  MFMA ~3us -> wall ~25-32us if 2-wave TLP + intra-iter ILP (32 MFMA,
//  2 indep rg chains) covers the chain latency. launch_bounds(256,2).
// gemm_qkv / gemm_out / ln / cvt3 unchanged from R15b.

typedef __attribute__((ext_vector_type(8))) short short8;
typedef __attribute__((ext_vector_type(4))) short short4_;
typedef __attribute__((ext_vector_type(4))) float float4_;
typedef __attribute__((ext_vector_type(16))) float floatx16;
typedef __attribute__((ext_vector_type(4))) int int4_;

#if __has_builtin(__builtin_amdgcn_exp2f)
#define EXP2(x) __builtin_amdgcn_exp2f(x)
#else
#define EXP2(x) exp2f(x)
#endif

__device__ __forceinline__ float bf2f(short s) {
    unsigned int u = ((unsigned int)(unsigned short)s) << 16;
    float f;
    __builtin_memcpy(&f, &u, 4);
    return f;
}
__device__ __forceinline__ short f2bf(float f) {
    unsigned int u;
    __builtin_memcpy(&u, &f, 4);
    u += 0x7fffu + ((u >> 16) & 1u);   // round-to-nearest-even
    return (short)(u >> 16);
}
__device__ __forceinline__ short8 f8_to_bf8(const float* __restrict__ p) {
    float4_ a = *(const float4_*)(p);
    float4_ b = *(const float4_*)(p + 4);
    short8 r;
    r[0] = f2bf(a[0]); r[1] = f2bf(a[1]); r[2] = f2bf(a[2]); r[3] = f2bf(a[3]);
    r[4] = f2bf(b[0]); r[5] = f2bf(b[1]); r[6] = f2bf(b[2]); r[7] = f2bf(b[3]);
    return r;
}
__device__ __forceinline__ void gll16(const short* g, short* l) {
    __builtin_amdgcn_global_load_lds(
        (const __attribute__((address_space(1))) unsigned int*)g,
        (__attribute__((address_space(3))) unsigned int*)l, 16, 0, 0);
}
// pack two f32 -> one u32 of 2 bf16 (lo = first arg)
__device__ __forceinline__ int cvtpk(float lo, float hi) {
    int r;
    asm("v_cvt_pk_bf16_f32 %0, %1, %2" : "=v"(r) : "v"(lo), "v"(hi));
    return r;
}

#define LDT 72

// ---- cvt3: fp32->bf16 for x / w_qkv / w_out -------------------------------
__global__ __launch_bounds__(256) void cvt3(
    const float* __restrict__ a, int na, const float* __restrict__ b, int nb,
    const float* __restrict__ c, int nc,
    short* __restrict__ oa, short* __restrict__ ob, short* __restrict__ oc)
{
    int i = (blockIdx.x * 256 + threadIdx.x) * 8;
    if (i < na) {
        *(short8*)&oa[i] = f8_to_bf8(a + i);
    } else if (i < na + nb) {
        int j = i - na;
        *(short8*)&ob[j] = f8_to_bf8(b + j);
    } else {
        int j = i - na - nb;
        if (j < nc) *(short8*)&oc[j] = f8_to_bf8(c + j);
    }
}

// ---- gemm_qkv: dilution-aware QKV projection, 128x64 tiles ----------------
// Covered cells only. 1344 blocks: g0 = 768 (64 my x 12 nx, rows stride 1,
// heads 0-3), g1 = 384 (32 x 12, rows 1+2i), g2 = 192 (16 x 12, rows 2+4i).
// gcol = (nx>>2)*768 + g*256 + (nx&3)*64.
__global__ __launch_bounds__(256) void gemm_qkv(
    const short* __restrict__ A,     // xb [8192,768]
    const short* __restrict__ B,     // wqkvb [2304,768]
    const float* __restrict__ bias,  // b_qkv [2304]
    short* __restrict__ C)           // qkv [8192,2304]
{
    __shared__ short As[128 * 64];   // chunk-swizzled: slot(r,c)=G(r, c^(r&7))
    __shared__ short Bs[64 * 64];

    const int bx = blockIdx.x;
    const int L  = (bx & 7) * 168 + (bx >> 3);   // 1344 = 8 XCDs * 168
    int g, t, rate, off0;
    if (L < 768)       { g = 0; t = L;        rate = 1; off0 = 0; }
    else if (L < 1152) { g = 1; t = L - 768;  rate = 2; off0 = 1; }
    else               { g = 2; t = L - 1152; rate = 4; off0 = 2; }
    const int nx = t % 12, my = t / 12;         // nx fastest: A-panel shared
    const int ncol0 = (nx >> 2) * 768 + g * 256 + (nx & 3) * 64;
    const int m0 = my * 128;                    // local (gathered) row base

    const int tid  = threadIdx.x;
    const int wave = tid >> 6, lane = tid & 63;
    const int quad = lane >> 4, l16 = lane & 15;
    const int lrow   = lane >> 3;
    const int lchunk = (lane & 7) ^ lrow;

    const short* Abase = A + (size_t)(off0 + (m0 + wave * 32 + lrow) * rate) * 768
                           + lchunk * 8;
    const short* Bbase = B + (size_t)(ncol0 + wave * 16 + lrow) * 768 + lchunk * 8;
    short* AsW = &As[(wave * 32) * 64];
    short* BsW = &Bs[(wave * 16) * 64];
    const size_t arowstep = (size_t)8 * rate * 768;

    float4_ acc[2][4] = {};

    for (int k0 = 0; k0 < 768; k0 += 64) {
        __syncthreads();
        #pragma unroll
        for (int i = 0; i < 4; i++)
            gll16(Abase + (size_t)i * arowstep + k0, AsW + (i * 8) * 64);
        #pragma unroll
        for (int i = 0; i < 2; i++)
            gll16(Bbase + (size_t)(i * 8) * 768 + k0, BsW + (i * 8) * 64);
        __syncthreads();
        #pragma unroll
        for (int ks = 0; ks < 2; ks++) {
            const int ca = ((ks * 4 + quad) ^ (l16 & 7)) * 8;
            short8 af[2], bf[4];
            #pragma unroll
            for (int mt = 0; mt < 2; mt++)
                af[mt] = *(const short8*)&As[(wave * 32 + mt * 16 + l16) * 64 + ca];
            #pragma unroll
            for (int nt = 0; nt < 4; nt++)
                bf[nt] = *(const short8*)&Bs[(nt * 16 + l16) * 64 + ca];
            #pragma unroll
            for (int mt = 0; mt < 2; mt++)
                #pragma unroll
                for (int nt = 0; nt < 4; nt++)
                    acc[mt][nt] = __builtin_amdgcn_mfma_f32_16x16x32_bf16(
                        af[mt], bf[nt], acc[mt][nt], 0, 0, 0);
        }
    }

    #pragma unroll
    for (int nt = 0; nt < 4; nt++) {
        const int gcol = ncol0 + nt * 16 + l16;
        const float bv = bias[gcol];
        #pragma unroll
        for (int mt = 0; mt < 2; mt++) {
            #pragma unroll
            for (int r = 0; r < 4; r++) {
                const int rl = m0 + wave * 32 + mt * 16 + quad * 4 + r;
                const size_t grow = (size_t)off0 + (size_t)rl * rate;
                C[grow * 2304 + gcol] = f2bf(acc[mt][nt][r] + bv);
            }
        }
    }
}

// ---- gemm_out: out-projection, 128x64 tiles, fp32 store -------------------
// out[row, col] = LN(o)[row,:768] @ w_out[col,:]^T + b_out[col].
// 768 blocks = 12 nx x 64 my, XCD swizzle 8x96.
__global__ __launch_bounds__(256) void gemm_out(
    const short* __restrict__ A,     // qkv [8192,2304], q section = LN(o)
    const short* __restrict__ B,     // woutb [768,768]
    const float* __restrict__ bias,  // b_out [768]
    float* __restrict__ C)           // out [8192,768] fp32
{
    __shared__ short As[128 * 64];
    __shared__ short Bs[64 * 64];

    const int bx = blockIdx.x;
    const int L  = (bx & 7) * 96 + (bx >> 3);   // 768 = 8 XCDs * 96
    const int nx = L % 12, my = L / 12;
    const int n0 = nx * 64, m0 = my * 128;

    const int tid  = threadIdx.x;
    const int wave = tid >> 6, lane = tid & 63;
    const int quad = lane >> 4, l16 = lane & 15;
    const int lrow   = lane >> 3;
    const int lchunk = (lane & 7) ^ lrow;

    const short* Abase = A + (size_t)(m0 + wave * 32 + lrow) * 2304 + lchunk * 8;
    const short* Bbase = B + (size_t)(n0 + wave * 16 + lrow) * 768 + lchunk * 8;
    short* AsW = &As[(wave * 32) * 64];
    short* BsW = &Bs[(wave * 16) * 64];

    float4_ acc[2][4] = {};

    for (int k0 = 0; k0 < 768; k0 += 64) {
        __syncthreads();
        #pragma unroll
        for (int i = 0; i < 4; i++)
            gll16(Abase + (size_t)(i * 8) * 2304 + k0, AsW + (i * 8) * 64);
        #pragma unroll
        for (int i = 0; i < 2; i++)
            gll16(Bbase + (size_t)(i * 8) * 768 + k0, BsW + (i * 8) * 64);
        __syncthreads();
        #pragma unroll
        for (int ks = 0; ks < 2; ks++) {
            const int ca = ((ks * 4 + quad) ^ (l16 & 7)) * 8;
            short8 af[2], bf[4];
            #pragma unroll
            for (int mt = 0; mt < 2; mt++)
                af[mt] = *(const short8*)&As[(wave * 32 + mt * 16 + l16) * 64 + ca];
            #pragma unroll
            for (int nt = 0; nt < 4; nt++)
                bf[nt] = *(const short8*)&Bs[(nt * 16 + l16) * 64 + ca];
            #pragma unroll
            for (int mt = 0; mt < 2; mt++)
                #pragma unroll
                for (int nt = 0; nt < 4; nt++)
                    acc[mt][nt] = __builtin_amdgcn_mfma_f32_16x16x32_bf16(
                        af[mt], bf[nt], acc[mt][nt], 0, 0, 0);
        }
    }

    #pragma unroll
    for (int nt = 0; nt < 4; nt++) {
        const int col = n0 + nt * 16 + l16;
        const float bv = bias[col];
        #pragma unroll
        for (int mt = 0; mt < 2; mt++) {
            #pragma unroll
            for (int r = 0; r < 4; r++) {
                const int row = m0 + wave * 32 + mt * 16 + quad * 4 + r;
                C[(size_t)row * 768 + col] = acc[mt][nt][r] + bv;
            }
        }
    }
}

// ---- Split-K in-register-P dilated attention, 64 q-rows/wave --------------
// Grid: 448 = 28 sh * 2 half * 8 qt (XCD-chunk swizzled, qt fastest).
// Block 256 = 4 waves; wave w owns q-rows [w*64, w*64+64) as two rg-subtiles
// of 32. 16 K/V tiles of 64 keys, double-buffered, counted-vmcnt pipeline.
// ak/bv LDS fragments are read ONCE and feed both rg MFMAs (halves the
// per-work LDS read traffic vs 32 rows/wave).
__global__ __launch_bounds__(256, 2) void dilated_attn(
    const short* __restrict__ qkv, short* __restrict__ obuf1,
    short* __restrict__ obuf2, float* __restrict__ lbuf)
{
    __shared__ short Ks[2 * 64 * 64];   // K[key][d], chunk-XOR swizzled (DMA)
    __shared__ short Vt[2 * 64 * LDT];  // Vt[d][key], key cols XOR-swizzled

    const int bx = blockIdx.x;
    const int L  = (bx & 7) * 56 + (bx >> 3);   // 448 = 8 XCDs * 56
    const int qt   = L & 7;
    const int half = (L >> 3) & 1;
    const int sh   = L >> 4;   // 0..27

    int g, seg, s, rate, off0;
    if (sh < 16)      { g = 0; seg = sh >> 2;        s = 2048; rate = 1; off0 = 0; }
    else if (sh < 24) { g = 1; seg = (sh - 16) >> 2; s = 4096; rate = 2; off0 = 1; }
    else              { g = 2; seg = 0;              s = 8192; rate = 4; off0 = 2; }
    const int head = g * 4 + (sh & 3);

    const int tid  = threadIdx.x;
    const int wave = tid >> 6, lane = tid & 63;
    const int h = lane >> 5, l32 = lane & 31;
    const int srow = tid >> 2, scol = (tid & 3) * 16;   // V-staging map

    // ---- Q frags (B-operand of swapped QK), two rg-subtiles of 32 rows ----
    // lane (h,l32) holds Q[q = base + rg*32 + l32][kt*16 + h*8 + e],
    // pre-scaled by 0.125*log2(e).
    const size_t bpos = (size_t)seg * s + off0
                      + (size_t)(qt * 256 + wave * 64) * rate;
    short8 aq[2][4];
    #pragma unroll
    for (int rg = 0; rg < 2; rg++) {
        const short* qsrc = qkv + (bpos + (size_t)(rg * 32 + l32) * rate) * 2304
                                + head * 64 + h * 8;
        #pragma unroll
        for (int kt = 0; kt < 4; kt++) {
            short8 q = *(const short8*)(qsrc + kt * 16);
            #pragma unroll
            for (int e = 0; e < 8; e++) q[e] = f2bf(bf2f(q[e]) * 0.1803368801111244f);
            aq[rg][kt] = q;
        }
    }

    // staging maps (key index offset by half*1024 dilated positions)
    const int krow0  = wave * 8 + (lane >> 3);
    const int kchunk = (lane & 7) ^ (lane >> 3);
    const size_t kstep = (size_t)64 * rate * 2304;
    const size_t kq0 = (size_t)seg * s + off0 + (size_t)(half * 1024) * rate;
    const short* kg0 = qkv + (kq0 + (size_t)krow0 * rate) * 2304
                           + 768 + head * 64 + kchunk * 8;
    const short* kg1 = kg0 + (size_t)32 * rate * 2304;
    const short* vgp = qkv + (kq0 + (size_t)srow * rate) * 2304
                           + 1536 + head * 64 + scol;
    const int kofsA = (wave * 8) * 64;
    const int kofsB = kofsA + 32 * 64;
    const int vswz  = scol;

    // ---- prologue: K0 DMA into buf0; V0 regs -> buf0; va := V1 ------------
    gll16(kg0, &Ks[kofsA]);
    gll16(kg1, &Ks[kofsB]);
    kg0 += kstep; kg1 += kstep;
    short8 va0 = *(const short8*)(vgp);
    short8 va1 = *(const short8*)(vgp + 8);
    vgp += kstep;
    // compiler inserts counted vmcnt before consuming va0/va1 (drains K0 too)
    #pragma unroll
    for (int e = 0; e < 8; e++) Vt[(scol + e) * LDT + (srow ^ vswz)] = va0[e];
    #pragma unroll
    for (int e = 0; e < 8; e++) Vt[(scol + 8 + e) * LDT + (srow ^ vswz)] = va1[e];
    va0 = *(const short8*)(vgp);      // V tile 1
    va1 = *(const short8*)(vgp + 8);
    vgp += kstep;
    // outstanding entering loop: va_V1(2)

    float lsum[2] = {};
    floatx16 oacc[2][2] = {};

    auto compute = [&](const short* kb, const short* vb) {
        // S'^T = K (Q*c)^T : sacc[rg][t] covers keys [t*32,t*32+32) x 32 q
        floatx16 sacc[2][2] = {};
        __builtin_amdgcn_s_setprio(1);
        #pragma unroll
        for (int kt = 0; kt < 4; kt++) {
            #pragma unroll
            for (int t = 0; t < 2; t++) {
                short8 ak = *(const short8*)&kb[(t * 32 + l32) * 64
                                                + (((kt * 2 + h) ^ (l32 & 7)) * 8)];
                #pragma unroll
                for (int rg = 0; rg < 2; rg++)
                    sacc[rg][t] = __builtin_amdgcn_mfma_f32_32x32x16_bf16(
                        ak, aq[rg][kt], sacc[rg][t], 0, 0, 0);
            }
        }
        __builtin_amdgcn_s_setprio(0);

        // P = exp2(S'), lane-local partial row sums; pack PV A-frags
        short8 pa[2][4];
        #pragma unroll
        for (int rg = 0; rg < 2; rg++) {
            #pragma unroll
            for (int e = 0; e < 16; e++) {
                float pa_ = EXP2(sacc[rg][0][e]);
                float pb_ = EXP2(sacc[rg][1][e]);
                sacc[rg][0][e] = pa_; sacc[rg][1][e] = pb_;
                lsum[rg] += pa_ + pb_;
            }
            #pragma unroll
            for (int kt = 0; kt < 4; kt++) {
                const int t = kt >> 1, b = (kt & 1) * 8;
                int A1 = cvtpk(sacc[rg][t][b + 0], sacc[rg][t][b + 1]);
                int A2 = cvtpk(sacc[rg][t][b + 2], sacc[rg][t][b + 3]);
                int B1 = cvtpk(sacc[rg][t][b + 4], sacc[rg][t][b + 5]);
                int B2 = cvtpk(sacc[rg][t][b + 6], sacc[rg][t][b + 7]);
                asm volatile("v_permlane32_swap_b32 %0, %1" : "+v"(A1), "+v"(B1));
                asm volatile("v_permlane32_swap_b32 %0, %1" : "+v"(A2), "+v"(B2));
                int4_ w; w[0] = A1; w[1] = A2; w[2] = B1; w[3] = B2;
                __builtin_memcpy(&pa[rg][kt], &w, 16);
            }
        }

        // O += P @ V  (B-frag: V[kt*16 + h*8 + e][d = dt*32 + l32])
        __builtin_amdgcn_s_setprio(1);
        #pragma unroll
        for (int kt = 0; kt < 4; kt++) {
            #pragma unroll
            for (int dt = 0; dt < 2; dt++) {
                const int d = dt * 32 + l32;
                short8 bv = *(const short8*)&vb[d * LDT
                                                + ((kt ^ ((d >> 4) & 3)) * 16 + h * 8)];
                #pragma unroll
                for (int rg = 0; rg < 2; rg++)
                    oacc[rg][dt] = __builtin_amdgcn_mfma_f32_32x32x16_bf16(
                        pa[rg][kt], bv, oacc[rg][dt], 0, 0, 0);
            }
        }
        __builtin_amdgcn_s_setprio(0);
    };

    for (int j = 0; j < 15; j++) {
        // K_j DMA landed (2 newest — va_{j+1} — may fly); own ds ops retired
        asm volatile("s_waitcnt vmcnt(2)" ::: "memory");
        asm volatile("s_waitcnt lgkmcnt(0)" ::: "memory");
        __builtin_amdgcn_s_barrier();   // buf[j&1] fully valid for all waves

        const int nb = (j + 1) & 1;
        gll16(kg0, &Ks[nb * 4096 + kofsA]);   // K_{j+1}: flies across phases
        gll16(kg1, &Ks[nb * 4096 + kofsB]);
        kg0 += kstep; kg1 += kstep;
        // wait va_{j+1} only (K_{j+1} stays outstanding)
        asm volatile("s_waitcnt vmcnt(2)" ::: "memory");
        short* vt = &Vt[nb * 64 * LDT];
        #pragma unroll
        for (int e = 0; e < 8; e++) vt[(scol + e) * LDT + (srow ^ vswz)] = va0[e];
        #pragma unroll
        for (int e = 0; e < 8; e++) vt[(scol + 8 + e) * LDT + (srow ^ vswz)] = va1[e];
        if (j < 14) {
            va0 = *(const short8*)(vgp);      // va_{j+2}: flies across phases
            va1 = *(const short8*)(vgp + 8);
            vgp += kstep;
        }
        compute(&Ks[(j & 1) * 4096], &Vt[(j & 1) * 64 * LDT]);
    }
    // last iter (j=15): only K_15(2) outstanding
    asm volatile("s_waitcnt vmcnt(0)" ::: "memory");
    asm volatile("s_waitcnt lgkmcnt(0)" ::: "memory");
    __builtin_amdgcn_s_barrier();
    compute(&Ks[4096], &Vt[64 * LDT]);

    // epilogue: partial O (unnormalized) -> obuf[half], raw l -> lbuf[half].
    // oacc[rg][dt][reg] = O[q = rg*32 + 4h+(reg&3)+8*(reg>>2)][d = dt*32+l32]
    {
        short* obase = half ? obuf2 : obuf1;
        float* lb = lbuf + (size_t)half * 8192 * 12;
        #pragma unroll
        for (int rg = 0; rg < 2; rg++) {
            float lt = lsum[rg] + __shfl_xor(lsum[rg], 32, 64);
            #pragma unroll
            for (int m = 0; m < 4; m++) {
                #pragma unroll
                for (int r = 0; r < 4; r++) {
                    const int ql = rg * 32 + 4 * h + r + 8 * m;
                    short* od = obase + (bpos + (size_t)ql * rate) * 768 + head * 64;
                    od[l32]      = f2bf(oacc[rg][0][m * 4 + r]);
                    od[32 + l32] = f2bf(oacc[rg][1][m * 4 + r]);
                }
            }
            if (lane < 32)
                lb[(bpos + (size_t)(rg * 32 + l32) * rate) * 12 + head] = lt;
        }
    }
}

// ---- Fused LayerNorm + split-K combine: obuf1+obuf2 -> q section ----------
__global__ __launch_bounds__(256) void ln_inplace(
    short* __restrict__ qkv, const short* __restrict__ obuf1,
    const short* __restrict__ obuf2, const float* __restrict__ lbuf,
    const float* __restrict__ gamma, const float* __restrict__ beta)
{
    const int row  = blockIdx.x * 4 + (threadIdx.x >> 6);
    const int lane = threadIdx.x & 63;
    const short* s1 = obuf1 + (size_t)row * 768;
    const short* s2 = obuf2 + (size_t)row * 768;
    short* dst = qkv + (size_t)row * 2304;

    // heads: first 8 elems (idx lane*8..+7) in head lane>>3;
    // last 4 (idx 512+lane*4..+3) in head 8+(lane>>4)
    const int h1 = lane >> 3;          // 0..7  (groups 0,1)
    const int h2 = 8 + (lane >> 4);    // 8..11 (group 2)
    const bool cov1 = (h1 < 4) || ((row & 1) == 1);
    const bool cov2 = ((row & 3) == 2);
    const float li1 = cov1
        ? 1.0f / (lbuf[row * 12 + h1] + lbuf[8192 * 12 + row * 12 + h1]) : 0.0f;
    const float li2 = cov2
        ? 1.0f / (lbuf[row * 12 + h2] + lbuf[8192 * 12 + row * 12 + h2]) : 0.0f;

    short8  a  = *(const short8*)&s1[lane * 8];
    short4_ b  = *(const short4_*)&s1[512 + lane * 4];
    short8  a2 = *(const short8*)&s2[lane * 8];
    short4_ b2 = *(const short4_*)&s2[512 + lane * 4];
    float v[12];
    #pragma unroll
    for (int e = 0; e < 8; e++)
        v[e] = cov1 ? (bf2f(a[e]) + bf2f(a2[e])) * li1 : 0.0f;
    #pragma unroll
    for (int e = 0; e < 4; e++)
        v[8 + e] = cov2 ? (bf2f(b[e]) + bf2f(b2[e])) * li2 : 0.0f;

    float sum = 0.f, sq = 0.f;
    #pragma unroll
    for (int e = 0; e < 12; e++) { sum += v[e]; sq += v[e] * v[e]; }
    #pragma unroll
    for (int off = 1; off < 64; off <<= 1) {
        sum += __shfl_xor(sum, off, 64);
        sq  += __shfl_xor(sq,  off, 64);
    }
    float mean = sum * (1.0f / 768.0f);
    float var  = sq * (1.0f / 768.0f) - mean * mean;
    float rstd = rsqrtf(var + 1e-5f);

    short8 o8; short4_ o4;
    #pragma unroll
    for (int e = 0; e < 8; e++)
        o8[e] = f2bf((v[e] - mean) * rstd * gamma[lane * 8 + e] + beta[lane * 8 + e]);
    #pragma unroll
    for (int e = 0; e < 4; e++)
        o4[e] = f2bf((v[8 + e] - mean) * rstd * gamma[512 + lane * 4 + e] + beta[512 + lane * 4 + e]);

    *(short8*)&dst[lane * 8] = o8;
    *(short4_*)&dst[512 + lane * 4] = o4;
}

extern "C" void kernel_launch(void* const* d_in, const int* in_sizes, int n_in,
                              void* d_out, int out_size, void* d_ws, size_t ws_size,
                              hipStream_t stream) {
    const float* x     = (const float*)d_in[0];   // [8192,768]
    const float* w_qkv = (const float*)d_in[1];   // [2304,768]
    const float* b_qkv = (const float*)d_in[2];
    const float* w_out = (const float*)d_in[3];   // [768,768]
    const float* b_out = (const float*)d_in[4];
    const float* gamma = (const float*)d_in[5];
    const float* beta  = (const float*)d_in[6];
    float* out = (float*)d_out;                   // [8192,768] fp32

    const int NX = 8192 * 768, NW1 = 2304 * 768, NW2 = 768 * 768;
    char* ws = (char*)d_ws;
    short* qkv   = (short*)(ws);                          // 37.75 MB
    short* xb    = (short*)(ws + (size_t)8192 * 2304 * 2);
    short* wqkvb = xb + NX;
    short* woutb = wqkvb + NW1;
    float* lbuf  = (float*)(woutb + NW2);                 // 2*8192*12 fp32
    short* obuf2 = (short*)(lbuf + 2 * 8192 * 12);        // 12.6 MB
    short* obuf1 = xb;   // xb dead after gemm_qkv; reuse for split-0 partial O

    // 0) one-shot fp32->bf16 conversions
    cvt3<<<dim3((NX + NW1 + NW2) / (256 * 8)), 256, 0, stream>>>(
        x, NX, w_qkv, NW1, w_out, NW2, xb, wqkvb, woutb);

    // 1) qkv = x @ w_qkv^T + b_qkv, covered cells only (16.9 GFLOP)
    gemm_qkv<<<dim3(1344), 256, 0, stream>>>(xb, wqkvb, b_qkv, qkv);

    // 2) split-K in-reg-P attention: partial O -> obuf1/obuf2, l -> lbuf
    dilated_attn<<<dim3(448), 256, 0, stream>>>(qkv, obuf1, obuf2, lbuf);

    // 3) LayerNorm + combine -> q section (full 768 cols written)
    ln_inplace<<<dim3(8192 / 4), 256, 0, stream>>>(
        qkv, obuf1, obuf2, lbuf, gamma, beta);

    // 4) out = LN(o) @ w_out^T + b_out (fp32 store)
    gemm_out<<<dim3(768), 256, 0, stream>>>(qkv, woutb, b_out, out);
}

// Round 10
// 182.562 us; speedup vs baseline: 1.2291x; 1.0030x over previous
//
#include <hip/hip_runtime.h>
#include <hip/hip_bf16.h>
#include <cstdint>
#include <cstddef>

// R17: revert attn to R14 structure (spill-free, proven 47.7us) + K-prescale.
//  R16 post-mortem: 64-row waves need sacc(64)+oacc(64)+aq(16)+misc ~170
//  VGPR but allocator emitted 128 -> SPILLS (WRITE_SIZE 16->21MB) AND
//  occupancy halved (7 waves/CU) -> 53.5us regression. Bank conflicts DID
//  halve (3.67M->1.84M) so the traffic model holds, but the design is
//  VGPR-walled: spill-free => <=3 waves/SIMD => occupancy loss cancels the
//  traffic win. Revert to 32-row/2-way-split/counted-vmcnt attn (VGPR 64).
//  Free win while here: fold 0.125*log2(e) into K at projection time —
//  cvt3 scales w_qkv rows 768..1535, gemm_qkv scales K-section bias; attn
//  loads Q raw (one less bf16 requant + 64 VALU off the prologue).
// gemm_qkv / gemm_out / ln / cvt3 structure unchanged from R15b.

typedef __attribute__((ext_vector_type(8))) short short8;
typedef __attribute__((ext_vector_type(4))) short short4_;
typedef __attribute__((ext_vector_type(4))) float float4_;
typedef __attribute__((ext_vector_type(16))) float floatx16;
typedef __attribute__((ext_vector_type(4))) int int4_;

#if __has_builtin(__builtin_amdgcn_exp2f)
#define EXP2(x) __builtin_amdgcn_exp2f(x)
#else
#define EXP2(x) exp2f(x)
#endif

#define QK_SCALE 0.1803368801111244f   // 0.125 * log2(e)

__device__ __forceinline__ float bf2f(short s) {
    unsigned int u = ((unsigned int)(unsigned short)s) << 16;
    float f;
    __builtin_memcpy(&f, &u, 4);
    return f;
}
__device__ __forceinline__ short f2bf(float f) {
    unsigned int u;
    __builtin_memcpy(&u, &f, 4);
    u += 0x7fffu + ((u >> 16) & 1u);   // round-to-nearest-even
    return (short)(u >> 16);
}
__device__ __forceinline__ short8 f8_to_bf8_s(const float* __restrict__ p, float s) {
    float4_ a = *(const float4_*)(p);
    float4_ b = *(const float4_*)(p + 4);
    short8 r;
    r[0] = f2bf(a[0] * s); r[1] = f2bf(a[1] * s);
    r[2] = f2bf(a[2] * s); r[3] = f2bf(a[3] * s);
    r[4] = f2bf(b[0] * s); r[5] = f2bf(b[1] * s);
    r[6] = f2bf(b[2] * s); r[7] = f2bf(b[3] * s);
    return r;
}
__device__ __forceinline__ void gll16(const short* g, short* l) {
    __builtin_amdgcn_global_load_lds(
        (const __attribute__((address_space(1))) unsigned int*)g,
        (__attribute__((address_space(3))) unsigned int*)l, 16, 0, 0);
}
// pack two f32 -> one u32 of 2 bf16 (lo = first arg)
__device__ __forceinline__ int cvtpk(float lo, float hi) {
    int r;
    asm("v_cvt_pk_bf16_f32 %0, %1, %2" : "=v"(r) : "v"(lo), "v"(hi));
    return r;
}

#define LDT 72

// ---- cvt3: fp32->bf16 for x / w_qkv / w_out; scales K-rows of w_qkv ------
__global__ __launch_bounds__(256) void cvt3(
    const float* __restrict__ a, int na, const float* __restrict__ b, int nb,
    const float* __restrict__ c, int nc,
    short* __restrict__ oa, short* __restrict__ ob, short* __restrict__ oc)
{
    int i = (blockIdx.x * 256 + threadIdx.x) * 8;
    if (i < na) {
        *(short8*)&oa[i] = f8_to_bf8_s(a + i, 1.0f);
    } else if (i < na + nb) {
        int j = i - na;
        // w_qkv rows [768,1536) = K section: fold in the softmax scale
        float s = (j >= 768 * 768 && j < 1536 * 768) ? QK_SCALE : 1.0f;
        *(short8*)&ob[j] = f8_to_bf8_s(b + j, s);
    } else {
        int j = i - na - nb;
        if (j < nc) *(short8*)&oc[j] = f8_to_bf8_s(c + j, 1.0f);
    }
}

// ---- gemm_qkv: dilution-aware QKV projection, 128x64 tiles ----------------
// Covered cells only. 1344 blocks: g0 = 768 (64 my x 12 nx, rows stride 1,
// heads 0-3), g1 = 384 (32 x 12, rows 1+2i), g2 = 192 (16 x 12, rows 2+4i).
// gcol = (nx>>2)*768 + g*256 + (nx&3)*64. K-section bias scaled by QK_SCALE
// (W K-rows already scaled in cvt3).
__global__ __launch_bounds__(256) void gemm_qkv(
    const short* __restrict__ A,     // xb [8192,768]
    const short* __restrict__ B,     // wqkvb [2304,768]
    const float* __restrict__ bias,  // b_qkv [2304]
    short* __restrict__ C)           // qkv [8192,2304]
{
    __shared__ short As[128 * 64];   // chunk-swizzled: slot(r,c)=G(r, c^(r&7))
    __shared__ short Bs[64 * 64];

    const int bx = blockIdx.x;
    const int L  = (bx & 7) * 168 + (bx >> 3);   // 1344 = 8 XCDs * 168
    int g, t, rate, off0;
    if (L < 768)       { g = 0; t = L;        rate = 1; off0 = 0; }
    else if (L < 1152) { g = 1; t = L - 768;  rate = 2; off0 = 1; }
    else               { g = 2; t = L - 1152; rate = 4; off0 = 2; }
    const int nx = t % 12, my = t / 12;         // nx fastest: A-panel shared
    const int ncol0 = (nx >> 2) * 768 + g * 256 + (nx & 3) * 64;
    const int m0 = my * 128;                    // local (gathered) row base
    const float bscale = ((nx >> 2) == 1) ? QK_SCALE : 1.0f;

    const int tid  = threadIdx.x;
    const int wave = tid >> 6, lane = tid & 63;
    const int quad = lane >> 4, l16 = lane & 15;
    const int lrow   = lane >> 3;
    const int lchunk = (lane & 7) ^ lrow;

    const short* Abase = A + (size_t)(off0 + (m0 + wave * 32 + lrow) * rate) * 768
                           + lchunk * 8;
    const short* Bbase = B + (size_t)(ncol0 + wave * 16 + lrow) * 768 + lchunk * 8;
    short* AsW = &As[(wave * 32) * 64];
    short* BsW = &Bs[(wave * 16) * 64];
    const size_t arowstep = (size_t)8 * rate * 768;

    float4_ acc[2][4] = {};

    for (int k0 = 0; k0 < 768; k0 += 64) {
        __syncthreads();
        #pragma unroll
        for (int i = 0; i < 4; i++)
            gll16(Abase + (size_t)i * arowstep + k0, AsW + (i * 8) * 64);
        #pragma unroll
        for (int i = 0; i < 2; i++)
            gll16(Bbase + (size_t)(i * 8) * 768 + k0, BsW + (i * 8) * 64);
        __syncthreads();
        #pragma unroll
        for (int ks = 0; ks < 2; ks++) {
            const int ca = ((ks * 4 + quad) ^ (l16 & 7)) * 8;
            short8 af[2], bf[4];
            #pragma unroll
            for (int mt = 0; mt < 2; mt++)
                af[mt] = *(const short8*)&As[(wave * 32 + mt * 16 + l16) * 64 + ca];
            #pragma unroll
            for (int nt = 0; nt < 4; nt++)
                bf[nt] = *(const short8*)&Bs[(nt * 16 + l16) * 64 + ca];
            #pragma unroll
            for (int mt = 0; mt < 2; mt++)
                #pragma unroll
                for (int nt = 0; nt < 4; nt++)
                    acc[mt][nt] = __builtin_amdgcn_mfma_f32_16x16x32_bf16(
                        af[mt], bf[nt], acc[mt][nt], 0, 0, 0);
        }
    }

    #pragma unroll
    for (int nt = 0; nt < 4; nt++) {
        const int gcol = ncol0 + nt * 16 + l16;
        const float bv = bias[gcol] * bscale;
        #pragma unroll
        for (int mt = 0; mt < 2; mt++) {
            #pragma unroll
            for (int r = 0; r < 4; r++) {
                const int rl = m0 + wave * 32 + mt * 16 + quad * 4 + r;
                const size_t grow = (size_t)off0 + (size_t)rl * rate;
                C[grow * 2304 + gcol] = f2bf(acc[mt][nt][r] + bv);
            }
        }
    }
}

// ---- gemm_out: out-projection, 128x64 tiles, fp32 store -------------------
// out[row, col] = LN(o)[row,:768] @ w_out[col,:]^T + b_out[col].
// 768 blocks = 12 nx x 64 my, XCD swizzle 8x96.
__global__ __launch_bounds__(256) void gemm_out(
    const short* __restrict__ A,     // qkv [8192,2304], q section = LN(o)
    const short* __restrict__ B,     // woutb [768,768]
    const float* __restrict__ bias,  // b_out [768]
    float* __restrict__ C)           // out [8192,768] fp32
{
    __shared__ short As[128 * 64];
    __shared__ short Bs[64 * 64];

    const int bx = blockIdx.x;
    const int L  = (bx & 7) * 96 + (bx >> 3);   // 768 = 8 XCDs * 96
    const int nx = L % 12, my = L / 12;
    const int n0 = nx * 64, m0 = my * 128;

    const int tid  = threadIdx.x;
    const int wave = tid >> 6, lane = tid & 63;
    const int quad = lane >> 4, l16 = lane & 15;
    const int lrow   = lane >> 3;
    const int lchunk = (lane & 7) ^ lrow;

    const short* Abase = A + (size_t)(m0 + wave * 32 + lrow) * 2304 + lchunk * 8;
    const short* Bbase = B + (size_t)(n0 + wave * 16 + lrow) * 768 + lchunk * 8;
    short* AsW = &As[(wave * 32) * 64];
    short* BsW = &Bs[(wave * 16) * 64];

    float4_ acc[2][4] = {};

    for (int k0 = 0; k0 < 768; k0 += 64) {
        __syncthreads();
        #pragma unroll
        for (int i = 0; i < 4; i++)
            gll16(Abase + (size_t)(i * 8) * 2304 + k0, AsW + (i * 8) * 64);
        #pragma unroll
        for (int i = 0; i < 2; i++)
            gll16(Bbase + (size_t)(i * 8) * 768 + k0, BsW + (i * 8) * 64);
        __syncthreads();
        #pragma unroll
        for (int ks = 0; ks < 2; ks++) {
            const int ca = ((ks * 4 + quad) ^ (l16 & 7)) * 8;
            short8 af[2], bf[4];
            #pragma unroll
            for (int mt = 0; mt < 2; mt++)
                af[mt] = *(const short8*)&As[(wave * 32 + mt * 16 + l16) * 64 + ca];
            #pragma unroll
            for (int nt = 0; nt < 4; nt++)
                bf[nt] = *(const short8*)&Bs[(nt * 16 + l16) * 64 + ca];
            #pragma unroll
            for (int mt = 0; mt < 2; mt++)
                #pragma unroll
                for (int nt = 0; nt < 4; nt++)
                    acc[mt][nt] = __builtin_amdgcn_mfma_f32_16x16x32_bf16(
                        af[mt], bf[nt], acc[mt][nt], 0, 0, 0);
        }
    }

    #pragma unroll
    for (int nt = 0; nt < 4; nt++) {
        const int col = n0 + nt * 16 + l16;
        const float bv = bias[col];
        #pragma unroll
        for (int mt = 0; mt < 2; mt++) {
            #pragma unroll
            for (int r = 0; r < 4; r++) {
                const int row = m0 + wave * 32 + mt * 16 + quad * 4 + r;
                C[(size_t)row * 768 + col] = acc[mt][nt][r] + bv;
            }
        }
    }
}

// ---- Split-K in-register-P dilated attention, counted-vmcnt pipeline ------
// Grid: 896 = 28 sh * 2 half * 16 qt (XCD-chunk swizzled, qt fastest).
// Block 256 = 4 waves; wave w owns q-rows [w*32, w*32+32). 16 K/V tiles of
// 64 keys, double-buffered. Raw s_barrier + counted vmcnt: K-DMA and V
// register-prefetch span phases (never drained to 0 mid-loop).
// K is pre-scaled by QK_SCALE at projection; Q loaded raw.
__global__ __launch_bounds__(256, 4) void dilated_attn(
    const short* __restrict__ qkv, short* __restrict__ obuf1,
    short* __restrict__ obuf2, float* __restrict__ lbuf)
{
    __shared__ short Ks[2 * 64 * 64];   // K[key][d], chunk-XOR swizzled (DMA)
    __shared__ short Vt[2 * 64 * LDT];  // Vt[d][key], key cols XOR-swizzled

    const int bx = blockIdx.x;
    const int L  = (bx & 7) * 112 + (bx >> 3);   // 896 = 8 XCDs * 112
    const int qt   = L & 15;
    const int half = (L >> 4) & 1;
    const int sh   = L >> 5;   // 0..27

    int g, seg, s, rate, off0;
    if (sh < 16)      { g = 0; seg = sh >> 2;        s = 2048; rate = 1; off0 = 0; }
    else if (sh < 24) { g = 1; seg = (sh - 16) >> 2; s = 4096; rate = 2; off0 = 1; }
    else              { g = 2; seg = 0;              s = 8192; rate = 4; off0 = 2; }
    const int head = g * 4 + (sh & 3);

    const int tid  = threadIdx.x;
    const int wave = tid >> 6, lane = tid & 63;
    const int h = lane >> 5, l32 = lane & 31;
    const int srow = tid >> 2, scol = (tid & 3) * 16;   // V-staging map

    // ---- Q frags (B-operand of swapped QK): lane (h,l32) holds
    // Q[q = qt*128+wave*32+l32][kt*16 + h*8 + e], raw (K carries the scale).
    const size_t bpos = (size_t)seg * s + off0
                      + (size_t)(qt * 128 + wave * 32) * rate;
    short8 aq[4];
    {
        const short* qsrc = qkv + (bpos + (size_t)l32 * rate) * 2304
                                + head * 64 + h * 8;
        #pragma unroll
        for (int kt = 0; kt < 4; kt++)
            aq[kt] = *(const short8*)(qsrc + kt * 16);
    }

    // staging maps (key index offset by half*1024 dilated positions)
    const int krow0  = wave * 8 + (lane >> 3);
    const int kchunk = (lane & 7) ^ (lane >> 3);
    const size_t kstep = (size_t)64 * rate * 2304;
    const size_t kq0 = (size_t)seg * s + off0 + (size_t)(half * 1024) * rate;
    const short* kg0 = qkv + (kq0 + (size_t)krow0 * rate) * 2304
                           + 768 + head * 64 + kchunk * 8;
    const short* kg1 = kg0 + (size_t)32 * rate * 2304;
    const short* vgp = qkv + (kq0 + (size_t)srow * rate) * 2304
                           + 1536 + head * 64 + scol;
    const int kofsA = (wave * 8) * 64;
    const int kofsB = kofsA + 32 * 64;
    const int vswz  = scol;

    // ---- prologue: K0 DMA into buf0; V0 regs -> buf0; va := V1 ------------
    gll16(kg0, &Ks[kofsA]);
    gll16(kg1, &Ks[kofsB]);
    kg0 += kstep; kg1 += kstep;
    short8 va0 = *(const short8*)(vgp);
    short8 va1 = *(const short8*)(vgp + 8);
    vgp += kstep;
    // compiler inserts counted vmcnt before consuming va0/va1 (drains K0 too)
    #pragma unroll
    for (int e = 0; e < 8; e++) Vt[(scol + e) * LDT + (srow ^ vswz)] = va0[e];
    #pragma unroll
    for (int e = 0; e < 8; e++) Vt[(scol + 8 + e) * LDT + (srow ^ vswz)] = va1[e];
    va0 = *(const short8*)(vgp);      // V tile 1
    va1 = *(const short8*)(vgp + 8);
    vgp += kstep;
    // outstanding entering loop: va_V1(2)

    float lsum = 0.f;
    floatx16 oacc[2] = {};

    auto compute = [&](const short* kb, const short* vb) {
        // S'^T = K' Q^T : sacc[t] covers keys [t*32,t*32+32) x 32 q-rows
        floatx16 sacc[2] = {};
        __builtin_amdgcn_s_setprio(1);
        #pragma unroll
        for (int kt = 0; kt < 4; kt++) {
            #pragma unroll
            for (int t = 0; t < 2; t++) {
                short8 ak = *(const short8*)&kb[(t * 32 + l32) * 64
                                                + (((kt * 2 + h) ^ (l32 & 7)) * 8)];
                sacc[t] = __builtin_amdgcn_mfma_f32_32x32x16_bf16(
                    ak, aq[kt], sacc[t], 0, 0, 0);
            }
        }
        __builtin_amdgcn_s_setprio(0);

        // P = exp2(S'), lane-local partial row sum
        #pragma unroll
        for (int e = 0; e < 16; e++) {
            float pa_ = EXP2(sacc[0][e]);
            float pb_ = EXP2(sacc[1][e]);
            sacc[0][e] = pa_; sacc[1][e] = pb_;
            lsum += pa_ + pb_;
        }

        // PV A-frags in-register: pa[kt] = P[q=l32][kt*16 + h*8 + e]
        short8 pa[4];
        #pragma unroll
        for (int kt = 0; kt < 4; kt++) {
            const int t = kt >> 1, b = (kt & 1) * 8;
            int A1 = cvtpk(sacc[t][b + 0], sacc[t][b + 1]);
            int A2 = cvtpk(sacc[t][b + 2], sacc[t][b + 3]);
            int B1 = cvtpk(sacc[t][b + 4], sacc[t][b + 5]);
            int B2 = cvtpk(sacc[t][b + 6], sacc[t][b + 7]);
            asm volatile("v_permlane32_swap_b32 %0, %1" : "+v"(A1), "+v"(B1));
            asm volatile("v_permlane32_swap_b32 %0, %1" : "+v"(A2), "+v"(B2));
            int4_ w; w[0] = A1; w[1] = A2; w[2] = B1; w[3] = B2;
            __builtin_memcpy(&pa[kt], &w, 16);
        }

        // O += P @ V  (B-frag: V[kt*16 + h*8 + e][d = dt*32 + l32])
        __builtin_amdgcn_s_setprio(1);
        #pragma unroll
        for (int kt = 0; kt < 4; kt++) {
            #pragma unroll
            for (int dt = 0; dt < 2; dt++) {
                const int d = dt * 32 + l32;
                short8 bv = *(const short8*)&vb[d * LDT
                                                + ((kt ^ ((d >> 4) & 3)) * 16 + h * 8)];
                oacc[dt] = __builtin_amdgcn_mfma_f32_32x32x16_bf16(
                    pa[kt], bv, oacc[dt], 0, 0, 0);
            }
        }
        __builtin_amdgcn_s_setprio(0);
    };

    for (int j = 0; j < 15; j++) {
        // K_j DMA landed (2 newest — va_{j+1} — may fly); own ds ops retired
        asm volatile("s_waitcnt vmcnt(2)" ::: "memory");
        asm volatile("s_waitcnt lgkmcnt(0)" ::: "memory");
        __builtin_amdgcn_s_barrier();   // buf[j&1] fully valid for all waves

        const int nb = (j + 1) & 1;
        gll16(kg0, &Ks[nb * 4096 + kofsA]);   // K_{j+1}: flies across phases
        gll16(kg1, &Ks[nb * 4096 + kofsB]);
        kg0 += kstep; kg1 += kstep;
        // wait va_{j+1} only (K_{j+1} stays outstanding)
        asm volatile("s_waitcnt vmcnt(2)" ::: "memory");
        short* vt = &Vt[nb * 64 * LDT];
        #pragma unroll
        for (int e = 0; e < 8; e++) vt[(scol + e) * LDT + (srow ^ vswz)] = va0[e];
        #pragma unroll
        for (int e = 0; e < 8; e++) vt[(scol + 8 + e) * LDT + (srow ^ vswz)] = va1[e];
        if (j < 14) {
            va0 = *(const short8*)(vgp);      // va_{j+2}: flies across phases
            va1 = *(const short8*)(vgp + 8);
            vgp += kstep;
        }
        compute(&Ks[(j & 1) * 4096], &Vt[(j & 1) * 64 * LDT]);
    }
    // last iter (j=15): only K_15(2) outstanding
    asm volatile("s_waitcnt vmcnt(0)" ::: "memory");
    asm volatile("s_waitcnt lgkmcnt(0)" ::: "memory");
    __builtin_amdgcn_s_barrier();
    compute(&Ks[4096], &Vt[64 * LDT]);

    // epilogue: partial O (unnormalized) -> obuf[half], raw l -> lbuf[half].
    // oacc[dt][reg] = O[q_local = 4h + (reg&3) + 8*(reg>>2)][d = dt*32+l32]
    {
        short* obase = half ? obuf2 : obuf1;
        float* lb = lbuf + (size_t)half * 8192 * 12;
        float lt = lsum + __shfl_xor(lsum, 32, 64);
        #pragma unroll
        for (int m = 0; m < 4; m++) {
            #pragma unroll
            for (int r = 0; r < 4; r++) {
                const int ql = 4 * h + r + 8 * m;
                short* od = obase + (bpos + (size_t)ql * rate) * 768 + head * 64;
                od[l32]      = f2bf(oacc[0][m * 4 + r]);
                od[32 + l32] = f2bf(oacc[1][m * 4 + r]);
            }
        }
        if (lane < 32)
            lb[(bpos + (size_t)l32 * rate) * 12 + head] = lt;
    }
}

// ---- Fused LayerNorm + split-K combine: obuf1+obuf2 -> q section ----------
__global__ __launch_bounds__(256) void ln_inplace(
    short* __restrict__ qkv, const short* __restrict__ obuf1,
    const short* __restrict__ obuf2, const float* __restrict__ lbuf,
    const float* __restrict__ gamma, const float* __restrict__ beta)
{
    const int row  = blockIdx.x * 4 + (threadIdx.x >> 6);
    const int lane = threadIdx.x & 63;
    const short* s1 = obuf1 + (size_t)row * 768;
    const short* s2 = obuf2 + (size_t)row * 768;
    short* dst = qkv + (size_t)row * 2304;

    // heads: first 8 elems (idx lane*8..+7) in head lane>>3;
    // last 4 (idx 512+lane*4..+3) in head 8+(lane>>4)
    const int h1 = lane >> 3;          // 0..7  (groups 0,1)
    const int h2 = 8 + (lane >> 4);    // 8..11 (group 2)
    const bool cov1 = (h1 < 4) || ((row & 1) == 1);
    const bool cov2 = ((row & 3) == 2);
    const float li1 = cov1
        ? 1.0f / (lbuf[row * 12 + h1] + lbuf[8192 * 12 + row * 12 + h1]) : 0.0f;
    const float li2 = cov2
        ? 1.0f / (lbuf[row * 12 + h2] + lbuf[8192 * 12 + row * 12 + h2]) : 0.0f;

    short8  a  = *(const short8*)&s1[lane * 8];
    short4_ b  = *(const short4_*)&s1[512 + lane * 4];
    short8  a2 = *(const short8*)&s2[lane * 8];
    short4_ b2 = *(const short4_*)&s2[512 + lane * 4];
    float v[12];
    #pragma unroll
    for (int e = 0; e < 8; e++)
        v[e] = cov1 ? (bf2f(a[e]) + bf2f(a2[e])) * li1 : 0.0f;
    #pragma unroll
    for (int e = 0; e < 4; e++)
        v[8 + e] = cov2 ? (bf2f(b[e]) + bf2f(b2[e])) * li2 : 0.0f;

    float sum = 0.f, sq = 0.f;
    #pragma unroll
    for (int e = 0; e < 12; e++) { sum += v[e]; sq += v[e] * v[e]; }
    #pragma unroll
    for (int off = 1; off < 64; off <<= 1) {
        sum += __shfl_xor(sum, off, 64);
        sq  += __shfl_xor(sq,  off, 64);
    }
    float mean = sum * (1.0f / 768.0f);
    float var  = sq * (1.0f / 768.0f) - mean * mean;
    float rstd = rsqrtf(var + 1e-5f);

    short8 o8; short4_ o4;
    #pragma unroll
    for (int e = 0; e < 8; e++)
        o8[e] = f2bf((v[e] - mean) * rstd * gamma[lane * 8 + e] + beta[lane * 8 + e]);
    #pragma unroll
    for (int e = 0; e < 4; e++)
        o4[e] = f2bf((v[8 + e] - mean) * rstd * gamma[512 + lane * 4 + e] + beta[512 + lane * 4 + e]);

    *(short8*)&dst[lane * 8] = o8;
    *(short4_*)&dst[512 + lane * 4] = o4;
}

extern "C" void kernel_launch(void* const* d_in, const int* in_sizes, int n_in,
                              void* d_out, int out_size, void* d_ws, size_t ws_size,
                              hipStream_t stream) {
    const float* x     = (const float*)d_in[0];   // [8192,768]
    const float* w_qkv = (const float*)d_in[1];   // [2304,768]
    const float* b_qkv = (const float*)d_in[2];
    const float* w_out = (const float*)d_in[3];   // [768,768]
    const float* b_out = (const float*)d_in[4];
    const float* gamma = (const float*)d_in[5];
    const float* beta  = (const float*)d_in[6];
    float* out = (float*)d_out;                   // [8192,768] fp32

    const int NX = 8192 * 768, NW1 = 2304 * 768, NW2 = 768 * 768;
    char* ws = (char*)d_ws;
    short* qkv   = (short*)(ws);                          // 37.75 MB
    short* xb    = (short*)(ws + (size_t)8192 * 2304 * 2);
    short* wqkvb = xb + NX;
    short* woutb = wqkvb + NW1;
    float* lbuf  = (float*)(woutb + NW2);                 // 2*8192*12 fp32
    short* obuf2 = (short*)(lbuf + 2 * 8192 * 12);        // 12.6 MB
    short* obuf1 = xb;   // xb dead after gemm_qkv; reuse for split-0 partial O

    // 0) one-shot fp32->bf16 conversions (K-rows of w_qkv pre-scaled)
    cvt3<<<dim3((NX + NW1 + NW2) / (256 * 8)), 256, 0, stream>>>(
        x, NX, w_qkv, NW1, w_out, NW2, xb, wqkvb, woutb);

    // 1) qkv = x @ w_qkv^T + b_qkv, covered cells only (16.9 GFLOP)
    gemm_qkv<<<dim3(1344), 256, 0, stream>>>(xb, wqkvb, b_qkv, qkv);

    // 2) split-K in-reg-P attention: partial O -> obuf1/obuf2, l -> lbuf
    dilated_attn<<<dim3(28 * 2 * 16), 256, 0, stream>>>(qkv, obuf1, obuf2, lbuf);

    // 3) LayerNorm + combine -> q section (full 768 cols written)
    ln_inplace<<<dim3(8192 / 4), 256, 0, stream>>>(
        qkv, obuf1, obuf2, lbuf, gamma, beta);

    // 4) out = LN(o) @ w_out^T + b_out (fp32 store)
    gemm_out<<<dim3(768), 256, 0, stream>>>(qkv, woutb, b_out, out);
}